// Round 3
// baseline (1721.012 us; speedup 1.0000x reference)
//
#include <hip/hip_runtime.h>
#include <hip/hip_bf16.h>
#include <cstdint>

// DeltaNet forward, MI355X. Round 3: fix 64x128 tile staging decode in
// phaseA/phaseB (rr=ch>>4, kc=ch&15) -- was OOB/garbage -> NaN.

typedef _Float16 f16;
typedef __attribute__((ext_vector_type(8))) _Float16 h8;
typedef __attribute__((ext_vector_type(4))) _Float16 h4;
typedef __attribute__((ext_vector_type(4))) float f4;

#define DEV __device__ __forceinline__

static constexpr int Bb_ = 4;     // batch
static constexpr int Hh  = 8;     // heads
static constexpr int Dd  = 1024;  // hidden
static constexpr int Tt  = 2048;  // seq
static constexpr int NC  = 32;    // chunks (T/64)

DEV float siluf(float x) { return x / (1.f + expf(-x)); }

#define AS1(p) ((const __attribute__((address_space(1))) void*)(uintptr_t)(p))
#define AS3(p) ((__attribute__((address_space(3))) void*)(uint32_t)(uintptr_t)(p))

// ---------------- GEMM: C[M,N] (+)= A[M,K] * Bt[N,K]^T, f16 in --------------
// EPI 0: f32 store; 1: f32 +=; 2: f16 store; 3: f16 glu store silu(acc)*Y
template<int EPI>
__global__ __launch_bounds__(256) void gemm_bt(const f16* __restrict__ A, const f16* __restrict__ Bt,
                                               void* __restrict__ C, const f16* __restrict__ Yp,
                                               int M, int N, int K) {
  __shared__ __align__(16) f16 As[128 * 64];
  __shared__ __align__(16) f16 Bs[128 * 64];
  const int tid = threadIdx.x, lane = tid & 63, wv = tid >> 6;
  const int l15 = lane & 15, l4 = lane >> 4;
  const int wrow = (wv & 1) << 6, wcol = (wv >> 1) << 6;
  const size_t bx = blockIdx.x, by = blockIdx.y;
  const f16* Ab = A + by * 128 * (size_t)K;
  const f16* Bb = Bt + bx * 128 * (size_t)K;
  f4 acc[4][4] = {};
  for (int kt = 0; kt < K; kt += 64) {
#pragma unroll
    for (int i = 0; i < 4; ++i) {
      const int ch = tid + i * 256;        // 1024 chunks of 16B per tile
      const int rr = ch >> 3, kc = ch & 7; // 128 rows x 8 chunks (64 cols)
      __builtin_amdgcn_global_load_lds(AS1(Ab + (size_t)rr * K + kt + kc * 8), AS3(As + ch * 8), 16, 0, 0);
      __builtin_amdgcn_global_load_lds(AS1(Bb + (size_t)rr * K + kt + kc * 8), AS3(Bs + ch * 8), 16, 0, 0);
    }
    __syncthreads();
#pragma unroll
    for (int ks = 0; ks < 2; ++ks) {
      h8 a[4], b[4];
#pragma unroll
      for (int r = 0; r < 4; ++r) a[r] = *(const h8*)(As + (wrow + r * 16 + l15) * 64 + ks * 32 + l4 * 8);
#pragma unroll
      for (int c = 0; c < 4; ++c) b[c] = *(const h8*)(Bs + (wcol + c * 16 + l15) * 64 + ks * 32 + l4 * 8);
#pragma unroll
      for (int r = 0; r < 4; ++r)
#pragma unroll
        for (int c = 0; c < 4; ++c)
          acc[r][c] = __builtin_amdgcn_mfma_f32_16x16x32_f16(a[r], b[c], acc[r][c], 0, 0, 0);
    }
    __syncthreads();
  }
#pragma unroll
  for (int r = 0; r < 4; ++r) {
#pragma unroll
    for (int c = 0; c < 4; ++c) {
      const int row0 = (int)by * 128 + wrow + r * 16 + l4 * 4;
      const int col = (int)bx * 128 + wcol + c * 16 + l15;
#pragma unroll
      for (int q = 0; q < 4; ++q) {
        size_t idx = (size_t)(row0 + q) * N + col;
        float v = acc[r][c][q];
        if (EPI == 0) ((float*)C)[idx] = v;
        if (EPI == 1) ((float*)C)[idx] += v;
        if (EPI == 2) ((f16*)C)[idx] = (f16)v;
        if (EPI == 3) ((f16*)C)[idx] = (f16)(siluf(v) * (float)Yp[idx]);
      }
    }
  }
}

// ---------------- RMSNorm over D=1024 ------------------------------------
template<int OUT_F16>
__global__ __launch_bounds__(256) void rmsnorm_k(const float* __restrict__ x, const float* __restrict__ w,
                                                 void* __restrict__ out) {
  const int r = blockIdx.x, tid = threadIdx.x;
  const float4 v = *(const float4*)(x + (size_t)r * 1024 + tid * 4);
  float ss = v.x * v.x + v.y * v.y + v.z * v.z + v.w * v.w;
#pragma unroll
  for (int m = 1; m < 64; m <<= 1) ss += __shfl_xor(ss, m);
  __shared__ float red[4];
  if ((tid & 63) == 0) red[tid >> 6] = ss;
  __syncthreads();
  const float scale = rsqrtf((red[0] + red[1] + red[2] + red[3]) * (1.f / 1024.f) + 1e-6f);
  const float4 w4 = *(const float4*)(w + tid * 4);
  float o0 = v.x * scale * w4.x, o1 = v.y * scale * w4.y, o2 = v.z * scale * w4.z, o3 = v.w * scale * w4.w;
  if (OUT_F16) {
    h4 o = {(f16)o0, (f16)o1, (f16)o2, (f16)o3};
    *(h4*)((f16*)out + (size_t)r * 1024 + tid * 4) = o;
  } else {
    *(float4*)((float*)out + (size_t)r * 1024 + tid * 4) = make_float4(o0, o1, o2, o3);
  }
}

// ---------------- silu + per-head l2norm for q,k; silu for v ---------------
__global__ __launch_bounds__(256) void qkv_epi(const f16* __restrict__ qraw, const f16* __restrict__ kraw,
                                               const f16* __restrict__ vraw, f16* __restrict__ qb,
                                               f16* __restrict__ kb, f16* __restrict__ vb) {
  const int r = blockIdx.x, tid = threadIdx.x;
  const int head = tid >> 5, l32 = tid & 31;
  const size_t base = (size_t)r * 1024 + head * 128 + l32 * 4;
  {
    const h4 v = *(const h4*)(qraw + base);
    float s0 = siluf((float)v[0]), s1 = siluf((float)v[1]), s2 = siluf((float)v[2]), s3 = siluf((float)v[3]);
    float ss = s0 * s0 + s1 * s1 + s2 * s2 + s3 * s3;
#pragma unroll
    for (int m = 1; m <= 16; m <<= 1) ss += __shfl_xor(ss, m);
    const float sc = rsqrtf(ss + 1e-6f);
    h4 o = {(f16)(s0 * sc), (f16)(s1 * sc), (f16)(s2 * sc), (f16)(s3 * sc)};
    *(h4*)(qb + base) = o;
  }
  {
    const h4 v = *(const h4*)(kraw + base);
    float s0 = siluf((float)v[0]), s1 = siluf((float)v[1]), s2 = siluf((float)v[2]), s3 = siluf((float)v[3]);
    float ss = s0 * s0 + s1 * s1 + s2 * s2 + s3 * s3;
#pragma unroll
    for (int m = 1; m <= 16; m <<= 1) ss += __shfl_xor(ss, m);
    const float sc = rsqrtf(ss + 1e-6f);
    h4 o = {(f16)(s0 * sc), (f16)(s1 * sc), (f16)(s2 * sc), (f16)(s3 * sc)};
    *(h4*)(kb + base) = o;
  }
  {
    const size_t b2 = (size_t)r * 1024 + tid * 4;
    const h4 v = *(const h4*)(vraw + b2);
    h4 o = {(f16)siluf((float)v[0]), (f16)siluf((float)v[1]), (f16)siluf((float)v[2]), (f16)siluf((float)v[3])};
    *(h4*)(vb + b2) = o;
  }
}

// ---------------- per-head RMSNorm (DV=128) with shared weight -------------
__global__ __launch_bounds__(256) void onorm_k(const float* __restrict__ o, const float* __restrict__ w,
                                               f16* __restrict__ ob) {
  const int r = blockIdx.x, tid = threadIdx.x;
  const int head = tid >> 5, l32 = tid & 31;
  const size_t base = (size_t)r * 1024 + head * 128 + l32 * 4;
  const float4 v = *(const float4*)(o + base);
  float ss = v.x * v.x + v.y * v.y + v.z * v.z + v.w * v.w;
#pragma unroll
  for (int m = 1; m <= 16; m <<= 1) ss += __shfl_xor(ss, m);
  const float sc = rsqrtf(ss * (1.f / 128.f) + 1e-6f);
  const float4 w4 = *(const float4*)(w + l32 * 4);
  h4 out = {(f16)(v.x * sc * w4.x), (f16)(v.y * sc * w4.y), (f16)(v.z * sc * w4.z), (f16)(v.w * sc * w4.w)};
  *(h4*)(ob + base) = out;
}

// ---------------- beta = 2*sigmoid(h @ Wb) --------------------------------
__global__ __launch_bounds__(256) void beta_k(const f16* __restrict__ hb, const float* __restrict__ Wb,
                                              float* __restrict__ beta) {
  const int r = blockIdx.x, tid = threadIdx.x;
  const int j = tid >> 5, l32 = tid & 31;
  float acc = 0.f;
#pragma unroll 4
  for (int i = 0; i < 32; ++i) {
    const int kk = l32 + i * 32;
    acc += (float)hb[(size_t)r * 1024 + kk] * Wb[(size_t)kk * 8 + j];
  }
#pragma unroll
  for (int m = 1; m <= 16; m <<= 1) acc += __shfl_xor(acc, m);
  if (l32 == 0) beta[(size_t)r * 8 + j] = 2.f / (1.f + expf(-acc));
}

// ---------------- W[K][N] f32 -> Wt[N][K] f16 ------------------------------
__global__ __launch_bounds__(256) void transpose_k(const float* __restrict__ W, f16* __restrict__ Wt,
                                                   int K, int N) {
  __shared__ float tile[32][33];
  const int n0 = blockIdx.x * 32, k0 = blockIdx.y * 32;
  const int tx = threadIdx.x & 31, ty = threadIdx.x >> 5;
#pragma unroll
  for (int i = 0; i < 32; i += 8) tile[ty + i][tx] = W[(size_t)(k0 + ty + i) * N + n0 + tx];
  __syncthreads();
#pragma unroll
  for (int i = 0; i < 32; i += 8) Wt[(size_t)(n0 + ty + i) * K + k0 + tx] = (f16)tile[tx][ty + i];
}

// ---------------- diagnostic fill ------------------------------------------
__global__ void fill_k(float* p, int n, float v) {
  const int i = blockIdx.x * 256 + threadIdx.x;
  if (i < n) p[i] = v;
}

// ---------------- Phase A: per-(bh,chunk) WY transform ---------------------
// A = strict_tril(diag(beta) K K^T); solve (I+A)w=betaK, (I+A)u=betaV;
// P = tril_incl(Q K^T). Outputs w(f16), u(f16), P(f16).
__global__ __launch_bounds__(256) void phaseA(const f16* __restrict__ kb, const f16* __restrict__ qb,
                                              const f16* __restrict__ vb, const float* __restrict__ beta,
                                              f16* __restrict__ wbuf, f16* __restrict__ ubuf,
                                              f16* __restrict__ pbuf) {
  const int blk = blockIdx.x;
  const int c = blk >> 5, bh = blk & 31;
  const int b = bh >> 3, h = bh & 7;
  const int tid = threadIdx.x, lane = tid & 63, wv = tid >> 6;
  const int l15 = lane & 15, l4 = lane >> 4;

  __shared__ __align__(16) f16 Ks[64 * 128];
  __shared__ __align__(16) char Xreg[64 * 128 * 4];  // Qs (f16) then wu (f32 [64][128])
  __shared__ __align__(16) f16 Abuf[64 * 66];
  __shared__ float betas[64];
  f16* Qs = (f16*)Xreg;
  float* wu = (float*)Xreg;

  const size_t rowstr = (size_t)Bb_ * Dd;
  const size_t gbase = ((size_t)(c * 64) * Bb_ + b) * Dd + h * 128;

#pragma unroll
  for (int i = 0; i < 4; ++i) {
    const int ch = tid + i * 256;
    const int rr = ch >> 4, kc = ch & 15;  // 64 rows x 16 chunks (128 cols)
    *(h8*)(Ks + ch * 8) = *(const h8*)(kb + gbase + (size_t)rr * rowstr + kc * 8);
    *(h8*)(Qs + ch * 8) = *(const h8*)(qb + gbase + (size_t)rr * rowstr + kc * 8);
  }
  if (tid < 64) betas[tid] = beta[((size_t)(c * 64 + tid) * Bb_ + b) * Hh + h];
  __syncthreads();

  f4 accS[4] = {}, accP[4] = {};
  const int arow = wv * 16 + l15;
  const int koff = l4 * 8;
#pragma unroll
  for (int kc = 0; kc < 4; ++kc) {
    const h8 aK = *(const h8*)(Ks + arow * 128 + kc * 32 + koff);
    const h8 aQ = *(const h8*)(Qs + arow * 128 + kc * 32 + koff);
#pragma unroll
    for (int f = 0; f < 4; ++f) {
      const h8 bK = *(const h8*)(Ks + (f * 16 + l15) * 128 + kc * 32 + koff);
      accS[f] = __builtin_amdgcn_mfma_f32_16x16x32_f16(aK, bK, accS[f], 0, 0, 0);
      accP[f] = __builtin_amdgcn_mfma_f32_16x16x32_f16(aQ, bK, accP[f], 0, 0, 0);
    }
  }
  const size_t pbase = (((size_t)bh * NC + c) * 64) * 64;
#pragma unroll
  for (int f = 0; f < 4; ++f) {
#pragma unroll
    for (int q = 0; q < 4; ++q) {
      const int i = wv * 16 + l4 * 4 + q;
      const int j = f * 16 + l15;
      Abuf[i * 66 + j] = (f16)((j < i) ? betas[i] * accS[f][q] : 0.f);
      pbuf[pbase + (size_t)i * 64 + j] = (f16)((j <= i) ? accP[f][q] : 0.f);
    }
  }
  __syncthreads();

  const size_t wub = ((size_t)bh * Tt + c * 64) * 128;
  // pass 1: w
  if (tid < 128) {
#pragma unroll 4
    for (int i = 0; i < 64; ++i) wu[i * 128 + tid] = betas[i] * (float)Ks[i * 128 + tid];
    float* col = wu + tid;
    for (int i = 1; i < 64; ++i) {
      float a0 = 0.f, a1 = 0.f;
      const f16* Ai = Abuf + i * 66;
      int j = 0;
      for (; j + 2 <= i; j += 2) { a0 += (float)Ai[j] * col[j * 128]; a1 += (float)Ai[j + 1] * col[(j + 1) * 128]; }
      if (j < i) a0 += (float)Ai[j] * col[j * 128];
      col[i * 128] -= (a0 + a1);
    }
  }
  __syncthreads();
  for (int e = tid; e < 64 * 128; e += 256) wbuf[wub + e] = (f16)wu[e];
  __syncthreads();
  // pass 2: u
  if (tid < 128) {
    const f16* vp = vb + gbase + tid;
#pragma unroll 4
    for (int i = 0; i < 64; ++i) wu[i * 128 + tid] = betas[i] * (float)vp[(size_t)i * rowstr];
    float* col = wu + tid;
    for (int i = 1; i < 64; ++i) {
      float a0 = 0.f, a1 = 0.f;
      const f16* Ai = Abuf + i * 66;
      int j = 0;
      for (; j + 2 <= i; j += 2) { a0 += (float)Ai[j] * col[j * 128]; a1 += (float)Ai[j + 1] * col[(j + 1) * 128]; }
      if (j < i) a0 += (float)Ai[j] * col[j * 128];
      col[i * 128] -= (a0 + a1);
    }
  }
  __syncthreads();
  for (int e = tid; e < 64 * 128; e += 256) ubuf[wub + e] = (f16)wu[e];
}

// ---------------- Phase B: sequential chunk recurrence ---------------------
// Per block (bh, g of 4 DV-groups of 32 cols): state M = S^T [32,128] in f32 frags.
// Per chunk: R = u - w@S ; O = Q@S + P@R ; M += R^T K.
__global__ __launch_bounds__(256) void phaseB(const f16* __restrict__ qb, const f16* __restrict__ kb,
                                              const f16* __restrict__ wbuf, const f16* __restrict__ ubuf,
                                              const f16* __restrict__ pbuf, float* __restrict__ obuf) {
  const int blk = blockIdx.x;  // bh*4 + g
  const int bh = blk >> 2, g = blk & 3;
  const int b = bh >> 3, h = bh & 7;
  const int tid = threadIdx.x, lane = tid & 63, wv = tid >> 6;
  const int l15 = lane & 15, l4 = lane >> 4;

  __shared__ __align__(16) f16 Ws[64 * 128];
  __shared__ __align__(16) f16 Qs[64 * 128];
  __shared__ __align__(16) f16 Ks[64 * 128];
  __shared__ __align__(16) f16 Ps[64 * 64];
  __shared__ __align__(16) f16 Rt[32 * 72];   // R^T, padded rows
  __shared__ __align__(16) f16 Ms[32 * 136];  // M = S^T (f16 export), padded rows

  for (int i = tid; i < 32 * 136; i += 256) Ms[i] = (f16)0.f;
  f4 macc[2][2] = {};  // persistent f32 state frags

  const size_t rowstr = (size_t)Bb_ * Dd;
  const size_t qk0 = (size_t)b * Dd + h * 128;
  const int arow = wv * 16 + l15;
  const int koff = l4 * 8;
  __syncthreads();

  for (int c = 0; c < NC; ++c) {
    const size_t wub = ((size_t)bh * Tt + c * 64) * 128;
    const size_t pbase = (((size_t)bh * NC + c) * 64) * 64;
#pragma unroll
    for (int i = 0; i < 4; ++i) {
      const int ch = tid + i * 256;
      const int rr = ch >> 4, kc = ch & 15;  // 64 rows x 16 chunks (128 cols)
      *(h8*)(Ws + ch * 8) = *(const h8*)(wbuf + wub + ch * 8);
      *(h8*)(Qs + ch * 8) = *(const h8*)(qb + qk0 + (size_t)(c * 64 + rr) * rowstr + kc * 8);
      *(h8*)(Ks + ch * 8) = *(const h8*)(kb + qk0 + (size_t)(c * 64 + rr) * rowstr + kc * 8);
    }
#pragma unroll
    for (int i = 0; i < 2; ++i) {
      const int ch = tid + i * 256;
      *(h8*)(Ps + ch * 8) = *(const h8*)(pbuf + pbase + ch * 8);
    }
    __syncthreads();

    // phase1: accR = w@S (then R = u - accR), accO = Q@S
    f4 accR[2] = {}, accO[2] = {};
#pragma unroll
    for (int kc = 0; kc < 4; ++kc) {
      const h8 aW = *(const h8*)(Ws + arow * 128 + kc * 32 + koff);
      const h8 aQ = *(const h8*)(Qs + arow * 128 + kc * 32 + koff);
#pragma unroll
      for (int f = 0; f < 2; ++f) {
        const h8 bM = *(const h8*)(Ms + (f * 16 + l15) * 136 + kc * 32 + koff);
        accR[f] = __builtin_amdgcn_mfma_f32_16x16x32_f16(aW, bM, accR[f], 0, 0, 0);
        accO[f] = __builtin_amdgcn_mfma_f32_16x16x32_f16(aQ, bM, accO[f], 0, 0, 0);
      }
    }
#pragma unroll
    for (int f = 0; f < 2; ++f) {
#pragma unroll
      for (int q = 0; q < 4; ++q) {
        const int i = wv * 16 + l4 * 4 + q;
        const int cc = f * 16 + l15;
        const float uv = (float)ubuf[wub + (size_t)i * 128 + g * 32 + cc];
        const float rv = uv - accR[f][q];
        accR[f][q] = rv;
        Rt[cc * 72 + i] = (f16)rv;
      }
    }
    __syncthreads();

    // phase2: accO += P@R ; store O ; M += R^T K ; export Ms
#pragma unroll
    for (int kc = 0; kc < 2; ++kc) {
      const h8 aP = *(const h8*)(Ps + arow * 64 + kc * 32 + koff);
#pragma unroll
      for (int f = 0; f < 2; ++f) {
        const h8 bR = *(const h8*)(Rt + (f * 16 + l15) * 72 + kc * 32 + koff);
        accO[f] = __builtin_amdgcn_mfma_f32_16x16x32_f16(aP, bR, accO[f], 0, 0, 0);
      }
    }
#pragma unroll
    for (int f = 0; f < 2; ++f)
#pragma unroll
      for (int q = 0; q < 4; ++q) {
        const int i = wv * 16 + l4 * 4 + q;
        const int cc = f * 16 + l15;
        obuf[((size_t)(c * 64 + i) * Bb_ + b) * Dd + h * 128 + g * 32 + cc] = accO[f][q];
      }

#pragma unroll
    for (int kc = 0; kc < 2; ++kc) {
      const h8 aR0 = *(const h8*)(Rt + l15 * 72 + kc * 32 + koff);
      const h8 aR1 = *(const h8*)(Rt + (16 + l15) * 72 + kc * 32 + koff);
#pragma unroll
      for (int cf = 0; cf < 2; ++cf) {
        const int kcol = wv * 32 + cf * 16 + l15;
        h8 bKv;
#pragma unroll
        for (int j = 0; j < 8; ++j) bKv[j] = Ks[(kc * 32 + koff + j) * 128 + kcol];
        macc[0][cf] = __builtin_amdgcn_mfma_f32_16x16x32_f16(aR0, bKv, macc[0][cf], 0, 0, 0);
        macc[1][cf] = __builtin_amdgcn_mfma_f32_16x16x32_f16(aR1, bKv, macc[1][cf], 0, 0, 0);
      }
    }
#pragma unroll
    for (int rf = 0; rf < 2; ++rf)
#pragma unroll
      for (int cf = 0; cf < 2; ++cf)
#pragma unroll
        for (int q = 0; q < 4; ++q) {
          const int cr = rf * 16 + l4 * 4 + q;
          const int kcol = wv * 32 + cf * 16 + l15;
          Ms[cr * 136 + kcol] = (f16)macc[rf][cf][q];
        }
    __syncthreads();
  }
}

// ---------------------------------------------------------------------------
extern "C" void kernel_launch(void* const* d_in, const int* in_sizes, int n_in,
                              void* d_out, int out_size, void* d_ws, size_t ws_size,
                              hipStream_t stream) {
  (void)in_sizes; (void)n_in;
  const float* input = (const float*)d_in[0];
  const float* Wq = (const float*)d_in[1];
  const float* Wk = (const float*)d_in[2];
  const float* Wv = (const float*)d_in[3];
  const float* Wb = (const float*)d_in[4];
  const float* Wo = (const float*)d_in[5];
  const float* onw = (const float*)d_in[6];
  const float* n1w = (const float*)d_in[7];
  const float* n2w = (const float*)d_in[8];
  const float* Wg = (const float*)d_in[9];
  const float* Wd = (const float*)d_in[10];
  const float* fnw = (const float*)d_in[11];

  char* ws = (char*)d_ws;
  size_t off = 0;
  auto alloc = [&](size_t bytes) { void* p = ws + off; off += (bytes + 255) & ~(size_t)255; return p; };
  const size_t RD = 8192ull * 1024ull;                 // rows x D elements
  float* x    = (float*)alloc(RD * 4);                 // 32 MiB, residual stream [T,B,D]
  f16*  hb    = (f16*)alloc(RD * 2);                   // 16 MiB
  f16*  qb    = (f16*)alloc(RD * 2);                   // 16 MiB  (qb/kbuf/vbuf contiguous;
  f16*  kbuf  = (f16*)alloc(RD * 2);                   //          reused as `my` [8192,2816] f16)
  f16*  vbuf  = (f16*)alloc(RD * 2);
  float* beta = (float*)alloc(8192ull * 8 * 4);
  f16*  wbuf  = (f16*)alloc(RD * 2);                   // 16 MiB (reused as ob after phaseB)
  f16*  ubuf  = (f16*)alloc(RD * 2);                   // 16 MiB
  f16*  pbuf  = (f16*)alloc(32ull * 32 * 64 * 64 * 2); // 8 MiB
  char* arena = (char*)alloc(3 * RD * 2);              // 48 MiB union: {qraw,kraw,vraw}|{obuf}|{Y}
  f16*  WqT   = (f16*)alloc(1024ull * 1024 * 2);       // single-layer transposed weights
  f16*  WkT   = (f16*)alloc(1024ull * 1024 * 2);
  f16*  WvT   = (f16*)alloc(1024ull * 1024 * 2);
  f16*  WoT   = (f16*)alloc(1024ull * 1024 * 2);
  f16*  WgT   = (f16*)alloc(5632ull * 1024 * 2);
  f16*  WdT   = (f16*)alloc(1024ull * 2816 * 2);
  if (off > ws_size) {  // diagnostic: huge sentinel so this failure mode is unambiguous
    fill_k<<<(out_size + 255) / 256, 256, 0, stream>>>((float*)d_out, out_size, 1.0e6f);
    return;
  }
  f16* qraw = (f16*)arena;
  f16* kraw = qraw + RD;
  f16* vraw = kraw + RD;
  float* obuf = (float*)arena;
  f16* Ybuf = (f16*)arena;
  f16* my = qb;      // 44 MiB into the 48 MiB qb/kbuf/vbuf region (dead by then)
  f16* ob = wbuf;    // wbuf dead after phaseB

  hipMemcpyAsync(x, input, RD * 4, hipMemcpyDeviceToDevice, stream);

  for (int l = 0; l < 2; ++l) {
    const size_t o2 = (size_t)l * 1024 * 1024;
    transpose_k<<<dim3(32, 32), 256, 0, stream>>>(Wq + o2, WqT, 1024, 1024);
    transpose_k<<<dim3(32, 32), 256, 0, stream>>>(Wk + o2, WkT, 1024, 1024);
    transpose_k<<<dim3(32, 32), 256, 0, stream>>>(Wv + o2, WvT, 1024, 1024);
    transpose_k<<<dim3(32, 32), 256, 0, stream>>>(Wo + o2, WoT, 1024, 1024);
    transpose_k<<<dim3(176, 32), 256, 0, stream>>>(Wg + (size_t)l * 1024 * 5632, WgT, 1024, 5632);
    transpose_k<<<dim3(32, 88), 256, 0, stream>>>(Wd + (size_t)l * 2816 * 1024, WdT, 2816, 1024);

    rmsnorm_k<1><<<8192, 256, 0, stream>>>(x, n1w + l * 1024, hb);
    gemm_bt<2><<<dim3(8, 64), 256, 0, stream>>>(hb, WqT, qraw, nullptr, 8192, 1024, 1024);
    gemm_bt<2><<<dim3(8, 64), 256, 0, stream>>>(hb, WkT, kraw, nullptr, 8192, 1024, 1024);
    gemm_bt<2><<<dim3(8, 64), 256, 0, stream>>>(hb, WvT, vraw, nullptr, 8192, 1024, 1024);
    beta_k<<<8192, 256, 0, stream>>>(hb, Wb + (size_t)l * 1024 * 8, beta);
    qkv_epi<<<8192, 256, 0, stream>>>(qraw, kraw, vraw, qb, kbuf, vbuf);
    phaseA<<<1024, 256, 0, stream>>>(kbuf, qb, vbuf, beta, wbuf, ubuf, pbuf);
    phaseB<<<128, 256, 0, stream>>>(qb, kbuf, wbuf, ubuf, pbuf, obuf);
    onorm_k<<<8192, 256, 0, stream>>>(obuf, onw + l * 128, ob);
    gemm_bt<1><<<dim3(8, 64), 256, 0, stream>>>(ob, WoT, x, nullptr, 8192, 1024, 1024);

    rmsnorm_k<1><<<8192, 256, 0, stream>>>(x, n2w + l * 1024, hb);
    // y half first (cols 2816..5632 of Wg), then g half with fused GLU epilogue
    gemm_bt<2><<<dim3(22, 64), 256, 0, stream>>>(hb, WgT + 2816ull * 1024, Ybuf, nullptr, 8192, 2816, 1024);
    gemm_bt<3><<<dim3(22, 64), 256, 0, stream>>>(hb, WgT, my, Ybuf, 8192, 2816, 1024);
    gemm_bt<1><<<dim3(8, 64), 256, 0, stream>>>(my, WdT, x, nullptr, 8192, 1024, 2816);
  }
  rmsnorm_k<0><<<8192, 256, 0, stream>>>(x, fnw, d_out);
}

// Round 4
// 1430.193 us; speedup vs baseline: 1.2033x; 1.2033x over previous
//
#include <hip/hip_runtime.h>
#include <hip/hip_bf16.h>
#include <cstdint>

// DeltaNet forward, MI355X. Round 4: phaseA solve -> MFMA block inversion
// (was 184us latency-bound scalar substitution; predict ~20us).

typedef _Float16 f16;
typedef __attribute__((ext_vector_type(8))) _Float16 h8;
typedef __attribute__((ext_vector_type(4))) _Float16 h4;
typedef __attribute__((ext_vector_type(4))) float f4;

#define DEV __device__ __forceinline__

static constexpr int Bb_ = 4;     // batch
static constexpr int Hh  = 8;     // heads
static constexpr int Dd  = 1024;  // hidden
static constexpr int Tt  = 2048;  // seq
static constexpr int NC  = 32;    // chunks (T/64)

DEV float siluf(float x) { return x / (1.f + expf(-x)); }

#define AS1(p) ((const __attribute__((address_space(1))) void*)(uintptr_t)(p))
#define AS3(p) ((__attribute__((address_space(3))) void*)(uint32_t)(uintptr_t)(p))

// ---------------- GEMM: C[M,N] (+)= A[M,K] * Bt[N,K]^T, f16 in --------------
// EPI 0: f32 store; 1: f32 +=; 2: f16 store; 3: f16 glu store silu(acc)*Y
template<int EPI>
__global__ __launch_bounds__(256) void gemm_bt(const f16* __restrict__ A, const f16* __restrict__ Bt,
                                               void* __restrict__ C, const f16* __restrict__ Yp,
                                               int M, int N, int K) {
  __shared__ __align__(16) f16 As[128 * 64];
  __shared__ __align__(16) f16 Bs[128 * 64];
  const int tid = threadIdx.x, lane = tid & 63, wv = tid >> 6;
  const int l15 = lane & 15, l4 = lane >> 4;
  const int wrow = (wv & 1) << 6, wcol = (wv >> 1) << 6;
  const size_t bx = blockIdx.x, by = blockIdx.y;
  const f16* Ab = A + by * 128 * (size_t)K;
  const f16* Bb = Bt + bx * 128 * (size_t)K;
  f4 acc[4][4] = {};
  for (int kt = 0; kt < K; kt += 64) {
#pragma unroll
    for (int i = 0; i < 4; ++i) {
      const int ch = tid + i * 256;        // 1024 chunks of 16B per tile
      const int rr = ch >> 3, kc = ch & 7; // 128 rows x 8 chunks (64 cols)
      __builtin_amdgcn_global_load_lds(AS1(Ab + (size_t)rr * K + kt + kc * 8), AS3(As + ch * 8), 16, 0, 0);
      __builtin_amdgcn_global_load_lds(AS1(Bb + (size_t)rr * K + kt + kc * 8), AS3(Bs + ch * 8), 16, 0, 0);
    }
    __syncthreads();
#pragma unroll
    for (int ks = 0; ks < 2; ++ks) {
      h8 a[4], b[4];
#pragma unroll
      for (int r = 0; r < 4; ++r) a[r] = *(const h8*)(As + (wrow + r * 16 + l15) * 64 + ks * 32 + l4 * 8);
#pragma unroll
      for (int c = 0; c < 4; ++c) b[c] = *(const h8*)(Bs + (wcol + c * 16 + l15) * 64 + ks * 32 + l4 * 8);
#pragma unroll
      for (int r = 0; r < 4; ++r)
#pragma unroll
        for (int c = 0; c < 4; ++c)
          acc[r][c] = __builtin_amdgcn_mfma_f32_16x16x32_f16(a[r], b[c], acc[r][c], 0, 0, 0);
    }
    __syncthreads();
  }
#pragma unroll
  for (int r = 0; r < 4; ++r) {
#pragma unroll
    for (int c = 0; c < 4; ++c) {
      const int row0 = (int)by * 128 + wrow + r * 16 + l4 * 4;
      const int col = (int)bx * 128 + wcol + c * 16 + l15;
#pragma unroll
      for (int q = 0; q < 4; ++q) {
        size_t idx = (size_t)(row0 + q) * N + col;
        float v = acc[r][c][q];
        if (EPI == 0) ((float*)C)[idx] = v;
        if (EPI == 1) ((float*)C)[idx] += v;
        if (EPI == 2) ((f16*)C)[idx] = (f16)v;
        if (EPI == 3) ((f16*)C)[idx] = (f16)(siluf(v) * (float)Yp[idx]);
      }
    }
  }
}

// ---------------- RMSNorm over D=1024 ------------------------------------
template<int OUT_F16>
__global__ __launch_bounds__(256) void rmsnorm_k(const float* __restrict__ x, const float* __restrict__ w,
                                                 void* __restrict__ out) {
  const int r = blockIdx.x, tid = threadIdx.x;
  const float4 v = *(const float4*)(x + (size_t)r * 1024 + tid * 4);
  float ss = v.x * v.x + v.y * v.y + v.z * v.z + v.w * v.w;
#pragma unroll
  for (int m = 1; m < 64; m <<= 1) ss += __shfl_xor(ss, m);
  __shared__ float red[4];
  if ((tid & 63) == 0) red[tid >> 6] = ss;
  __syncthreads();
  const float scale = rsqrtf((red[0] + red[1] + red[2] + red[3]) * (1.f / 1024.f) + 1e-6f);
  const float4 w4 = *(const float4*)(w + tid * 4);
  float o0 = v.x * scale * w4.x, o1 = v.y * scale * w4.y, o2 = v.z * scale * w4.z, o3 = v.w * scale * w4.w;
  if (OUT_F16) {
    h4 o = {(f16)o0, (f16)o1, (f16)o2, (f16)o3};
    *(h4*)((f16*)out + (size_t)r * 1024 + tid * 4) = o;
  } else {
    *(float4*)((float*)out + (size_t)r * 1024 + tid * 4) = make_float4(o0, o1, o2, o3);
  }
}

// ---------------- silu + per-head l2norm for q,k; silu for v ---------------
__global__ __launch_bounds__(256) void qkv_epi(const f16* __restrict__ qraw, const f16* __restrict__ kraw,
                                               const f16* __restrict__ vraw, f16* __restrict__ qb,
                                               f16* __restrict__ kb, f16* __restrict__ vb) {
  const int r = blockIdx.x, tid = threadIdx.x;
  const int head = tid >> 5, l32 = tid & 31;
  const size_t base = (size_t)r * 1024 + head * 128 + l32 * 4;
  {
    const h4 v = *(const h4*)(qraw + base);
    float s0 = siluf((float)v[0]), s1 = siluf((float)v[1]), s2 = siluf((float)v[2]), s3 = siluf((float)v[3]);
    float ss = s0 * s0 + s1 * s1 + s2 * s2 + s3 * s3;
#pragma unroll
    for (int m = 1; m <= 16; m <<= 1) ss += __shfl_xor(ss, m);
    const float sc = rsqrtf(ss + 1e-6f);
    h4 o = {(f16)(s0 * sc), (f16)(s1 * sc), (f16)(s2 * sc), (f16)(s3 * sc)};
    *(h4*)(qb + base) = o;
  }
  {
    const h4 v = *(const h4*)(kraw + base);
    float s0 = siluf((float)v[0]), s1 = siluf((float)v[1]), s2 = siluf((float)v[2]), s3 = siluf((float)v[3]);
    float ss = s0 * s0 + s1 * s1 + s2 * s2 + s3 * s3;
#pragma unroll
    for (int m = 1; m <= 16; m <<= 1) ss += __shfl_xor(ss, m);
    const float sc = rsqrtf(ss + 1e-6f);
    h4 o = {(f16)(s0 * sc), (f16)(s1 * sc), (f16)(s2 * sc), (f16)(s3 * sc)};
    *(h4*)(kb + base) = o;
  }
  {
    const size_t b2 = (size_t)r * 1024 + tid * 4;
    const h4 v = *(const h4*)(vraw + b2);
    h4 o = {(f16)siluf((float)v[0]), (f16)siluf((float)v[1]), (f16)siluf((float)v[2]), (f16)siluf((float)v[3])};
    *(h4*)(vb + b2) = o;
  }
}

// ---------------- per-head RMSNorm (DV=128) with shared weight -------------
__global__ __launch_bounds__(256) void onorm_k(const float* __restrict__ o, const float* __restrict__ w,
                                               f16* __restrict__ ob) {
  const int r = blockIdx.x, tid = threadIdx.x;
  const int head = tid >> 5, l32 = tid & 31;
  const size_t base = (size_t)r * 1024 + head * 128 + l32 * 4;
  const float4 v = *(const float4*)(o + base);
  float ss = v.x * v.x + v.y * v.y + v.z * v.z + v.w * v.w;
#pragma unroll
  for (int m = 1; m <= 16; m <<= 1) ss += __shfl_xor(ss, m);
  const float sc = rsqrtf(ss * (1.f / 128.f) + 1e-6f);
  const float4 w4 = *(const float4*)(w + l32 * 4);
  h4 out = {(f16)(v.x * sc * w4.x), (f16)(v.y * sc * w4.y), (f16)(v.z * sc * w4.z), (f16)(v.w * sc * w4.w)};
  *(h4*)(ob + base) = out;
}

// ---------------- beta = 2*sigmoid(h @ Wb) --------------------------------
__global__ __launch_bounds__(256) void beta_k(const f16* __restrict__ hb, const float* __restrict__ Wb,
                                              float* __restrict__ beta) {
  const int r = blockIdx.x, tid = threadIdx.x;
  const int j = tid >> 5, l32 = tid & 31;
  float acc = 0.f;
#pragma unroll 4
  for (int i = 0; i < 32; ++i) {
    const int kk = l32 + i * 32;
    acc += (float)hb[(size_t)r * 1024 + kk] * Wb[(size_t)kk * 8 + j];
  }
#pragma unroll
  for (int m = 1; m <= 16; m <<= 1) acc += __shfl_xor(acc, m);
  if (l32 == 0) beta[(size_t)r * 8 + j] = 2.f / (1.f + expf(-acc));
}

// ---------------- W[K][N] f32 -> Wt[N][K] f16 ------------------------------
__global__ __launch_bounds__(256) void transpose_k(const float* __restrict__ W, f16* __restrict__ Wt,
                                                   int K, int N) {
  __shared__ float tile[32][33];
  const int n0 = blockIdx.x * 32, k0 = blockIdx.y * 32;
  const int tx = threadIdx.x & 31, ty = threadIdx.x >> 5;
#pragma unroll
  for (int i = 0; i < 32; i += 8) tile[ty + i][tx] = W[(size_t)(k0 + ty + i) * N + n0 + tx];
  __syncthreads();
#pragma unroll
  for (int i = 0; i < 32; i += 8) Wt[(size_t)(n0 + ty + i) * K + k0 + tx] = (f16)tile[tx][ty + i];
}

// ---------------- diagnostic fill ------------------------------------------
__global__ void fill_k(float* p, int n, float v) {
  const int i = blockIdx.x * 256 + threadIdx.x;
  if (i < n) p[i] = v;
}

// ---------------- Phase A: per-(bh,chunk) WY transform ---------------------
// A = strict_tril(diag(beta) K K^T); T = (I+A)^-1 via 16x16 block inversion;
// w = (T diag(beta)) K ; u = (T diag(beta)) V ; P = tril(Q K^T).
DEV f4 mm16(const f16* A, int as, const f16* B, f4 c, int l15, int l4) {
  // block product M1 * M2^T: A = rows of M1 (stride as), B = rows of M2 (stride 20)
  h4 a = *(const h4*)(A + l15 * as + l4 * 4);
  h4 b = *(const h4*)(B + l15 * 20 + l4 * 4);
  return __builtin_amdgcn_mfma_f32_16x16x16f16(a, b, c, 0, 0, 0);
}
DEV void wr_T(f16* slot, f4 acc, int l15, int l4, float sgn) {  // transposed store [col][row]
  h4 v = {(f16)(sgn * acc[0]), (f16)(sgn * acc[1]), (f16)(sgn * acc[2]), (f16)(sgn * acc[3])};
  *(h4*)(slot + l15 * 20 + l4 * 4) = v;
}
DEV void wr_Tb(f16* Tb, int bi, int bj, f4 acc, const float* betas, int l15, int l4, float sgn) {
  const float bc = betas[bj * 16 + l15];
#pragma unroll
  for (int q = 0; q < 4; ++q)
    Tb[(bi * 16 + l4 * 4 + q) * 72 + bj * 16 + l15] = (f16)(sgn * acc[q] * bc);
}

__global__ __launch_bounds__(256) void phaseA(const f16* __restrict__ kb, const f16* __restrict__ qb,
                                              const f16* __restrict__ vb, const float* __restrict__ beta,
                                              f16* __restrict__ wbuf, f16* __restrict__ ubuf,
                                              f16* __restrict__ pbuf) {
  const int blk = blockIdx.x;
  const int c = blk >> 5, bh = blk & 31;
  const int b = bh >> 3, h = bh & 7;
  const int tid = threadIdx.x, lane = tid & 63, wv = tid >> 6;
  const int l15 = lane & 15, l4 = lane >> 4;

  __shared__ __align__(16) f16 Ks[64 * 128];
  __shared__ __align__(16) f16 QVs[64 * 128];    // Q for P, then V
  __shared__ __align__(16) f16 Abuf[64 * 68];
  __shared__ __align__(16) f16 Dr[4][16 * 20];   // diag-block inverses, row-major
  __shared__ __align__(16) f16 Dt[4][16 * 20];   // transposed
  __shared__ __align__(16) f16 Tp[3][16 * 20];   // T'_10, T'_21, T'_20 (transposed)
  __shared__ __align__(16) f16 Xp[3][16 * 20];   // scratch (transposed)
  __shared__ __align__(16) f16 Tb[64 * 72];      // T * diag(beta), row-major
  __shared__ float betas[64];

  const size_t rowstr = (size_t)Bb_ * Dd;
  const size_t gbase = ((size_t)(c * 64) * Bb_ + b) * Dd + h * 128;

#pragma unroll
  for (int i = 0; i < 4; ++i) {
    const int ch = tid + i * 256;
    const int rr = ch >> 4, kc = ch & 15;  // 64 rows x 16 chunks (128 cols)
    *(h8*)(Ks + ch * 8) = *(const h8*)(kb + gbase + (size_t)rr * rowstr + kc * 8);
    *(h8*)(QVs + ch * 8) = *(const h8*)(qb + gbase + (size_t)rr * rowstr + kc * 8);
  }
  for (int i = tid; i < 64 * 72; i += 256) Tb[i] = (f16)0.f;
  if (tid < 64) betas[tid] = beta[((size_t)(c * 64 + tid) * Bb_ + b) * Hh + h];
  __syncthreads();

  // ---- S = K K^T (beta-scaled strict tril -> Abuf), P = tril(Q K^T) -> global
  f4 accS[4] = {}, accP[4] = {};
  const int arow = wv * 16 + l15;
  const int koff = l4 * 8;
#pragma unroll
  for (int kc = 0; kc < 4; ++kc) {
    const h8 aK = *(const h8*)(Ks + arow * 128 + kc * 32 + koff);
    const h8 aQ = *(const h8*)(QVs + arow * 128 + kc * 32 + koff);
#pragma unroll
    for (int f = 0; f < 4; ++f) {
      const h8 bK = *(const h8*)(Ks + (f * 16 + l15) * 128 + kc * 32 + koff);
      accS[f] = __builtin_amdgcn_mfma_f32_16x16x32_f16(aK, bK, accS[f], 0, 0, 0);
      accP[f] = __builtin_amdgcn_mfma_f32_16x16x32_f16(aQ, bK, accP[f], 0, 0, 0);
    }
  }
  const size_t pbase = (((size_t)bh * NC + c) * 64) * 64;
#pragma unroll
  for (int f = 0; f < 4; ++f) {
#pragma unroll
    for (int q = 0; q < 4; ++q) {
      const int i = wv * 16 + l4 * 4 + q;
      const int j = f * 16 + l15;
      Abuf[i * 68 + j] = (f16)((j < i) ? betas[i] * accS[f][q] : 0.f);
      pbuf[pbase + (size_t)i * 64 + j] = (f16)((j <= i) ? accP[f][q] : 0.f);
    }
  }
  __syncthreads();

  // ---- stage V into QVs (Q dead) ----
#pragma unroll
  for (int i = 0; i < 4; ++i) {
    const int ch = tid + i * 256;
    const int rr = ch >> 4, kc = ch & 15;
    *(h8*)(QVs + ch * 8) = *(const h8*)(vb + gbase + (size_t)rr * rowstr + kc * 8);
  }

  // ---- diag 16x16 inverses: wave wv handles block bi=wv; lane c owns col ----
  {
    const int bi = wv;
    const int cc = l15;
    const f16* Ad = Abuf + (bi * 16) * 68 + bi * 16;
    float t[16];
    t[0] = (cc == 0) ? 1.f : 0.f;
#pragma unroll
    for (int i = 1; i < 16; ++i) {
      float s = (cc == i) ? 1.f : 0.f;
#pragma unroll
      for (int j = 0; j < i; ++j) s -= (float)Ad[i * 68 + j] * t[j];
      t[i] = s;
    }
    if (lane < 16) {
#pragma unroll
      for (int j4 = 0; j4 < 4; ++j4) {
        h4 v = {(f16)t[j4 * 4], (f16)t[j4 * 4 + 1], (f16)t[j4 * 4 + 2], (f16)t[j4 * 4 + 3]};
        *(h4*)(&Dt[bi][cc * 20 + j4 * 4]) = v;
      }
      const float bc = betas[bi * 16 + cc];
#pragma unroll
      for (int j = 0; j < 16; ++j) {
        Dr[bi][j * 20 + cc] = (f16)t[j];
        Tb[(bi * 16 + j) * 72 + bi * 16 + cc] = (f16)(t[j] * bc);
      }
    }
  }
  __syncthreads();

  const f16* AB10 = Abuf + 16 * 68 + 0;
  const f16* AB20 = Abuf + 32 * 68 + 0;
  const f16* AB21 = Abuf + 32 * 68 + 16;
  const f16* AB30 = Abuf + 48 * 68 + 0;
  const f16* AB31 = Abuf + 48 * 68 + 16;
  const f16* AB32 = Abuf + 48 * 68 + 32;
  f4 z = {};
  f4 x20, x30;

  // L1: X_10=A_10 D_0 (w0), X_21=A_21 D_1 (w1), X_32=A_32 D_2 (w2), X_20=A_20 D_0 (w3 regs)
  if (wv == 0) wr_T(Xp[0], mm16(AB10, 68, Dt[0], z, l15, l4), l15, l4, 1.f);
  if (wv == 1) wr_T(Xp[1], mm16(AB21, 68, Dt[1], z, l15, l4), l15, l4, 1.f);
  if (wv == 2) wr_T(Xp[2], mm16(AB32, 68, Dt[2], z, l15, l4), l15, l4, 1.f);
  if (wv == 3) x20 = mm16(AB20, 68, Dt[0], z, l15, l4);
  __syncthreads();
  // L2: T_10=-D_1 X_10 (w0), T_21=-D_2 X_21 (w1), T_32=-D_3 X_32 (w2), X_30=A_30 D_0 (w3)
  if (wv == 0) { f4 r = mm16(Dr[1], 20, Xp[0], z, l15, l4); wr_T(Tp[0], r, l15, l4, -1.f); wr_Tb(Tb, 1, 0, r, betas, l15, l4, -1.f); }
  if (wv == 1) { f4 r = mm16(Dr[2], 20, Xp[1], z, l15, l4); wr_T(Tp[1], r, l15, l4, -1.f); wr_Tb(Tb, 2, 1, r, betas, l15, l4, -1.f); }
  if (wv == 2) { f4 r = mm16(Dr[3], 20, Xp[2], z, l15, l4); wr_Tb(Tb, 3, 2, r, betas, l15, l4, -1.f); }
  if (wv == 3) x30 = mm16(AB30, 68, Dt[0], z, l15, l4);
  __syncthreads();
  // L3: Y_20 = X_20 + A_21 T_10 (w3); Y_31 = A_31 D_1 + A_32 T_21 (w1)
  if (wv == 3) wr_T(Xp[0], mm16(AB21, 68, Tp[0], x20, l15, l4), l15, l4, 1.f);
  if (wv == 1) { f4 r = mm16(AB31, 68, Dt[1], z, l15, l4); r = mm16(AB32, 68, Tp[1], r, l15, l4); wr_T(Xp[1], r, l15, l4, 1.f); }
  __syncthreads();
  // L4: T_20 = -D_2 Y_20 (w3); T_31 = -D_3 Y_31 (w1)
  if (wv == 3) { f4 r = mm16(Dr[2], 20, Xp[0], z, l15, l4); wr_T(Tp[2], r, l15, l4, -1.f); wr_Tb(Tb, 2, 0, r, betas, l15, l4, -1.f); }
  if (wv == 1) { f4 r = mm16(Dr[3], 20, Xp[1], z, l15, l4); wr_Tb(Tb, 3, 1, r, betas, l15, l4, -1.f); }
  __syncthreads();
  // L5: Y_30 = X_30 + A_31 T_10 + A_32 T_20 (w3)
  if (wv == 3) { f4 r = mm16(AB31, 68, Tp[0], x30, l15, l4); r = mm16(AB32, 68, Tp[2], r, l15, l4); wr_T(Xp[2], r, l15, l4, 1.f); }
  __syncthreads();
  // L6: T_30 = -D_3 Y_30 (w3)
  if (wv == 3) { f4 r = mm16(Dr[3], 20, Xp[2], z, l15, l4); wr_Tb(Tb, 3, 0, r, betas, l15, l4, -1.f); }
  __syncthreads();

  // ---- w = Tb K, u = Tb V : 64x128x64 MFMA, b-frags gathered (K^T/V^T) ----
  const size_t wub = ((size_t)bh * Tt + c * 64) * 128;
  f4 wacc[8] = {}, uacc[8] = {};
#pragma unroll
  for (int kc = 0; kc < 2; ++kc) {
    const h8 aT = *(const h8*)(Tb + (wv * 16 + l15) * 72 + kc * 32 + koff);
#pragma unroll
    for (int f = 0; f < 8; ++f) {
      h8 bK, bV;
#pragma unroll
      for (int j = 0; j < 8; ++j) {
        const int t2 = kc * 32 + koff + j;
        const int d = f * 16 + l15;
        bK[j] = Ks[t2 * 128 + d];
        bV[j] = QVs[t2 * 128 + d];
      }
      wacc[f] = __builtin_amdgcn_mfma_f32_16x16x32_f16(aT, bK, wacc[f], 0, 0, 0);
      uacc[f] = __builtin_amdgcn_mfma_f32_16x16x32_f16(aT, bV, uacc[f], 0, 0, 0);
    }
  }
#pragma unroll
  for (int f = 0; f < 8; ++f)
#pragma unroll
    for (int q = 0; q < 4; ++q) {
      const int i = wv * 16 + l4 * 4 + q;
      const int d = f * 16 + l15;
      wbuf[wub + (size_t)i * 128 + d] = (f16)wacc[f][q];
      ubuf[wub + (size_t)i * 128 + d] = (f16)uacc[f][q];
    }
}

// ---------------- Phase B: sequential chunk recurrence ---------------------
__global__ __launch_bounds__(256) void phaseB(const f16* __restrict__ qb, const f16* __restrict__ kb,
                                              const f16* __restrict__ wbuf, const f16* __restrict__ ubuf,
                                              const f16* __restrict__ pbuf, float* __restrict__ obuf) {
  const int blk = blockIdx.x;  // bh*4 + g
  const int bh = blk >> 2, g = blk & 3;
  const int b = bh >> 3, h = bh & 7;
  const int tid = threadIdx.x, lane = tid & 63, wv = tid >> 6;
  const int l15 = lane & 15, l4 = lane >> 4;

  __shared__ __align__(16) f16 Ws[64 * 128];
  __shared__ __align__(16) f16 Qs[64 * 128];
  __shared__ __align__(16) f16 Ks[64 * 128];
  __shared__ __align__(16) f16 Ps[64 * 64];
  __shared__ __align__(16) f16 Rt[32 * 72];   // R^T, padded rows
  __shared__ __align__(16) f16 Ms[32 * 136];  // M = S^T (f16 export), padded rows

  for (int i = tid; i < 32 * 136; i += 256) Ms[i] = (f16)0.f;
  f4 macc[2][2] = {};  // persistent f32 state frags

  const size_t rowstr = (size_t)Bb_ * Dd;
  const size_t qk0 = (size_t)b * Dd + h * 128;
  const int arow = wv * 16 + l15;
  const int koff = l4 * 8;
  __syncthreads();

  for (int c = 0; c < NC; ++c) {
    const size_t wub = ((size_t)bh * Tt + c * 64) * 128;
    const size_t pbase = (((size_t)bh * NC + c) * 64) * 64;
#pragma unroll
    for (int i = 0; i < 4; ++i) {
      const int ch = tid + i * 256;
      const int rr = ch >> 4, kc = ch & 15;  // 64 rows x 16 chunks (128 cols)
      *(h8*)(Ws + ch * 8) = *(const h8*)(wbuf + wub + ch * 8);
      *(h8*)(Qs + ch * 8) = *(const h8*)(qb + qk0 + (size_t)(c * 64 + rr) * rowstr + kc * 8);
      *(h8*)(Ks + ch * 8) = *(const h8*)(kb + qk0 + (size_t)(c * 64 + rr) * rowstr + kc * 8);
    }
#pragma unroll
    for (int i = 0; i < 2; ++i) {
      const int ch = tid + i * 256;
      *(h8*)(Ps + ch * 8) = *(const h8*)(pbuf + pbase + ch * 8);
    }
    __syncthreads();

    // phase1: accR = w@S (then R = u - accR), accO = Q@S
    f4 accR[2] = {}, accO[2] = {};
#pragma unroll
    for (int kc = 0; kc < 4; ++kc) {
      const h8 aW = *(const h8*)(Ws + arow * 128 + kc * 32 + koff);
      const h8 aQ = *(const h8*)(Qs + arow * 128 + kc * 32 + koff);
#pragma unroll
      for (int f = 0; f < 2; ++f) {
        const h8 bM = *(const h8*)(Ms + (f * 16 + l15) * 136 + kc * 32 + koff);
        accR[f] = __builtin_amdgcn_mfma_f32_16x16x32_f16(aW, bM, accR[f], 0, 0, 0);
        accO[f] = __builtin_amdgcn_mfma_f32_16x16x32_f16(aQ, bM, accO[f], 0, 0, 0);
      }
    }
#pragma unroll
    for (int f = 0; f < 2; ++f) {
#pragma unroll
      for (int q = 0; q < 4; ++q) {
        const int i = wv * 16 + l4 * 4 + q;
        const int cc = f * 16 + l15;
        const float uv = (float)ubuf[wub + (size_t)i * 128 + g * 32 + cc];
        const float rv = uv - accR[f][q];
        accR[f][q] = rv;
        Rt[cc * 72 + i] = (f16)rv;
      }
    }
    __syncthreads();

    // phase2: accO += P@R ; store O ; M += R^T K ; export Ms
#pragma unroll
    for (int kc = 0; kc < 2; ++kc) {
      const h8 aP = *(const h8*)(Ps + arow * 64 + kc * 32 + koff);
#pragma unroll
      for (int f = 0; f < 2; ++f) {
        const h8 bR = *(const h8*)(Rt + (f * 16 + l15) * 72 + kc * 32 + koff);
        accO[f] = __builtin_amdgcn_mfma_f32_16x16x32_f16(aP, bR, accO[f], 0, 0, 0);
      }
    }
#pragma unroll
    for (int f = 0; f < 2; ++f)
#pragma unroll
      for (int q = 0; q < 4; ++q) {
        const int i = wv * 16 + l4 * 4 + q;
        const int cc = f * 16 + l15;
        obuf[((size_t)(c * 64 + i) * Bb_ + b) * Dd + h * 128 + g * 32 + cc] = accO[f][q];
      }

#pragma unroll
    for (int kc = 0; kc < 2; ++kc) {
      const h8 aR0 = *(const h8*)(Rt + l15 * 72 + kc * 32 + koff);
      const h8 aR1 = *(const h8*)(Rt + (16 + l15) * 72 + kc * 32 + koff);
#pragma unroll
      for (int cf = 0; cf < 2; ++cf) {
        const int kcol = wv * 32 + cf * 16 + l15;
        h8 bKv;
#pragma unroll
        for (int j = 0; j < 8; ++j) bKv[j] = Ks[(kc * 32 + koff + j) * 128 + kcol];
        macc[0][cf] = __builtin_amdgcn_mfma_f32_16x16x32_f16(aR0, bKv, macc[0][cf], 0, 0, 0);
        macc[1][cf] = __builtin_amdgcn_mfma_f32_16x16x32_f16(aR1, bKv, macc[1][cf], 0, 0, 0);
      }
    }
#pragma unroll
    for (int rf = 0; rf < 2; ++rf)
#pragma unroll
      for (int cf = 0; cf < 2; ++cf)
#pragma unroll
        for (int q = 0; q < 4; ++q) {
          const int cr = rf * 16 + l4 * 4 + q;
          const int kcol = wv * 32 + cf * 16 + l15;
          Ms[cr * 136 + kcol] = (f16)macc[rf][cf][q];
        }
    __syncthreads();
  }
}

// ---------------------------------------------------------------------------
extern "C" void kernel_launch(void* const* d_in, const int* in_sizes, int n_in,
                              void* d_out, int out_size, void* d_ws, size_t ws_size,
                              hipStream_t stream) {
  (void)in_sizes; (void)n_in;
  const float* input = (const float*)d_in[0];
  const float* Wq = (const float*)d_in[1];
  const float* Wk = (const float*)d_in[2];
  const float* Wv = (const float*)d_in[3];
  const float* Wb = (const float*)d_in[4];
  const float* Wo = (const float*)d_in[5];
  const float* onw = (const float*)d_in[6];
  const float* n1w = (const float*)d_in[7];
  const float* n2w = (const float*)d_in[8];
  const float* Wg = (const float*)d_in[9];
  const float* Wd = (const float*)d_in[10];
  const float* fnw = (const float*)d_in[11];

  char* ws = (char*)d_ws;
  size_t off = 0;
  auto alloc = [&](size_t bytes) { void* p = ws + off; off += (bytes + 255) & ~(size_t)255; return p; };
  const size_t RD = 8192ull * 1024ull;                 // rows x D elements
  float* x    = (float*)alloc(RD * 4);                 // 32 MiB, residual stream [T,B,D]
  f16*  hb    = (f16*)alloc(RD * 2);                   // 16 MiB
  f16*  qb    = (f16*)alloc(RD * 2);                   // 16 MiB  (qb/kbuf/vbuf contiguous;
  f16*  kbuf  = (f16*)alloc(RD * 2);                   //          reused as `my` [8192,2816] f16)
  f16*  vbuf  = (f16*)alloc(RD * 2);
  float* beta = (float*)alloc(8192ull * 8 * 4);
  f16*  wbuf  = (f16*)alloc(RD * 2);                   // 16 MiB (reused as ob after phaseB)
  f16*  ubuf  = (f16*)alloc(RD * 2);                   // 16 MiB
  f16*  pbuf  = (f16*)alloc(32ull * 32 * 64 * 64 * 2); // 8 MiB
  char* arena = (char*)alloc(3 * RD * 2);              // 48 MiB union: {qraw,kraw,vraw}|{obuf}|{Y}
  f16*  WqT   = (f16*)alloc(1024ull * 1024 * 2);       // single-layer transposed weights
  f16*  WkT   = (f16*)alloc(1024ull * 1024 * 2);
  f16*  WvT   = (f16*)alloc(1024ull * 1024 * 2);
  f16*  WoT   = (f16*)alloc(1024ull * 1024 * 2);
  f16*  WgT   = (f16*)alloc(5632ull * 1024 * 2);
  f16*  WdT   = (f16*)alloc(1024ull * 2816 * 2);
  if (off > ws_size) {  // diagnostic: huge sentinel so this failure mode is unambiguous
    fill_k<<<(out_size + 255) / 256, 256, 0, stream>>>((float*)d_out, out_size, 1.0e6f);
    return;
  }
  f16* qraw = (f16*)arena;
  f16* kraw = qraw + RD;
  f16* vraw = kraw + RD;
  float* obuf = (float*)arena;
  f16* Ybuf = (f16*)arena;
  f16* my = qb;      // 44 MiB into the 48 MiB qb/kbuf/vbuf region (dead by then)
  f16* ob = wbuf;    // wbuf dead after phaseB

  hipMemcpyAsync(x, input, RD * 4, hipMemcpyDeviceToDevice, stream);

  for (int l = 0; l < 2; ++l) {
    const size_t o2 = (size_t)l * 1024 * 1024;
    transpose_k<<<dim3(32, 32), 256, 0, stream>>>(Wq + o2, WqT, 1024, 1024);
    transpose_k<<<dim3(32, 32), 256, 0, stream>>>(Wk + o2, WkT, 1024, 1024);
    transpose_k<<<dim3(32, 32), 256, 0, stream>>>(Wv + o2, WvT, 1024, 1024);
    transpose_k<<<dim3(32, 32), 256, 0, stream>>>(Wo + o2, WoT, 1024, 1024);
    transpose_k<<<dim3(176, 32), 256, 0, stream>>>(Wg + (size_t)l * 1024 * 5632, WgT, 1024, 5632);
    transpose_k<<<dim3(32, 88), 256, 0, stream>>>(Wd + (size_t)l * 2816 * 1024, WdT, 2816, 1024);

    rmsnorm_k<1><<<8192, 256, 0, stream>>>(x, n1w + l * 1024, hb);
    gemm_bt<2><<<dim3(8, 64), 256, 0, stream>>>(hb, WqT, qraw, nullptr, 8192, 1024, 1024);
    gemm_bt<2><<<dim3(8, 64), 256, 0, stream>>>(hb, WkT, kraw, nullptr, 8192, 1024, 1024);
    gemm_bt<2><<<dim3(8, 64), 256, 0, stream>>>(hb, WvT, vraw, nullptr, 8192, 1024, 1024);
    beta_k<<<8192, 256, 0, stream>>>(hb, Wb + (size_t)l * 1024 * 8, beta);
    qkv_epi<<<8192, 256, 0, stream>>>(qraw, kraw, vraw, qb, kbuf, vbuf);
    phaseA<<<1024, 256, 0, stream>>>(kbuf, qb, vbuf, beta, wbuf, ubuf, pbuf);
    phaseB<<<128, 256, 0, stream>>>(qb, kbuf, wbuf, ubuf, pbuf, obuf);
    onorm_k<<<8192, 256, 0, stream>>>(obuf, onw + l * 128, ob);
    gemm_bt<1><<<dim3(8, 64), 256, 0, stream>>>(ob, WoT, x, nullptr, 8192, 1024, 1024);

    rmsnorm_k<1><<<8192, 256, 0, stream>>>(x, n2w + l * 1024, hb);
    // y half first (cols 2816..5632 of Wg), then g half with fused GLU epilogue
    gemm_bt<2><<<dim3(22, 64), 256, 0, stream>>>(hb, WgT + 2816ull * 1024, Ybuf, nullptr, 8192, 2816, 1024);
    gemm_bt<3><<<dim3(22, 64), 256, 0, stream>>>(hb, WgT, my, Ybuf, 8192, 2816, 1024);
    gemm_bt<1><<<dim3(8, 64), 256, 0, stream>>>(my, WdT, x, nullptr, 8192, 1024, 2816);
  }
  rmsnorm_k<0><<<8192, 256, 0, stream>>>(x, fnw, d_out);
}

// Round 5
// 1255.250 us; speedup vs baseline: 1.3711x; 1.1394x over previous
//
#include <hip/hip_runtime.h>
#include <hip/hip_bf16.h>
#include <cstdint>

// DeltaNet forward, MI355X. Round 5: beta_k rewrite -> wave-per-row vectorized
// GEMV (was 127us scalar-load latency-bound; predict ~5us).

typedef _Float16 f16;
typedef __attribute__((ext_vector_type(8))) _Float16 h8;
typedef __attribute__((ext_vector_type(4))) _Float16 h4;
typedef __attribute__((ext_vector_type(4))) float f4;

#define DEV __device__ __forceinline__

static constexpr int Bb_ = 4;     // batch
static constexpr int Hh  = 8;     // heads
static constexpr int Dd  = 1024;  // hidden
static constexpr int Tt  = 2048;  // seq
static constexpr int NC  = 32;    // chunks (T/64)

DEV float siluf(float x) { return x / (1.f + expf(-x)); }

#define AS1(p) ((const __attribute__((address_space(1))) void*)(uintptr_t)(p))
#define AS3(p) ((__attribute__((address_space(3))) void*)(uint32_t)(uintptr_t)(p))

// ---------------- GEMM: C[M,N] (+)= A[M,K] * Bt[N,K]^T, f16 in --------------
// EPI 0: f32 store; 1: f32 +=; 2: f16 store; 3: f16 glu store silu(acc)*Y
template<int EPI>
__global__ __launch_bounds__(256) void gemm_bt(const f16* __restrict__ A, const f16* __restrict__ Bt,
                                               void* __restrict__ C, const f16* __restrict__ Yp,
                                               int M, int N, int K) {
  __shared__ __align__(16) f16 As[128 * 64];
  __shared__ __align__(16) f16 Bs[128 * 64];
  const int tid = threadIdx.x, lane = tid & 63, wv = tid >> 6;
  const int l15 = lane & 15, l4 = lane >> 4;
  const int wrow = (wv & 1) << 6, wcol = (wv >> 1) << 6;
  const size_t bx = blockIdx.x, by = blockIdx.y;
  const f16* Ab = A + by * 128 * (size_t)K;
  const f16* Bb = Bt + bx * 128 * (size_t)K;
  f4 acc[4][4] = {};
  for (int kt = 0; kt < K; kt += 64) {
#pragma unroll
    for (int i = 0; i < 4; ++i) {
      const int ch = tid + i * 256;        // 1024 chunks of 16B per tile
      const int rr = ch >> 3, kc = ch & 7; // 128 rows x 8 chunks (64 cols)
      __builtin_amdgcn_global_load_lds(AS1(Ab + (size_t)rr * K + kt + kc * 8), AS3(As + ch * 8), 16, 0, 0);
      __builtin_amdgcn_global_load_lds(AS1(Bb + (size_t)rr * K + kt + kc * 8), AS3(Bs + ch * 8), 16, 0, 0);
    }
    __syncthreads();
#pragma unroll
    for (int ks = 0; ks < 2; ++ks) {
      h8 a[4], b[4];
#pragma unroll
      for (int r = 0; r < 4; ++r) a[r] = *(const h8*)(As + (wrow + r * 16 + l15) * 64 + ks * 32 + l4 * 8);
#pragma unroll
      for (int c = 0; c < 4; ++c) b[c] = *(const h8*)(Bs + (wcol + c * 16 + l15) * 64 + ks * 32 + l4 * 8);
#pragma unroll
      for (int r = 0; r < 4; ++r)
#pragma unroll
        for (int c = 0; c < 4; ++c)
          acc[r][c] = __builtin_amdgcn_mfma_f32_16x16x32_f16(a[r], b[c], acc[r][c], 0, 0, 0);
    }
    __syncthreads();
  }
#pragma unroll
  for (int r = 0; r < 4; ++r) {
#pragma unroll
    for (int c = 0; c < 4; ++c) {
      const int row0 = (int)by * 128 + wrow + r * 16 + l4 * 4;
      const int col = (int)bx * 128 + wcol + c * 16 + l15;
#pragma unroll
      for (int q = 0; q < 4; ++q) {
        size_t idx = (size_t)(row0 + q) * N + col;
        float v = acc[r][c][q];
        if (EPI == 0) ((float*)C)[idx] = v;
        if (EPI == 1) ((float*)C)[idx] += v;
        if (EPI == 2) ((f16*)C)[idx] = (f16)v;
        if (EPI == 3) ((f16*)C)[idx] = (f16)(siluf(v) * (float)Yp[idx]);
      }
    }
  }
}

// ---------------- RMSNorm over D=1024 ------------------------------------
template<int OUT_F16>
__global__ __launch_bounds__(256) void rmsnorm_k(const float* __restrict__ x, const float* __restrict__ w,
                                                 void* __restrict__ out) {
  const int r = blockIdx.x, tid = threadIdx.x;
  const float4 v = *(const float4*)(x + (size_t)r * 1024 + tid * 4);
  float ss = v.x * v.x + v.y * v.y + v.z * v.z + v.w * v.w;
#pragma unroll
  for (int m = 1; m < 64; m <<= 1) ss += __shfl_xor(ss, m);
  __shared__ float red[4];
  if ((tid & 63) == 0) red[tid >> 6] = ss;
  __syncthreads();
  const float scale = rsqrtf((red[0] + red[1] + red[2] + red[3]) * (1.f / 1024.f) + 1e-6f);
  const float4 w4 = *(const float4*)(w + tid * 4);
  float o0 = v.x * scale * w4.x, o1 = v.y * scale * w4.y, o2 = v.z * scale * w4.z, o3 = v.w * scale * w4.w;
  if (OUT_F16) {
    h4 o = {(f16)o0, (f16)o1, (f16)o2, (f16)o3};
    *(h4*)((f16*)out + (size_t)r * 1024 + tid * 4) = o;
  } else {
    *(float4*)((float*)out + (size_t)r * 1024 + tid * 4) = make_float4(o0, o1, o2, o3);
  }
}

// ---------------- silu + per-head l2norm for q,k; silu for v ---------------
__global__ __launch_bounds__(256) void qkv_epi(const f16* __restrict__ qraw, const f16* __restrict__ kraw,
                                               const f16* __restrict__ vraw, f16* __restrict__ qb,
                                               f16* __restrict__ kb, f16* __restrict__ vb) {
  const int r = blockIdx.x, tid = threadIdx.x;
  const int head = tid >> 5, l32 = tid & 31;
  const size_t base = (size_t)r * 1024 + head * 128 + l32 * 4;
  {
    const h4 v = *(const h4*)(qraw + base);
    float s0 = siluf((float)v[0]), s1 = siluf((float)v[1]), s2 = siluf((float)v[2]), s3 = siluf((float)v[3]);
    float ss = s0 * s0 + s1 * s1 + s2 * s2 + s3 * s3;
#pragma unroll
    for (int m = 1; m <= 16; m <<= 1) ss += __shfl_xor(ss, m);
    const float sc = rsqrtf(ss + 1e-6f);
    h4 o = {(f16)(s0 * sc), (f16)(s1 * sc), (f16)(s2 * sc), (f16)(s3 * sc)};
    *(h4*)(qb + base) = o;
  }
  {
    const h4 v = *(const h4*)(kraw + base);
    float s0 = siluf((float)v[0]), s1 = siluf((float)v[1]), s2 = siluf((float)v[2]), s3 = siluf((float)v[3]);
    float ss = s0 * s0 + s1 * s1 + s2 * s2 + s3 * s3;
#pragma unroll
    for (int m = 1; m <= 16; m <<= 1) ss += __shfl_xor(ss, m);
    const float sc = rsqrtf(ss + 1e-6f);
    h4 o = {(f16)(s0 * sc), (f16)(s1 * sc), (f16)(s2 * sc), (f16)(s3 * sc)};
    *(h4*)(kb + base) = o;
  }
  {
    const size_t b2 = (size_t)r * 1024 + tid * 4;
    const h4 v = *(const h4*)(vraw + b2);
    h4 o = {(f16)siluf((float)v[0]), (f16)siluf((float)v[1]), (f16)siluf((float)v[2]), (f16)siluf((float)v[3])};
    *(h4*)(vb + b2) = o;
  }
}

// ---------------- per-head RMSNorm (DV=128) with shared weight -------------
__global__ __launch_bounds__(256) void onorm_k(const float* __restrict__ o, const float* __restrict__ w,
                                               f16* __restrict__ ob) {
  const int r = blockIdx.x, tid = threadIdx.x;
  const int head = tid >> 5, l32 = tid & 31;
  const size_t base = (size_t)r * 1024 + head * 128 + l32 * 4;
  const float4 v = *(const float4*)(o + base);
  float ss = v.x * v.x + v.y * v.y + v.z * v.z + v.w * v.w;
#pragma unroll
  for (int m = 1; m <= 16; m <<= 1) ss += __shfl_xor(ss, m);
  const float sc = rsqrtf(ss * (1.f / 128.f) + 1e-6f);
  const float4 w4 = *(const float4*)(w + l32 * 4);
  h4 out = {(f16)(v.x * sc * w4.x), (f16)(v.y * sc * w4.y), (f16)(v.z * sc * w4.z), (f16)(v.w * sc * w4.w)};
  *(h4*)(ob + base) = out;
}

// ---------------- beta = 2*sigmoid(h @ Wb), wave-per-row GEMV --------------
__global__ __launch_bounds__(256) void beta_k(const f16* __restrict__ hb, const float* __restrict__ Wb,
                                              float* __restrict__ beta) {
  const int tid = threadIdx.x, lane = tid & 63, wv = tid >> 6;
  const int r = blockIdx.x * 4 + wv;
  const f16* row = hb + (size_t)r * 1024 + lane * 16;
  const h8 v0 = *(const h8*)(row);
  const h8 v1 = *(const h8*)(row + 8);
  const float* wb = Wb + (size_t)(lane * 16) * 8;
  float acc[8] = {};
#pragma unroll
  for (int e = 0; e < 8; ++e) {
    const float x0 = (float)v0[e], x1 = (float)v1[e];
    const float4 w0a = *(const float4*)(wb + e * 8);
    const float4 w0b = *(const float4*)(wb + e * 8 + 4);
    const float4 w1a = *(const float4*)(wb + (e + 8) * 8);
    const float4 w1b = *(const float4*)(wb + (e + 8) * 8 + 4);
    acc[0] += x0 * w0a.x + x1 * w1a.x;  acc[1] += x0 * w0a.y + x1 * w1a.y;
    acc[2] += x0 * w0a.z + x1 * w1a.z;  acc[3] += x0 * w0a.w + x1 * w1a.w;
    acc[4] += x0 * w0b.x + x1 * w1b.x;  acc[5] += x0 * w0b.y + x1 * w1b.y;
    acc[6] += x0 * w0b.z + x1 * w1b.z;  acc[7] += x0 * w0b.w + x1 * w1b.w;
  }
#pragma unroll
  for (int j = 0; j < 8; ++j)
#pragma unroll
    for (int m = 1; m < 64; m <<= 1) acc[j] += __shfl_xor(acc[j], m);
  if (lane == 0) {
#pragma unroll
    for (int j = 0; j < 8; ++j) beta[(size_t)r * 8 + j] = 2.f / (1.f + expf(-acc[j]));
  }
}

// ---------------- W[K][N] f32 -> Wt[N][K] f16 ------------------------------
__global__ __launch_bounds__(256) void transpose_k(const float* __restrict__ W, f16* __restrict__ Wt,
                                                   int K, int N) {
  __shared__ float tile[32][33];
  const int n0 = blockIdx.x * 32, k0 = blockIdx.y * 32;
  const int tx = threadIdx.x & 31, ty = threadIdx.x >> 5;
#pragma unroll
  for (int i = 0; i < 32; i += 8) tile[ty + i][tx] = W[(size_t)(k0 + ty + i) * N + n0 + tx];
  __syncthreads();
#pragma unroll
  for (int i = 0; i < 32; i += 8) Wt[(size_t)(n0 + ty + i) * K + k0 + tx] = (f16)tile[tx][ty + i];
}

// ---------------- diagnostic fill ------------------------------------------
__global__ void fill_k(float* p, int n, float v) {
  const int i = blockIdx.x * 256 + threadIdx.x;
  if (i < n) p[i] = v;
}

// ---------------- Phase A: per-(bh,chunk) WY transform ---------------------
// A = strict_tril(diag(beta) K K^T); T = (I+A)^-1 via 16x16 block inversion;
// w = (T diag(beta)) K ; u = (T diag(beta)) V ; P = tril(Q K^T).
DEV f4 mm16(const f16* A, int as, const f16* B, f4 c, int l15, int l4) {
  // block product M1 * M2^T: A = rows of M1 (stride as), B = rows of M2 (stride 20)
  h4 a = *(const h4*)(A + l15 * as + l4 * 4);
  h4 b = *(const h4*)(B + l15 * 20 + l4 * 4);
  return __builtin_amdgcn_mfma_f32_16x16x16f16(a, b, c, 0, 0, 0);
}
DEV void wr_T(f16* slot, f4 acc, int l15, int l4, float sgn) {  // transposed store [col][row]
  h4 v = {(f16)(sgn * acc[0]), (f16)(sgn * acc[1]), (f16)(sgn * acc[2]), (f16)(sgn * acc[3])};
  *(h4*)(slot + l15 * 20 + l4 * 4) = v;
}
DEV void wr_Tb(f16* Tb, int bi, int bj, f4 acc, const float* betas, int l15, int l4, float sgn) {
  const float bc = betas[bj * 16 + l15];
#pragma unroll
  for (int q = 0; q < 4; ++q)
    Tb[(bi * 16 + l4 * 4 + q) * 72 + bj * 16 + l15] = (f16)(sgn * acc[q] * bc);
}

__global__ __launch_bounds__(256) void phaseA(const f16* __restrict__ kb, const f16* __restrict__ qb,
                                              const f16* __restrict__ vb, const float* __restrict__ beta,
                                              f16* __restrict__ wbuf, f16* __restrict__ ubuf,
                                              f16* __restrict__ pbuf) {
  const int blk = blockIdx.x;
  const int c = blk >> 5, bh = blk & 31;
  const int b = bh >> 3, h = bh & 7;
  const int tid = threadIdx.x, lane = tid & 63, wv = tid >> 6;
  const int l15 = lane & 15, l4 = lane >> 4;

  __shared__ __align__(16) f16 Ks[64 * 128];
  __shared__ __align__(16) f16 QVs[64 * 128];    // Q for P, then V
  __shared__ __align__(16) f16 Abuf[64 * 68];
  __shared__ __align__(16) f16 Dr[4][16 * 20];   // diag-block inverses, row-major
  __shared__ __align__(16) f16 Dt[4][16 * 20];   // transposed
  __shared__ __align__(16) f16 Tp[3][16 * 20];   // T'_10, T'_21, T'_20 (transposed)
  __shared__ __align__(16) f16 Xp[3][16 * 20];   // scratch (transposed)
  __shared__ __align__(16) f16 Tb[64 * 72];      // T * diag(beta), row-major
  __shared__ float betas[64];

  const size_t rowstr = (size_t)Bb_ * Dd;
  const size_t gbase = ((size_t)(c * 64) * Bb_ + b) * Dd + h * 128;

#pragma unroll
  for (int i = 0; i < 4; ++i) {
    const int ch = tid + i * 256;
    const int rr = ch >> 4, kc = ch & 15;  // 64 rows x 16 chunks (128 cols)
    *(h8*)(Ks + ch * 8) = *(const h8*)(kb + gbase + (size_t)rr * rowstr + kc * 8);
    *(h8*)(QVs + ch * 8) = *(const h8*)(qb + gbase + (size_t)rr * rowstr + kc * 8);
  }
  for (int i = tid; i < 64 * 72; i += 256) Tb[i] = (f16)0.f;
  if (tid < 64) betas[tid] = beta[((size_t)(c * 64 + tid) * Bb_ + b) * Hh + h];
  __syncthreads();

  // ---- S = K K^T (beta-scaled strict tril -> Abuf), P = tril(Q K^T) -> global
  f4 accS[4] = {}, accP[4] = {};
  const int arow = wv * 16 + l15;
  const int koff = l4 * 8;
#pragma unroll
  for (int kc = 0; kc < 4; ++kc) {
    const h8 aK = *(const h8*)(Ks + arow * 128 + kc * 32 + koff);
    const h8 aQ = *(const h8*)(QVs + arow * 128 + kc * 32 + koff);
#pragma unroll
    for (int f = 0; f < 4; ++f) {
      const h8 bK = *(const h8*)(Ks + (f * 16 + l15) * 128 + kc * 32 + koff);
      accS[f] = __builtin_amdgcn_mfma_f32_16x16x32_f16(aK, bK, accS[f], 0, 0, 0);
      accP[f] = __builtin_amdgcn_mfma_f32_16x16x32_f16(aQ, bK, accP[f], 0, 0, 0);
    }
  }
  const size_t pbase = (((size_t)bh * NC + c) * 64) * 64;
#pragma unroll
  for (int f = 0; f < 4; ++f) {
#pragma unroll
    for (int q = 0; q < 4; ++q) {
      const int i = wv * 16 + l4 * 4 + q;
      const int j = f * 16 + l15;
      Abuf[i * 68 + j] = (f16)((j < i) ? betas[i] * accS[f][q] : 0.f);
      pbuf[pbase + (size_t)i * 64 + j] = (f16)((j <= i) ? accP[f][q] : 0.f);
    }
  }
  __syncthreads();

  // ---- stage V into QVs (Q dead) ----
#pragma unroll
  for (int i = 0; i < 4; ++i) {
    const int ch = tid + i * 256;
    const int rr = ch >> 4, kc = ch & 15;
    *(h8*)(QVs + ch * 8) = *(const h8*)(vb + gbase + (size_t)rr * rowstr + kc * 8);
  }

  // ---- diag 16x16 inverses: wave wv handles block bi=wv; lane c owns col ----
  {
    const int bi = wv;
    const int cc = l15;
    const f16* Ad = Abuf + (bi * 16) * 68 + bi * 16;
    float t[16];
    t[0] = (cc == 0) ? 1.f : 0.f;
#pragma unroll
    for (int i = 1; i < 16; ++i) {
      float s = (cc == i) ? 1.f : 0.f;
#pragma unroll
      for (int j = 0; j < i; ++j) s -= (float)Ad[i * 68 + j] * t[j];
      t[i] = s;
    }
    if (lane < 16) {
#pragma unroll
      for (int j4 = 0; j4 < 4; ++j4) {
        h4 v = {(f16)t[j4 * 4], (f16)t[j4 * 4 + 1], (f16)t[j4 * 4 + 2], (f16)t[j4 * 4 + 3]};
        *(h4*)(&Dt[bi][cc * 20 + j4 * 4]) = v;
      }
      const float bc = betas[bi * 16 + cc];
#pragma unroll
      for (int j = 0; j < 16; ++j) {
        Dr[bi][j * 20 + cc] = (f16)t[j];
        Tb[(bi * 16 + j) * 72 + bi * 16 + cc] = (f16)(t[j] * bc);
      }
    }
  }
  __syncthreads();

  const f16* AB10 = Abuf + 16 * 68 + 0;
  const f16* AB20 = Abuf + 32 * 68 + 0;
  const f16* AB21 = Abuf + 32 * 68 + 16;
  const f16* AB30 = Abuf + 48 * 68 + 0;
  const f16* AB31 = Abuf + 48 * 68 + 16;
  const f16* AB32 = Abuf + 48 * 68 + 32;
  f4 z = {};
  f4 x20, x30;

  // L1: X_10=A_10 D_0 (w0), X_21=A_21 D_1 (w1), X_32=A_32 D_2 (w2), X_20=A_20 D_0 (w3 regs)
  if (wv == 0) wr_T(Xp[0], mm16(AB10, 68, Dt[0], z, l15, l4), l15, l4, 1.f);
  if (wv == 1) wr_T(Xp[1], mm16(AB21, 68, Dt[1], z, l15, l4), l15, l4, 1.f);
  if (wv == 2) wr_T(Xp[2], mm16(AB32, 68, Dt[2], z, l15, l4), l15, l4, 1.f);
  if (wv == 3) x20 = mm16(AB20, 68, Dt[0], z, l15, l4);
  __syncthreads();
  // L2: T_10=-D_1 X_10 (w0), T_21=-D_2 X_21 (w1), T_32=-D_3 X_32 (w2), X_30=A_30 D_0 (w3)
  if (wv == 0) { f4 r = mm16(Dr[1], 20, Xp[0], z, l15, l4); wr_T(Tp[0], r, l15, l4, -1.f); wr_Tb(Tb, 1, 0, r, betas, l15, l4, -1.f); }
  if (wv == 1) { f4 r = mm16(Dr[2], 20, Xp[1], z, l15, l4); wr_T(Tp[1], r, l15, l4, -1.f); wr_Tb(Tb, 2, 1, r, betas, l15, l4, -1.f); }
  if (wv == 2) { f4 r = mm16(Dr[3], 20, Xp[2], z, l15, l4); wr_Tb(Tb, 3, 2, r, betas, l15, l4, -1.f); }
  if (wv == 3) x30 = mm16(AB30, 68, Dt[0], z, l15, l4);
  __syncthreads();
  // L3: Y_20 = X_20 + A_21 T_10 (w3); Y_31 = A_31 D_1 + A_32 T_21 (w1)
  if (wv == 3) wr_T(Xp[0], mm16(AB21, 68, Tp[0], x20, l15, l4), l15, l4, 1.f);
  if (wv == 1) { f4 r = mm16(AB31, 68, Dt[1], z, l15, l4); r = mm16(AB32, 68, Tp[1], r, l15, l4); wr_T(Xp[1], r, l15, l4, 1.f); }
  __syncthreads();
  // L4: T_20 = -D_2 Y_20 (w3); T_31 = -D_3 Y_31 (w1)
  if (wv == 3) { f4 r = mm16(Dr[2], 20, Xp[0], z, l15, l4); wr_T(Tp[2], r, l15, l4, -1.f); wr_Tb(Tb, 2, 0, r, betas, l15, l4, -1.f); }
  if (wv == 1) { f4 r = mm16(Dr[3], 20, Xp[1], z, l15, l4); wr_Tb(Tb, 3, 1, r, betas, l15, l4, -1.f); }
  __syncthreads();
  // L5: Y_30 = X_30 + A_31 T_10 + A_32 T_20 (w3)
  if (wv == 3) { f4 r = mm16(AB31, 68, Tp[0], x30, l15, l4); r = mm16(AB32, 68, Tp[2], r, l15, l4); wr_T(Xp[2], r, l15, l4, 1.f); }
  __syncthreads();
  // L6: T_30 = -D_3 Y_30 (w3)
  if (wv == 3) { f4 r = mm16(Dr[3], 20, Xp[2], z, l15, l4); wr_Tb(Tb, 3, 0, r, betas, l15, l4, -1.f); }
  __syncthreads();

  // ---- w = Tb K, u = Tb V : 64x128x64 MFMA, b-frags gathered (K^T/V^T) ----
  const size_t wub = ((size_t)bh * Tt + c * 64) * 128;
  f4 wacc[8] = {}, uacc[8] = {};
#pragma unroll
  for (int kc = 0; kc < 2; ++kc) {
    const h8 aT = *(const h8*)(Tb + (wv * 16 + l15) * 72 + kc * 32 + koff);
#pragma unroll
    for (int f = 0; f < 8; ++f) {
      h8 bK, bV;
#pragma unroll
      for (int j = 0; j < 8; ++j) {
        const int t2 = kc * 32 + koff + j;
        const int d = f * 16 + l15;
        bK[j] = Ks[t2 * 128 + d];
        bV[j] = QVs[t2 * 128 + d];
      }
      wacc[f] = __builtin_amdgcn_mfma_f32_16x16x32_f16(aT, bK, wacc[f], 0, 0, 0);
      uacc[f] = __builtin_amdgcn_mfma_f32_16x16x32_f16(aT, bV, uacc[f], 0, 0, 0);
    }
  }
#pragma unroll
  for (int f = 0; f < 8; ++f)
#pragma unroll
    for (int q = 0; q < 4; ++q) {
      const int i = wv * 16 + l4 * 4 + q;
      const int d = f * 16 + l15;
      wbuf[wub + (size_t)i * 128 + d] = (f16)wacc[f][q];
      ubuf[wub + (size_t)i * 128 + d] = (f16)uacc[f][q];
    }
}

// ---------------- Phase B: sequential chunk recurrence ---------------------
__global__ __launch_bounds__(256) void phaseB(const f16* __restrict__ qb, const f16* __restrict__ kb,
                                              const f16* __restrict__ wbuf, const f16* __restrict__ ubuf,
                                              const f16* __restrict__ pbuf, float* __restrict__ obuf) {
  const int blk = blockIdx.x;  // bh*4 + g
  const int bh = blk >> 2, g = blk & 3;
  const int b = bh >> 3, h = bh & 7;
  const int tid = threadIdx.x, lane = tid & 63, wv = tid >> 6;
  const int l15 = lane & 15, l4 = lane >> 4;

  __shared__ __align__(16) f16 Ws[64 * 128];
  __shared__ __align__(16) f16 Qs[64 * 128];
  __shared__ __align__(16) f16 Ks[64 * 128];
  __shared__ __align__(16) f16 Ps[64 * 64];
  __shared__ __align__(16) f16 Rt[32 * 72];   // R^T, padded rows
  __shared__ __align__(16) f16 Ms[32 * 136];  // M = S^T (f16 export), padded rows

  for (int i = tid; i < 32 * 136; i += 256) Ms[i] = (f16)0.f;
  f4 macc[2][2] = {};  // persistent f32 state frags

  const size_t rowstr = (size_t)Bb_ * Dd;
  const size_t qk0 = (size_t)b * Dd + h * 128;
  const int arow = wv * 16 + l15;
  const int koff = l4 * 8;
  __syncthreads();

  for (int c = 0; c < NC; ++c) {
    const size_t wub = ((size_t)bh * Tt + c * 64) * 128;
    const size_t pbase = (((size_t)bh * NC + c) * 64) * 64;
#pragma unroll
    for (int i = 0; i < 4; ++i) {
      const int ch = tid + i * 256;
      const int rr = ch >> 4, kc = ch & 15;  // 64 rows x 16 chunks (128 cols)
      *(h8*)(Ws + ch * 8) = *(const h8*)(wbuf + wub + ch * 8);
      *(h8*)(Qs + ch * 8) = *(const h8*)(qb + qk0 + (size_t)(c * 64 + rr) * rowstr + kc * 8);
      *(h8*)(Ks + ch * 8) = *(const h8*)(kb + qk0 + (size_t)(c * 64 + rr) * rowstr + kc * 8);
    }
#pragma unroll
    for (int i = 0; i < 2; ++i) {
      const int ch = tid + i * 256;
      *(h8*)(Ps + ch * 8) = *(const h8*)(pbuf + pbase + ch * 8);
    }
    __syncthreads();

    // phase1: accR = w@S (then R = u - accR), accO = Q@S
    f4 accR[2] = {}, accO[2] = {};
#pragma unroll
    for (int kc = 0; kc < 4; ++kc) {
      const h8 aW = *(const h8*)(Ws + arow * 128 + kc * 32 + koff);
      const h8 aQ = *(const h8*)(Qs + arow * 128 + kc * 32 + koff);
#pragma unroll
      for (int f = 0; f < 2; ++f) {
        const h8 bM = *(const h8*)(Ms + (f * 16 + l15) * 136 + kc * 32 + koff);
        accR[f] = __builtin_amdgcn_mfma_f32_16x16x32_f16(aW, bM, accR[f], 0, 0, 0);
        accO[f] = __builtin_amdgcn_mfma_f32_16x16x32_f16(aQ, bM, accO[f], 0, 0, 0);
      }
    }
#pragma unroll
    for (int f = 0; f < 2; ++f) {
#pragma unroll
      for (int q = 0; q < 4; ++q) {
        const int i = wv * 16 + l4 * 4 + q;
        const int cc = f * 16 + l15;
        const float uv = (float)ubuf[wub + (size_t)i * 128 + g * 32 + cc];
        const float rv = uv - accR[f][q];
        accR[f][q] = rv;
        Rt[cc * 72 + i] = (f16)rv;
      }
    }
    __syncthreads();

    // phase2: accO += P@R ; store O ; M += R^T K ; export Ms
#pragma unroll
    for (int kc = 0; kc < 2; ++kc) {
      const h8 aP = *(const h8*)(Ps + arow * 64 + kc * 32 + koff);
#pragma unroll
      for (int f = 0; f < 2; ++f) {
        const h8 bR = *(const h8*)(Rt + (f * 16 + l15) * 72 + kc * 32 + koff);
        accO[f] = __builtin_amdgcn_mfma_f32_16x16x32_f16(aP, bR, accO[f], 0, 0, 0);
      }
    }
#pragma unroll
    for (int f = 0; f < 2; ++f)
#pragma unroll
      for (int q = 0; q < 4; ++q) {
        const int i = wv * 16 + l4 * 4 + q;
        const int cc = f * 16 + l15;
        obuf[((size_t)(c * 64 + i) * Bb_ + b) * Dd + h * 128 + g * 32 + cc] = accO[f][q];
      }

#pragma unroll
    for (int kc = 0; kc < 2; ++kc) {
      const h8 aR0 = *(const h8*)(Rt + l15 * 72 + kc * 32 + koff);
      const h8 aR1 = *(const h8*)(Rt + (16 + l15) * 72 + kc * 32 + koff);
#pragma unroll
      for (int cf = 0; cf < 2; ++cf) {
        const int kcol = wv * 32 + cf * 16 + l15;
        h8 bKv;
#pragma unroll
        for (int j = 0; j < 8; ++j) bKv[j] = Ks[(kc * 32 + koff + j) * 128 + kcol];
        macc[0][cf] = __builtin_amdgcn_mfma_f32_16x16x32_f16(aR0, bKv, macc[0][cf], 0, 0, 0);
        macc[1][cf] = __builtin_amdgcn_mfma_f32_16x16x32_f16(aR1, bKv, macc[1][cf], 0, 0, 0);
      }
    }
#pragma unroll
    for (int rf = 0; rf < 2; ++rf)
#pragma unroll
      for (int cf = 0; cf < 2; ++cf)
#pragma unroll
        for (int q = 0; q < 4; ++q) {
          const int cr = rf * 16 + l4 * 4 + q;
          const int kcol = wv * 32 + cf * 16 + l15;
          Ms[cr * 136 + kcol] = (f16)macc[rf][cf][q];
        }
    __syncthreads();
  }
}

// ---------------------------------------------------------------------------
extern "C" void kernel_launch(void* const* d_in, const int* in_sizes, int n_in,
                              void* d_out, int out_size, void* d_ws, size_t ws_size,
                              hipStream_t stream) {
  (void)in_sizes; (void)n_in;
  const float* input = (const float*)d_in[0];
  const float* Wq = (const float*)d_in[1];
  const float* Wk = (const float*)d_in[2];
  const float* Wv = (const float*)d_in[3];
  const float* Wb = (const float*)d_in[4];
  const float* Wo = (const float*)d_in[5];
  const float* onw = (const float*)d_in[6];
  const float* n1w = (const float*)d_in[7];
  const float* n2w = (const float*)d_in[8];
  const float* Wg = (const float*)d_in[9];
  const float* Wd = (const float*)d_in[10];
  const float* fnw = (const float*)d_in[11];

  char* ws = (char*)d_ws;
  size_t off = 0;
  auto alloc = [&](size_t bytes) { void* p = ws + off; off += (bytes + 255) & ~(size_t)255; return p; };
  const size_t RD = 8192ull * 1024ull;                 // rows x D elements
  float* x    = (float*)alloc(RD * 4);                 // 32 MiB, residual stream [T,B,D]
  f16*  hb    = (f16*)alloc(RD * 2);                   // 16 MiB
  f16*  qb    = (f16*)alloc(RD * 2);                   // 16 MiB  (qb/kbuf/vbuf contiguous;
  f16*  kbuf  = (f16*)alloc(RD * 2);                   //          reused as `my` [8192,2816] f16)
  f16*  vbuf  = (f16*)alloc(RD * 2);
  float* beta = (float*)alloc(8192ull * 8 * 4);
  f16*  wbuf  = (f16*)alloc(RD * 2);                   // 16 MiB (reused as ob after phaseB)
  f16*  ubuf  = (f16*)alloc(RD * 2);                   // 16 MiB
  f16*  pbuf  = (f16*)alloc(32ull * 32 * 64 * 64 * 2); // 8 MiB
  char* arena = (char*)alloc(3 * RD * 2);              // 48 MiB union: {qraw,kraw,vraw}|{obuf}|{Y}
  f16*  WqT   = (f16*)alloc(1024ull * 1024 * 2);       // single-layer transposed weights
  f16*  WkT   = (f16*)alloc(1024ull * 1024 * 2);
  f16*  WvT   = (f16*)alloc(1024ull * 1024 * 2);
  f16*  WoT   = (f16*)alloc(1024ull * 1024 * 2);
  f16*  WgT   = (f16*)alloc(5632ull * 1024 * 2);
  f16*  WdT   = (f16*)alloc(1024ull * 2816 * 2);
  if (off > ws_size) {  // diagnostic: huge sentinel so this failure mode is unambiguous
    fill_k<<<(out_size + 255) / 256, 256, 0, stream>>>((float*)d_out, out_size, 1.0e6f);
    return;
  }
  f16* qraw = (f16*)arena;
  f16* kraw = qraw + RD;
  f16* vraw = kraw + RD;
  float* obuf = (float*)arena;
  f16* Ybuf = (f16*)arena;
  f16* my = qb;      // 44 MiB into the 48 MiB qb/kbuf/vbuf region (dead by then)
  f16* ob = wbuf;    // wbuf dead after phaseB

  hipMemcpyAsync(x, input, RD * 4, hipMemcpyDeviceToDevice, stream);

  for (int l = 0; l < 2; ++l) {
    const size_t o2 = (size_t)l * 1024 * 1024;
    transpose_k<<<dim3(32, 32), 256, 0, stream>>>(Wq + o2, WqT, 1024, 1024);
    transpose_k<<<dim3(32, 32), 256, 0, stream>>>(Wk + o2, WkT, 1024, 1024);
    transpose_k<<<dim3(32, 32), 256, 0, stream>>>(Wv + o2, WvT, 1024, 1024);
    transpose_k<<<dim3(32, 32), 256, 0, stream>>>(Wo + o2, WoT, 1024, 1024);
    transpose_k<<<dim3(176, 32), 256, 0, stream>>>(Wg + (size_t)l * 1024 * 5632, WgT, 1024, 5632);
    transpose_k<<<dim3(32, 88), 256, 0, stream>>>(Wd + (size_t)l * 2816 * 1024, WdT, 2816, 1024);

    rmsnorm_k<1><<<8192, 256, 0, stream>>>(x, n1w + l * 1024, hb);
    gemm_bt<2><<<dim3(8, 64), 256, 0, stream>>>(hb, WqT, qraw, nullptr, 8192, 1024, 1024);
    gemm_bt<2><<<dim3(8, 64), 256, 0, stream>>>(hb, WkT, kraw, nullptr, 8192, 1024, 1024);
    gemm_bt<2><<<dim3(8, 64), 256, 0, stream>>>(hb, WvT, vraw, nullptr, 8192, 1024, 1024);
    beta_k<<<2048, 256, 0, stream>>>(hb, Wb + (size_t)l * 1024 * 8, beta);
    qkv_epi<<<8192, 256, 0, stream>>>(qraw, kraw, vraw, qb, kbuf, vbuf);
    phaseA<<<1024, 256, 0, stream>>>(kbuf, qb, vbuf, beta, wbuf, ubuf, pbuf);
    phaseB<<<128, 256, 0, stream>>>(qb, kbuf, wbuf, ubuf, pbuf, obuf);
    onorm_k<<<8192, 256, 0, stream>>>(obuf, onw + l * 128, ob);
    gemm_bt<1><<<dim3(8, 64), 256, 0, stream>>>(ob, WoT, x, nullptr, 8192, 1024, 1024);

    rmsnorm_k<1><<<8192, 256, 0, stream>>>(x, n2w + l * 1024, hb);
    // y half first (cols 2816..5632 of Wg), then g half with fused GLU epilogue
    gemm_bt<2><<<dim3(22, 64), 256, 0, stream>>>(hb, WgT + 2816ull * 1024, Ybuf, nullptr, 8192, 2816, 1024);
    gemm_bt<3><<<dim3(22, 64), 256, 0, stream>>>(hb, WgT, my, Ybuf, 8192, 2816, 1024);
    gemm_bt<1><<<dim3(8, 64), 256, 0, stream>>>(my, WdT, x, nullptr, 8192, 1024, 2816);
  }
  rmsnorm_k<0><<<8192, 256, 0, stream>>>(x, fnw, d_out);
}

// Round 6
// 1251.594 us; speedup vs baseline: 1.3751x; 1.0029x over previous
//
#include <hip/hip_runtime.h>
#include <hip/hip_bf16.h>
#include <cstdint>

// DeltaNet forward, MI355X. Round 6: 256x256 8-phase GEMM (T2 swizzle + T3/T4
// counted vmcnt + T5 setprio + T1 xcd swizzle), fused QKV GEMM.

typedef _Float16 f16;
typedef __attribute__((ext_vector_type(8))) _Float16 h8;
typedef __attribute__((ext_vector_type(4))) _Float16 h4;
typedef __attribute__((ext_vector_type(4))) float f4;

#define DEV __device__ __forceinline__

static constexpr int Bb_ = 4;     // batch
static constexpr int Hh  = 8;     // heads
static constexpr int Dd  = 1024;  // hidden
static constexpr int Tt  = 2048;  // seq
static constexpr int NC  = 32;    // chunks (T/64)

DEV float siluf(float x) { return x / (1.f + expf(-x)); }

#define AS1(p) ((const __attribute__((address_space(1))) void*)(uintptr_t)(p))
#define AS3(p) ((__attribute__((address_space(3))) void*)(uint32_t)(uintptr_t)(p))

// ================= 256x256 8-phase GEMM: C[M,N] op= A[M,K]*Bt[N,K]^T ========
// EPI 0: f32 store; 1: f32 +=; 2: f16 store; 3: f16 glu store silu(acc)*Y
// LDS tiles [256][64] f16, 16B-chunk swizzle: chunk_store = chunk ^ (row&7).
// Stage: linear LDS dest (global_load_lds) + pre-swizzled global source.
DEV void stage_half(const f16* __restrict__ srcRowBase, int K, int kt,
                    f16* dstHalf, int tid) {
#pragma unroll
  for (int i = 0; i < 2; ++i) {
    const int q = i * 512 + tid;        // chunk 0..1023 (128 rows x 8 chunks)
    const int r = q >> 3, cs = q & 7;
    const int cl = cs ^ (r & 7);        // inverse swizzle on source
    __builtin_amdgcn_global_load_lds(AS1(srcRowBase + (size_t)r * K + kt * 64 + cl * 8),
                                     AS3(dstHalf + q * 8), 16, 0, 0);
  }
}
DEV h8 rd_sw(const f16* T, int row, int chunk) {  // swizzled ds_read_b128
  return *(const h8*)(T + (((row << 3) | (chunk ^ (row & 7))) * 8));
}

template<int EPI>
__global__ __launch_bounds__(512, 2) void gemm256(const f16* __restrict__ A, const f16* __restrict__ Bt,
                                                  void* __restrict__ C, const f16* __restrict__ Yp,
                                                  int M, int N, int K, int gx) {
  __shared__ __align__(16) f16 ldsA[2][16384];   // [buf][256*64]
  __shared__ __align__(16) f16 ldsB[2][16384];
  const int tid = threadIdx.x, lane = tid & 63, w = tid >> 6;
  const int l15 = lane & 15, l4 = lane >> 4;
  const int wr = w >> 2, wc = w & 3;             // 2M x 4N waves
  // XCD-aware bijective block swizzle (grid % 8 == 0 for all our shapes)
  const int nwg = gridDim.x;
  int flat = blockIdx.x;
  if ((nwg & 7) == 0) flat = (flat & 7) * (nwg >> 3) + (flat >> 3);
  const int bx = flat % gx, by = flat / gx;

  const f16* Ab = A + (size_t)by * 256 * K;
  const f16* Bb = Bt + (size_t)bx * 256 * K;
  const int NT = K >> 6;
  f4 acc[8][4] = {};

  // ---- prologue: tile0 all halves -> buf0; tile1 B halves -> buf1 ----
  stage_half(Bb, K, 0, ldsB[0], tid);
  stage_half(Bb + (size_t)128 * K, K, 0, ldsB[0] + 8192, tid);
  stage_half(Ab, K, 0, ldsA[0], tid);
  stage_half(Ab + (size_t)128 * K, K, 0, ldsA[0] + 8192, tid);
  if (NT > 1) {
    stage_half(Bb, K, 1, ldsB[1], tid);
    stage_half(Bb + (size_t)128 * K, K, 1, ldsB[1] + 8192, tid);
    asm volatile("s_waitcnt vmcnt(4)");
  } else {
    asm volatile("s_waitcnt vmcnt(0)");
  }
  __builtin_amdgcn_s_barrier();

  for (int t = 0; t < NT; ++t) {
    const int cur = t & 1, nxt = cur ^ 1;
    const f16* cA = ldsA[cur];
    const f16* cB = ldsB[cur];
    h8 b[4][2];
    h8 a[2][2];
    // ---------- phase 0: read all B-frags (regs) + A quadrant 0 ----------
#pragma unroll
    for (int cf = 0; cf < 4; ++cf)
#pragma unroll
      for (int ks = 0; ks < 2; ++ks)
        b[cf][ks] = rd_sw(cB, wc * 64 + cf * 16 + l15, ks * 4 + l4);
#pragma unroll
    for (int fr = 0; fr < 2; ++fr)
#pragma unroll
      for (int ks = 0; ks < 2; ++ks)
        a[fr][ks] = rd_sw(cA, wr * 128 + fr * 16 + l15, ks * 4 + l4);
    if (t + 1 < NT) stage_half(Ab, K, t + 1, ldsA[nxt], tid);
    __builtin_amdgcn_s_barrier();
    asm volatile("s_waitcnt lgkmcnt(0)");
    __builtin_amdgcn_s_setprio(1);
#pragma unroll
    for (int fr = 0; fr < 2; ++fr)
#pragma unroll
      for (int cf = 0; cf < 4; ++cf)
#pragma unroll
        for (int ks = 0; ks < 2; ++ks)
          acc[fr][cf] = __builtin_amdgcn_mfma_f32_16x16x32_f16(a[fr][ks], b[cf][ks], acc[fr][cf], 0, 0, 0);
    __builtin_amdgcn_s_setprio(0);
    __builtin_amdgcn_s_barrier();
    // ---------- phases 1..3 ----------
#pragma unroll
    for (int p = 1; p < 4; ++p) {
#pragma unroll
      for (int fr = 0; fr < 2; ++fr)
#pragma unroll
        for (int ks = 0; ks < 2; ++ks)
          a[fr][ks] = rd_sw(cA, wr * 128 + p * 32 + fr * 16 + l15, ks * 4 + l4);
      if (p == 1 && t + 1 < NT) stage_half(Ab + (size_t)128 * K, K, t + 1, ldsA[nxt] + 8192, tid);
      if (p == 2 && t + 2 < NT) stage_half(Bb, K, t + 2, ldsB[cur], tid);
      if (p == 3 && t + 2 < NT) stage_half(Bb + (size_t)128 * K, K, t + 2, ldsB[cur] + 8192, tid);
      __builtin_amdgcn_s_barrier();
      asm volatile("s_waitcnt lgkmcnt(0)");
      __builtin_amdgcn_s_setprio(1);
#pragma unroll
      for (int fr = 0; fr < 2; ++fr)
#pragma unroll
        for (int cf = 0; cf < 4; ++cf)
#pragma unroll
          for (int ks = 0; ks < 2; ++ks)
            acc[p * 2 + fr][cf] = __builtin_amdgcn_mfma_f32_16x16x32_f16(a[fr][ks], b[cf][ks], acc[p * 2 + fr][cf], 0, 0, 0);
      __builtin_amdgcn_s_setprio(0);
      if (p == 3) {
        if (t + 2 < NT) asm volatile("s_waitcnt vmcnt(4)");
        else if (t + 1 < NT) asm volatile("s_waitcnt vmcnt(0)");
      }
      __builtin_amdgcn_s_barrier();
    }
  }

  // ---- epilogue ----
#pragma unroll
  for (int fr = 0; fr < 8; ++fr) {
#pragma unroll
    for (int cf = 0; cf < 4; ++cf) {
      const int row0 = by * 256 + wr * 128 + fr * 16 + l4 * 4;
      const int col = bx * 256 + wc * 64 + cf * 16 + l15;
#pragma unroll
      for (int q = 0; q < 4; ++q) {
        const size_t idx = (size_t)(row0 + q) * N + col;
        const float v = acc[fr][cf][q];
        if (EPI == 0) ((float*)C)[idx] = v;
        if (EPI == 1) ((float*)C)[idx] += v;
        if (EPI == 2) ((f16*)C)[idx] = (f16)v;
        if (EPI == 3) ((f16*)C)[idx] = (f16)(siluf(v) * (float)Yp[idx]);
      }
    }
  }
}

// ---------------- RMSNorm over D=1024 ------------------------------------
template<int OUT_F16>
__global__ __launch_bounds__(256) void rmsnorm_k(const float* __restrict__ x, const float* __restrict__ w,
                                                 void* __restrict__ out) {
  const int r = blockIdx.x, tid = threadIdx.x;
  const float4 v = *(const float4*)(x + (size_t)r * 1024 + tid * 4);
  float ss = v.x * v.x + v.y * v.y + v.z * v.z + v.w * v.w;
#pragma unroll
  for (int m = 1; m < 64; m <<= 1) ss += __shfl_xor(ss, m);
  __shared__ float red[4];
  if ((tid & 63) == 0) red[tid >> 6] = ss;
  __syncthreads();
  const float scale = rsqrtf((red[0] + red[1] + red[2] + red[3]) * (1.f / 1024.f) + 1e-6f);
  const float4 w4 = *(const float4*)(w + tid * 4);
  float o0 = v.x * scale * w4.x, o1 = v.y * scale * w4.y, o2 = v.z * scale * w4.z, o3 = v.w * scale * w4.w;
  if (OUT_F16) {
    h4 o = {(f16)o0, (f16)o1, (f16)o2, (f16)o3};
    *(h4*)((f16*)out + (size_t)r * 1024 + tid * 4) = o;
  } else {
    *(float4*)((float*)out + (size_t)r * 1024 + tid * 4) = make_float4(o0, o1, o2, o3);
  }
}

// ------- silu + per-head l2norm for q,k; silu for v (fused qkv layout) ------
__global__ __launch_bounds__(256) void qkv_epi(const f16* __restrict__ qkv, f16* __restrict__ qb,
                                               f16* __restrict__ kb, f16* __restrict__ vb) {
  const int r = blockIdx.x, tid = threadIdx.x;
  const int head = tid >> 5, l32 = tid & 31;
  const size_t src = (size_t)r * 3072 + head * 128 + l32 * 4;
  const size_t dst = (size_t)r * 1024 + head * 128 + l32 * 4;
  {
    const h4 v = *(const h4*)(qkv + src);
    float s0 = siluf((float)v[0]), s1 = siluf((float)v[1]), s2 = siluf((float)v[2]), s3 = siluf((float)v[3]);
    float ss = s0 * s0 + s1 * s1 + s2 * s2 + s3 * s3;
#pragma unroll
    for (int m = 1; m <= 16; m <<= 1) ss += __shfl_xor(ss, m);
    const float sc = rsqrtf(ss + 1e-6f);
    h4 o = {(f16)(s0 * sc), (f16)(s1 * sc), (f16)(s2 * sc), (f16)(s3 * sc)};
    *(h4*)(qb + dst) = o;
  }
  {
    const h4 v = *(const h4*)(qkv + src + 1024);
    float s0 = siluf((float)v[0]), s1 = siluf((float)v[1]), s2 = siluf((float)v[2]), s3 = siluf((float)v[3]);
    float ss = s0 * s0 + s1 * s1 + s2 * s2 + s3 * s3;
#pragma unroll
    for (int m = 1; m <= 16; m <<= 1) ss += __shfl_xor(ss, m);
    const float sc = rsqrtf(ss + 1e-6f);
    h4 o = {(f16)(s0 * sc), (f16)(s1 * sc), (f16)(s2 * sc), (f16)(s3 * sc)};
    *(h4*)(kb + dst) = o;
  }
  {
    const h4 v = *(const h4*)(qkv + (size_t)r * 3072 + 2048 + tid * 4);
    h4 o = {(f16)siluf((float)v[0]), (f16)siluf((float)v[1]), (f16)siluf((float)v[2]), (f16)siluf((float)v[3])};
    *(h4*)(vb + (size_t)r * 1024 + tid * 4) = o;
  }
}

// ---------------- per-head RMSNorm (DV=128) with shared weight -------------
__global__ __launch_bounds__(256) void onorm_k(const float* __restrict__ o, const float* __restrict__ w,
                                               f16* __restrict__ ob) {
  const int r = blockIdx.x, tid = threadIdx.x;
  const int head = tid >> 5, l32 = tid & 31;
  const size_t base = (size_t)r * 1024 + head * 128 + l32 * 4;
  const float4 v = *(const float4*)(o + base);
  float ss = v.x * v.x + v.y * v.y + v.z * v.z + v.w * v.w;
#pragma unroll
  for (int m = 1; m <= 16; m <<= 1) ss += __shfl_xor(ss, m);
  const float sc = rsqrtf(ss * (1.f / 128.f) + 1e-6f);
  const float4 w4 = *(const float4*)(w + l32 * 4);
  h4 out = {(f16)(v.x * sc * w4.x), (f16)(v.y * sc * w4.y), (f16)(v.z * sc * w4.z), (f16)(v.w * sc * w4.w)};
  *(h4*)(ob + base) = out;
}

// ---------------- beta = 2*sigmoid(h @ Wb), wave-per-row GEMV --------------
__global__ __launch_bounds__(256) void beta_k(const f16* __restrict__ hb, const float* __restrict__ Wb,
                                              float* __restrict__ beta) {
  const int tid = threadIdx.x, lane = tid & 63, wv = tid >> 6;
  const int r = blockIdx.x * 4 + wv;
  const f16* row = hb + (size_t)r * 1024 + lane * 16;
  const h8 v0 = *(const h8*)(row);
  const h8 v1 = *(const h8*)(row + 8);
  const float* wb = Wb + (size_t)(lane * 16) * 8;
  float acc[8] = {};
#pragma unroll
  for (int e = 0; e < 8; ++e) {
    const float x0 = (float)v0[e], x1 = (float)v1[e];
    const float4 w0a = *(const float4*)(wb + e * 8);
    const float4 w0b = *(const float4*)(wb + e * 8 + 4);
    const float4 w1a = *(const float4*)(wb + (e + 8) * 8);
    const float4 w1b = *(const float4*)(wb + (e + 8) * 8 + 4);
    acc[0] += x0 * w0a.x + x1 * w1a.x;  acc[1] += x0 * w0a.y + x1 * w1a.y;
    acc[2] += x0 * w0a.z + x1 * w1a.z;  acc[3] += x0 * w0a.w + x1 * w1a.w;
    acc[4] += x0 * w0b.x + x1 * w1b.x;  acc[5] += x0 * w0b.y + x1 * w1b.y;
    acc[6] += x0 * w0b.z + x1 * w1b.z;  acc[7] += x0 * w0b.w + x1 * w1b.w;
  }
#pragma unroll
  for (int j = 0; j < 8; ++j)
#pragma unroll
    for (int m = 1; m < 64; m <<= 1) acc[j] += __shfl_xor(acc[j], m);
  if (lane == 0) {
#pragma unroll
    for (int j = 0; j < 8; ++j) beta[(size_t)r * 8 + j] = 2.f / (1.f + expf(-acc[j]));
  }
}

// ---------------- W[K][N] f32 -> Wt[N][K] f16 ------------------------------
__global__ __launch_bounds__(256) void transpose_k(const float* __restrict__ W, f16* __restrict__ Wt,
                                                   int K, int N) {
  __shared__ float tile[32][33];
  const int n0 = blockIdx.x * 32, k0 = blockIdx.y * 32;
  const int tx = threadIdx.x & 31, ty = threadIdx.x >> 5;
#pragma unroll
  for (int i = 0; i < 32; i += 8) tile[ty + i][tx] = W[(size_t)(k0 + ty + i) * N + n0 + tx];
  __syncthreads();
#pragma unroll
  for (int i = 0; i < 32; i += 8) Wt[(size_t)(n0 + ty + i) * K + k0 + tx] = (f16)tile[tx][ty + i];
}

// ---------------- diagnostic fill ------------------------------------------
__global__ void fill_k(float* p, int n, float v) {
  const int i = blockIdx.x * 256 + threadIdx.x;
  if (i < n) p[i] = v;
}

// ---------------- Phase A: per-(bh,chunk) WY transform ---------------------
DEV f4 mm16(const f16* A, int as, const f16* B, f4 c, int l15, int l4) {
  h4 a = *(const h4*)(A + l15 * as + l4 * 4);
  h4 b = *(const h4*)(B + l15 * 20 + l4 * 4);
  return __builtin_amdgcn_mfma_f32_16x16x16f16(a, b, c, 0, 0, 0);
}
DEV void wr_T(f16* slot, f4 acc, int l15, int l4, float sgn) {
  h4 v = {(f16)(sgn * acc[0]), (f16)(sgn * acc[1]), (f16)(sgn * acc[2]), (f16)(sgn * acc[3])};
  *(h4*)(slot + l15 * 20 + l4 * 4) = v;
}
DEV void wr_Tb(f16* Tb, int bi, int bj, f4 acc, const float* betas, int l15, int l4, float sgn) {
  const float bc = betas[bj * 16 + l15];
#pragma unroll
  for (int q = 0; q < 4; ++q)
    Tb[(bi * 16 + l4 * 4 + q) * 72 + bj * 16 + l15] = (f16)(sgn * acc[q] * bc);
}

__global__ __launch_bounds__(256) void phaseA(const f16* __restrict__ kb, const f16* __restrict__ qb,
                                              const f16* __restrict__ vb, const float* __restrict__ beta,
                                              f16* __restrict__ wbuf, f16* __restrict__ ubuf,
                                              f16* __restrict__ pbuf) {
  const int blk = blockIdx.x;
  const int c = blk >> 5, bh = blk & 31;
  const int b = bh >> 3, h = bh & 7;
  const int tid = threadIdx.x, lane = tid & 63, wv = tid >> 6;
  const int l15 = lane & 15, l4 = lane >> 4;

  __shared__ __align__(16) f16 Ks[64 * 128];
  __shared__ __align__(16) f16 QVs[64 * 128];
  __shared__ __align__(16) f16 Abuf[64 * 68];
  __shared__ __align__(16) f16 Dr[4][16 * 20];
  __shared__ __align__(16) f16 Dt[4][16 * 20];
  __shared__ __align__(16) f16 Tp[3][16 * 20];
  __shared__ __align__(16) f16 Xp[3][16 * 20];
  __shared__ __align__(16) f16 Tb[64 * 72];
  __shared__ float betas[64];

  const size_t rowstr = (size_t)Bb_ * Dd;
  const size_t gbase = ((size_t)(c * 64) * Bb_ + b) * Dd + h * 128;

#pragma unroll
  for (int i = 0; i < 4; ++i) {
    const int ch = tid + i * 256;
    const int rr = ch >> 4, kc = ch & 15;
    *(h8*)(Ks + ch * 8) = *(const h8*)(kb + gbase + (size_t)rr * rowstr + kc * 8);
    *(h8*)(QVs + ch * 8) = *(const h8*)(qb + gbase + (size_t)rr * rowstr + kc * 8);
  }
  for (int i = tid; i < 64 * 72; i += 256) Tb[i] = (f16)0.f;
  if (tid < 64) betas[tid] = beta[((size_t)(c * 64 + tid) * Bb_ + b) * Hh + h];
  __syncthreads();

  f4 accS[4] = {}, accP[4] = {};
  const int arow = wv * 16 + l15;
  const int koff = l4 * 8;
#pragma unroll
  for (int kc = 0; kc < 4; ++kc) {
    const h8 aK = *(const h8*)(Ks + arow * 128 + kc * 32 + koff);
    const h8 aQ = *(const h8*)(QVs + arow * 128 + kc * 32 + koff);
#pragma unroll
    for (int f = 0; f < 4; ++f) {
      const h8 bK = *(const h8*)(Ks + (f * 16 + l15) * 128 + kc * 32 + koff);
      accS[f] = __builtin_amdgcn_mfma_f32_16x16x32_f16(aK, bK, accS[f], 0, 0, 0);
      accP[f] = __builtin_amdgcn_mfma_f32_16x16x32_f16(aQ, bK, accP[f], 0, 0, 0);
    }
  }
  const size_t pbase = (((size_t)bh * NC + c) * 64) * 64;
#pragma unroll
  for (int f = 0; f < 4; ++f) {
#pragma unroll
    for (int q = 0; q < 4; ++q) {
      const int i = wv * 16 + l4 * 4 + q;
      const int j = f * 16 + l15;
      Abuf[i * 68 + j] = (f16)((j < i) ? betas[i] * accS[f][q] : 0.f);
      pbuf[pbase + (size_t)i * 64 + j] = (f16)((j <= i) ? accP[f][q] : 0.f);
    }
  }
  __syncthreads();

#pragma unroll
  for (int i = 0; i < 4; ++i) {
    const int ch = tid + i * 256;
    const int rr = ch >> 4, kc = ch & 15;
    *(h8*)(QVs + ch * 8) = *(const h8*)(vb + gbase + (size_t)rr * rowstr + kc * 8);
  }

  {
    const int bi = wv;
    const int cc = l15;
    const f16* Ad = Abuf + (bi * 16) * 68 + bi * 16;
    float t[16];
    t[0] = (cc == 0) ? 1.f : 0.f;
#pragma unroll
    for (int i = 1; i < 16; ++i) {
      float s = (cc == i) ? 1.f : 0.f;
#pragma unroll
      for (int j = 0; j < i; ++j) s -= (float)Ad[i * 68 + j] * t[j];
      t[i] = s;
    }
    if (lane < 16) {
#pragma unroll
      for (int j4 = 0; j4 < 4; ++j4) {
        h4 v = {(f16)t[j4 * 4], (f16)t[j4 * 4 + 1], (f16)t[j4 * 4 + 2], (f16)t[j4 * 4 + 3]};
        *(h4*)(&Dt[bi][cc * 20 + j4 * 4]) = v;
      }
      const float bc = betas[bi * 16 + cc];
#pragma unroll
      for (int j = 0; j < 16; ++j) {
        Dr[bi][j * 20 + cc] = (f16)t[j];
        Tb[(bi * 16 + j) * 72 + bi * 16 + cc] = (f16)(t[j] * bc);
      }
    }
  }
  __syncthreads();

  const f16* AB10 = Abuf + 16 * 68 + 0;
  const f16* AB20 = Abuf + 32 * 68 + 0;
  const f16* AB21 = Abuf + 32 * 68 + 16;
  const f16* AB30 = Abuf + 48 * 68 + 0;
  const f16* AB31 = Abuf + 48 * 68 + 16;
  const f16* AB32 = Abuf + 48 * 68 + 32;
  f4 z = {};
  f4 x20, x30;

  if (wv == 0) wr_T(Xp[0], mm16(AB10, 68, Dt[0], z, l15, l4), l15, l4, 1.f);
  if (wv == 1) wr_T(Xp[1], mm16(AB21, 68, Dt[1], z, l15, l4), l15, l4, 1.f);
  if (wv == 2) wr_T(Xp[2], mm16(AB32, 68, Dt[2], z, l15, l4), l15, l4, 1.f);
  if (wv == 3) x20 = mm16(AB20, 68, Dt[0], z, l15, l4);
  __syncthreads();
  if (wv == 0) { f4 r = mm16(Dr[1], 20, Xp[0], z, l15, l4); wr_T(Tp[0], r, l15, l4, -1.f); wr_Tb(Tb, 1, 0, r, betas, l15, l4, -1.f); }
  if (wv == 1) { f4 r = mm16(Dr[2], 20, Xp[1], z, l15, l4); wr_T(Tp[1], r, l15, l4, -1.f); wr_Tb(Tb, 2, 1, r, betas, l15, l4, -1.f); }
  if (wv == 2) { f4 r = mm16(Dr[3], 20, Xp[2], z, l15, l4); wr_Tb(Tb, 3, 2, r, betas, l15, l4, -1.f); }
  if (wv == 3) x30 = mm16(AB30, 68, Dt[0], z, l15, l4);
  __syncthreads();
  if (wv == 3) wr_T(Xp[0], mm16(AB21, 68, Tp[0], x20, l15, l4), l15, l4, 1.f);
  if (wv == 1) { f4 r = mm16(AB31, 68, Dt[1], z, l15, l4); r = mm16(AB32, 68, Tp[1], r, l15, l4); wr_T(Xp[1], r, l15, l4, 1.f); }
  __syncthreads();
  if (wv == 3) { f4 r = mm16(Dr[2], 20, Xp[0], z, l15, l4); wr_T(Tp[2], r, l15, l4, -1.f); wr_Tb(Tb, 2, 0, r, betas, l15, l4, -1.f); }
  if (wv == 1) { f4 r = mm16(Dr[3], 20, Xp[1], z, l15, l4); wr_Tb(Tb, 3, 1, r, betas, l15, l4, -1.f); }
  __syncthreads();
  if (wv == 3) { f4 r = mm16(AB31, 68, Tp[0], x30, l15, l4); r = mm16(AB32, 68, Tp[2], r, l15, l4); wr_T(Xp[2], r, l15, l4, 1.f); }
  __syncthreads();
  if (wv == 3) { f4 r = mm16(Dr[3], 20, Xp[2], z, l15, l4); wr_Tb(Tb, 3, 0, r, betas, l15, l4, -1.f); }
  __syncthreads();

  const size_t wub = ((size_t)bh * Tt + c * 64) * 128;
  f4 wacc[8] = {}, uacc[8] = {};
#pragma unroll
  for (int kc = 0; kc < 2; ++kc) {
    const h8 aT = *(const h8*)(Tb + (wv * 16 + l15) * 72 + kc * 32 + koff);
#pragma unroll
    for (int f = 0; f < 8; ++f) {
      h8 bK, bV;
#pragma unroll
      for (int j = 0; j < 8; ++j) {
        const int t2 = kc * 32 + koff + j;
        const int d = f * 16 + l15;
        bK[j] = Ks[t2 * 128 + d];
        bV[j] = QVs[t2 * 128 + d];
      }
      wacc[f] = __builtin_amdgcn_mfma_f32_16x16x32_f16(aT, bK, wacc[f], 0, 0, 0);
      uacc[f] = __builtin_amdgcn_mfma_f32_16x16x32_f16(aT, bV, uacc[f], 0, 0, 0);
    }
  }
#pragma unroll
  for (int f = 0; f < 8; ++f)
#pragma unroll
    for (int q = 0; q < 4; ++q) {
      const int i = wv * 16 + l4 * 4 + q;
      const int d = f * 16 + l15;
      wbuf[wub + (size_t)i * 128 + d] = (f16)wacc[f][q];
      ubuf[wub + (size_t)i * 128 + d] = (f16)uacc[f][q];
    }
}

// ---------------- Phase B: sequential chunk recurrence ---------------------
__global__ __launch_bounds__(256) void phaseB(const f16* __restrict__ qb, const f16* __restrict__ kb,
                                              const f16* __restrict__ wbuf, const f16* __restrict__ ubuf,
                                              const f16* __restrict__ pbuf, float* __restrict__ obuf) {
  const int blk = blockIdx.x;
  const int bh = blk >> 2, g = blk & 3;
  const int b = bh >> 3, h = bh & 7;
  const int tid = threadIdx.x, lane = tid & 63, wv = tid >> 6;
  const int l15 = lane & 15, l4 = lane >> 4;

  __shared__ __align__(16) f16 Ws[64 * 128];
  __shared__ __align__(16) f16 Qs[64 * 128];
  __shared__ __align__(16) f16 Ks[64 * 128];
  __shared__ __align__(16) f16 Ps[64 * 64];
  __shared__ __align__(16) f16 Rt[32 * 72];
  __shared__ __align__(16) f16 Ms[32 * 136];

  for (int i = tid; i < 32 * 136; i += 256) Ms[i] = (f16)0.f;
  f4 macc[2][2] = {};

  const size_t rowstr = (size_t)Bb_ * Dd;
  const size_t qk0 = (size_t)b * Dd + h * 128;
  const int arow = wv * 16 + l15;
  const int koff = l4 * 8;
  __syncthreads();

  for (int c = 0; c < NC; ++c) {
    const size_t wub = ((size_t)bh * Tt + c * 64) * 128;
    const size_t pbase = (((size_t)bh * NC + c) * 64) * 64;
#pragma unroll
    for (int i = 0; i < 4; ++i) {
      const int ch = tid + i * 256;
      const int rr = ch >> 4, kc = ch & 15;
      *(h8*)(Ws + ch * 8) = *(const h8*)(wbuf + wub + ch * 8);
      *(h8*)(Qs + ch * 8) = *(const h8*)(qb + qk0 + (size_t)(c * 64 + rr) * rowstr + kc * 8);
      *(h8*)(Ks + ch * 8) = *(const h8*)(kb + qk0 + (size_t)(c * 64 + rr) * rowstr + kc * 8);
    }
#pragma unroll
    for (int i = 0; i < 2; ++i) {
      const int ch = tid + i * 256;
      *(h8*)(Ps + ch * 8) = *(const h8*)(pbuf + pbase + ch * 8);
    }
    __syncthreads();

    f4 accR[2] = {}, accO[2] = {};
#pragma unroll
    for (int kc = 0; kc < 4; ++kc) {
      const h8 aW = *(const h8*)(Ws + arow * 128 + kc * 32 + koff);
      const h8 aQ = *(const h8*)(Qs + arow * 128 + kc * 32 + koff);
#pragma unroll
      for (int f = 0; f < 2; ++f) {
        const h8 bM = *(const h8*)(Ms + (f * 16 + l15) * 136 + kc * 32 + koff);
        accR[f] = __builtin_amdgcn_mfma_f32_16x16x32_f16(aW, bM, accR[f], 0, 0, 0);
        accO[f] = __builtin_amdgcn_mfma_f32_16x16x32_f16(aQ, bM, accO[f], 0, 0, 0);
      }
    }
#pragma unroll
    for (int f = 0; f < 2; ++f) {
#pragma unroll
      for (int q = 0; q < 4; ++q) {
        const int i = wv * 16 + l4 * 4 + q;
        const int cc = f * 16 + l15;
        const float uv = (float)ubuf[wub + (size_t)i * 128 + g * 32 + cc];
        const float rv = uv - accR[f][q];
        accR[f][q] = rv;
        Rt[cc * 72 + i] = (f16)rv;
      }
    }
    __syncthreads();

#pragma unroll
    for (int kc = 0; kc < 2; ++kc) {
      const h8 aP = *(const h8*)(Ps + arow * 64 + kc * 32 + koff);
#pragma unroll
      for (int f = 0; f < 2; ++f) {
        const h8 bR = *(const h8*)(Rt + (f * 16 + l15) * 72 + kc * 32 + koff);
        accO[f] = __builtin_amdgcn_mfma_f32_16x16x32_f16(aP, bR, accO[f], 0, 0, 0);
      }
    }
#pragma unroll
    for (int f = 0; f < 2; ++f)
#pragma unroll
      for (int q = 0; q < 4; ++q) {
        const int i = wv * 16 + l4 * 4 + q;
        const int cc = f * 16 + l15;
        obuf[((size_t)(c * 64 + i) * Bb_ + b) * Dd + h * 128 + g * 32 + cc] = accO[f][q];
      }

#pragma unroll
    for (int kc = 0; kc < 2; ++kc) {
      const h8 aR0 = *(const h8*)(Rt + l15 * 72 + kc * 32 + koff);
      const h8 aR1 = *(const h8*)(Rt + (16 + l15) * 72 + kc * 32 + koff);
#pragma unroll
      for (int cf = 0; cf < 2; ++cf) {
        const int kcol = wv * 32 + cf * 16 + l15;
        h8 bKv;
#pragma unroll
        for (int j = 0; j < 8; ++j) bKv[j] = Ks[(kc * 32 + koff + j) * 128 + kcol];
        macc[0][cf] = __builtin_amdgcn_mfma_f32_16x16x32_f16(aR0, bKv, macc[0][cf], 0, 0, 0);
        macc[1][cf] = __builtin_amdgcn_mfma_f32_16x16x32_f16(aR1, bKv, macc[1][cf], 0, 0, 0);
      }
    }
#pragma unroll
    for (int rf = 0; rf < 2; ++rf)
#pragma unroll
      for (int cf = 0; cf < 2; ++cf)
#pragma unroll
        for (int q = 0; q < 4; ++q) {
          const int cr = rf * 16 + l4 * 4 + q;
          const int kcol = wv * 32 + cf * 16 + l15;
          Ms[cr * 136 + kcol] = (f16)macc[rf][cf][q];
        }
    __syncthreads();
  }
}

// ---------------------------------------------------------------------------
extern "C" void kernel_launch(void* const* d_in, const int* in_sizes, int n_in,
                              void* d_out, int out_size, void* d_ws, size_t ws_size,
                              hipStream_t stream) {
  (void)in_sizes; (void)n_in;
  const float* input = (const float*)d_in[0];
  const float* Wq = (const float*)d_in[1];
  const float* Wk = (const float*)d_in[2];
  const float* Wv = (const float*)d_in[3];
  const float* Wb = (const float*)d_in[4];
  const float* Wo = (const float*)d_in[5];
  const float* onw = (const float*)d_in[6];
  const float* n1w = (const float*)d_in[7];
  const float* n2w = (const float*)d_in[8];
  const float* Wg = (const float*)d_in[9];
  const float* Wd = (const float*)d_in[10];
  const float* fnw = (const float*)d_in[11];

  char* ws = (char*)d_ws;
  size_t off = 0;
  auto alloc = [&](size_t bytes) { void* p = ws + off; off += (bytes + 255) & ~(size_t)255; return p; };
  const size_t RD = 8192ull * 1024ull;
  float* x    = (float*)alloc(RD * 4);
  f16*  hb    = (f16*)alloc(RD * 2);
  f16*  qb    = (f16*)alloc(RD * 2);
  f16*  kbuf  = (f16*)alloc(RD * 2);
  f16*  vbuf  = (f16*)alloc(RD * 2);
  float* beta = (float*)alloc(8192ull * 8 * 4);
  f16*  wbuf  = (f16*)alloc(RD * 2);
  f16*  ubuf  = (f16*)alloc(RD * 2);
  f16*  pbuf  = (f16*)alloc(32ull * 32 * 64 * 64 * 2);
  char* arena = (char*)alloc(3 * RD * 2);              // {qkv fused}|{obuf}|{Y}
  f16*  WqkvT = (f16*)alloc(3072ull * 1024 * 2);
  f16*  WoT   = (f16*)alloc(1024ull * 1024 * 2);
  f16*  WgT   = (f16*)alloc(5632ull * 1024 * 2);
  f16*  WdT   = (f16*)alloc(1024ull * 2816 * 2);
  if (off > ws_size) {
    fill_k<<<(out_size + 255) / 256, 256, 0, stream>>>((float*)d_out, out_size, 1.0e6f);
    return;
  }
  f16* qkvraw = (f16*)arena;       // [8192][3072]
  float* obuf = (float*)arena;
  f16* Ybuf = (f16*)arena;         // [8192][2816]
  f16* my = qb;                    // qb/kbuf/vbuf dead by then
  f16* ob = wbuf;                  // wbuf dead after phaseB

  hipMemcpyAsync(x, input, RD * 4, hipMemcpyDeviceToDevice, stream);

  for (int l = 0; l < 2; ++l) {
    const size_t o2 = (size_t)l * 1024 * 1024;
    transpose_k<<<dim3(32, 32), 256, 0, stream>>>(Wq + o2, WqkvT, 1024, 1024);
    transpose_k<<<dim3(32, 32), 256, 0, stream>>>(Wk + o2, WqkvT + 1024ull * 1024, 1024, 1024);
    transpose_k<<<dim3(32, 32), 256, 0, stream>>>(Wv + o2, WqkvT + 2048ull * 1024, 1024, 1024);
    transpose_k<<<dim3(32, 32), 256, 0, stream>>>(Wo + o2, WoT, 1024, 1024);
    transpose_k<<<dim3(176, 32), 256, 0, stream>>>(Wg + (size_t)l * 1024 * 5632, WgT, 1024, 5632);
    transpose_k<<<dim3(32, 88), 256, 0, stream>>>(Wd + (size_t)l * 2816 * 1024, WdT, 2816, 1024);

    rmsnorm_k<1><<<8192, 256, 0, stream>>>(x, n1w + l * 1024, hb);
    gemm256<2><<<32 * 12, 512, 0, stream>>>(hb, WqkvT, qkvraw, nullptr, 8192, 3072, 1024, 12);
    beta_k<<<2048, 256, 0, stream>>>(hb, Wb + (size_t)l * 1024 * 8, beta);
    qkv_epi<<<8192, 256, 0, stream>>>(qkvraw, qb, kbuf, vbuf);
    phaseA<<<1024, 256, 0, stream>>>(kbuf, qb, vbuf, beta, wbuf, ubuf, pbuf);
    phaseB<<<128, 256, 0, stream>>>(qb, kbuf, wbuf, ubuf, pbuf, obuf);
    onorm_k<<<8192, 256, 0, stream>>>(obuf, onw + l * 128, ob);
    gemm256<1><<<32 * 4, 512, 0, stream>>>(ob, WoT, x, nullptr, 8192, 1024, 1024, 4);

    rmsnorm_k<1><<<8192, 256, 0, stream>>>(x, n2w + l * 1024, hb);
    gemm256<2><<<32 * 11, 512, 0, stream>>>(hb, WgT + 2816ull * 1024, Ybuf, nullptr, 8192, 2816, 1024, 11);
    gemm256<3><<<32 * 11, 512, 0, stream>>>(hb, WgT, my, Ybuf, 8192, 2816, 1024, 11);
    gemm256<1><<<32 * 4, 512, 0, stream>>>(my, WdT, x, nullptr, 8192, 1024, 2816, 4);
  }
  rmsnorm_k<0><<<8192, 256, 0, stream>>>(x, fnw, d_out);
}

// Round 7
// 1142.099 us; speedup vs baseline: 1.5069x; 1.0959x over previous
//
#include <hip/hip_runtime.h>
#include <hip/hip_bf16.h>
#include <cstdint>

// DeltaNet forward, MI355X. Round 7: BN=128 8-phase GEMM variant for N=1024
// (fixes 128-block occupancy starvation), residual stream x in f16.

typedef _Float16 f16;
typedef __attribute__((ext_vector_type(8))) _Float16 h8;
typedef __attribute__((ext_vector_type(4))) _Float16 h4;
typedef __attribute__((ext_vector_type(4))) float f4;

#define DEV __device__ __forceinline__

static constexpr int Bb_ = 4;     // batch
static constexpr int Hh  = 8;     // heads
static constexpr int Dd  = 1024;  // hidden
static constexpr int Tt  = 2048;  // seq
static constexpr int NC  = 32;    // chunks (T/64)

DEV float siluf(float x) { return x / (1.f + expf(-x)); }

#define AS1(p) ((const __attribute__((address_space(1))) void*)(uintptr_t)(p))
#define AS3(p) ((__attribute__((address_space(3))) void*)(uint32_t)(uintptr_t)(p))

// ================= 8-phase GEMM: C[M,N] op= A[M,K]*Bt[N,K]^T ================
// BM=256, BN in {256,128}. EPI 0: f32 store; 1: f16 +=; 2: f16 store;
// 3: f16 glu store silu(acc)*Y.  LDS [rows][64] f16 halves of 128 rows,
// 16B-chunk swizzle chunk^=(row&7); linear gload_lds dest + pre-swz source.
DEV void stage_half(const f16* __restrict__ srcRowBase, int K, int kt,
                    f16* dstHalf, int tid) {
#pragma unroll
  for (int i = 0; i < 2; ++i) {
    const int q = i * 512 + tid;        // 1024 chunks (128 rows x 8)
    const int r = q >> 3, cs = q & 7;
    const int cl = cs ^ (r & 7);
    __builtin_amdgcn_global_load_lds(AS1(srcRowBase + (size_t)r * K + kt * 64 + cl * 8),
                                     AS3(dstHalf + q * 8), 16, 0, 0);
  }
}
DEV h8 rd_sw(const f16* T, int row, int chunk) {
  return *(const h8*)(T + (((row << 3) | (chunk ^ (row & 7))) * 8));
}

template<int EPI, int BN>
__global__ __launch_bounds__(512, 2) void gemm2(const f16* __restrict__ A, const f16* __restrict__ Bt,
                                                void* __restrict__ C, const f16* __restrict__ Yp,
                                                int M, int N, int K, int gx) {
  constexpr int NCF = BN / 64;                   // col frags per wave (4 or 2)
  __shared__ __align__(16) f16 ldsA[2][16384];
  __shared__ __align__(16) f16 ldsB[2][BN * 64];
  const int tid = threadIdx.x, lane = tid & 63, w = tid >> 6;
  const int l15 = lane & 15, l4 = lane >> 4;
  const int wr = w >> 2, wc = w & 3;
  const int nwg = gridDim.x;
  int flat = blockIdx.x;
  if ((nwg & 7) == 0) flat = (flat & 7) * (nwg >> 3) + (flat >> 3);
  const int bx = flat % gx, by = flat / gx;

  const f16* Ab = A + (size_t)by * 256 * K;
  const f16* Bb = Bt + (size_t)bx * BN * K;
  const int NT = K >> 6;
  f4 acc[8][NCF] = {};

  // ---- prologue ----
  stage_half(Bb, K, 0, ldsB[0], tid);
  if (BN == 256) stage_half(Bb + (size_t)128 * K, K, 0, ldsB[0] + 8192, tid);
  stage_half(Ab, K, 0, ldsA[0], tid);
  stage_half(Ab + (size_t)128 * K, K, 0, ldsA[0] + 8192, tid);
  if (NT > 1) {
    stage_half(Bb, K, 1, ldsB[1], tid);
    if (BN == 256) stage_half(Bb + (size_t)128 * K, K, 1, ldsB[1] + 8192, tid);
    if (BN == 256) asm volatile("s_waitcnt vmcnt(4)");
    else           asm volatile("s_waitcnt vmcnt(2)");
  } else {
    asm volatile("s_waitcnt vmcnt(0)");
  }
  __builtin_amdgcn_s_barrier();

  for (int t = 0; t < NT; ++t) {
    const int cur = t & 1, nxt = cur ^ 1;
    const f16* cA = ldsA[cur];
    const f16* cB = ldsB[cur];
    h8 b[NCF][2];
    h8 a[2][2];
    // ---------- phase 0: all B-frags + A quadrant 0; stage A(t+1)h0 ----------
#pragma unroll
    for (int cf = 0; cf < NCF; ++cf)
#pragma unroll
      for (int ks = 0; ks < 2; ++ks)
        b[cf][ks] = rd_sw(cB, wc * (BN / 4) + cf * 16 + l15, ks * 4 + l4);
#pragma unroll
    for (int fr = 0; fr < 2; ++fr)
#pragma unroll
      for (int ks = 0; ks < 2; ++ks)
        a[fr][ks] = rd_sw(cA, wr * 128 + fr * 16 + l15, ks * 4 + l4);
    if (t + 1 < NT) stage_half(Ab, K, t + 1, ldsA[nxt], tid);
    __builtin_amdgcn_s_barrier();
    asm volatile("s_waitcnt lgkmcnt(0)");
    __builtin_amdgcn_s_setprio(1);
#pragma unroll
    for (int fr = 0; fr < 2; ++fr)
#pragma unroll
      for (int cf = 0; cf < NCF; ++cf)
#pragma unroll
        for (int ks = 0; ks < 2; ++ks)
          acc[fr][cf] = __builtin_amdgcn_mfma_f32_16x16x32_f16(a[fr][ks], b[cf][ks], acc[fr][cf], 0, 0, 0);
    __builtin_amdgcn_s_setprio(0);
    __builtin_amdgcn_s_barrier();
    // ---------- phases 1..3 ----------
#pragma unroll
    for (int p = 1; p < 4; ++p) {
#pragma unroll
      for (int fr = 0; fr < 2; ++fr)
#pragma unroll
        for (int ks = 0; ks < 2; ++ks)
          a[fr][ks] = rd_sw(cA, wr * 128 + p * 32 + fr * 16 + l15, ks * 4 + l4);
      if (p == 1 && t + 1 < NT) stage_half(Ab + (size_t)128 * K, K, t + 1, ldsA[nxt] + 8192, tid);
      if (p == 2 && t + 2 < NT) stage_half(Bb, K, t + 2, ldsB[cur], tid);
      if (BN == 256 && p == 3 && t + 2 < NT) stage_half(Bb + (size_t)128 * K, K, t + 2, ldsB[cur] + 8192, tid);
      __builtin_amdgcn_s_barrier();
      asm volatile("s_waitcnt lgkmcnt(0)");
      __builtin_amdgcn_s_setprio(1);
#pragma unroll
      for (int fr = 0; fr < 2; ++fr)
#pragma unroll
        for (int cf = 0; cf < NCF; ++cf)
#pragma unroll
          for (int ks = 0; ks < 2; ++ks)
            acc[p * 2 + fr][cf] = __builtin_amdgcn_mfma_f32_16x16x32_f16(a[fr][ks], b[cf][ks], acc[p * 2 + fr][cf], 0, 0, 0);
      __builtin_amdgcn_s_setprio(0);
      if (p == 3) {
        if (t + 2 < NT) {
          if (BN == 256) asm volatile("s_waitcnt vmcnt(4)");
          else           asm volatile("s_waitcnt vmcnt(2)");
        } else if (t + 1 < NT) {
          asm volatile("s_waitcnt vmcnt(0)");
        }
      }
      __builtin_amdgcn_s_barrier();
    }
  }

  // ---- epilogue ----
#pragma unroll
  for (int fr = 0; fr < 8; ++fr) {
#pragma unroll
    for (int cf = 0; cf < NCF; ++cf) {
      const int row0 = by * 256 + wr * 128 + fr * 16 + l4 * 4;
      const int col = bx * BN + wc * (BN / 4) + cf * 16 + l15;
#pragma unroll
      for (int q = 0; q < 4; ++q) {
        const size_t idx = (size_t)(row0 + q) * N + col;
        const float v = acc[fr][cf][q];
        if (EPI == 0) ((float*)C)[idx] = v;
        if (EPI == 1) ((f16*)C)[idx] = (f16)((float)((f16*)C)[idx] + v);
        if (EPI == 2) ((f16*)C)[idx] = (f16)v;
        if (EPI == 3) ((f16*)C)[idx] = (f16)(siluf(v) * (float)Yp[idx]);
      }
    }
  }
}

// ---------------- f32 -> f16 convert (input -> residual) -------------------
__global__ __launch_bounds__(256) void cvt_k(const float* __restrict__ in, f16* __restrict__ out) {
  const size_t i = ((size_t)blockIdx.x * 256 + threadIdx.x) * 8;
  const float4 a = *(const float4*)(in + i);
  const float4 b = *(const float4*)(in + i + 4);
  h8 o = {(f16)a.x, (f16)a.y, (f16)a.z, (f16)a.w, (f16)b.x, (f16)b.y, (f16)b.z, (f16)b.w};
  *(h8*)(out + i) = o;
}

// ---------------- RMSNorm over D=1024, f16 in ------------------------------
template<int OUT_F16>
__global__ __launch_bounds__(256) void rmsnorm_k(const f16* __restrict__ x, const float* __restrict__ w,
                                                 void* __restrict__ out) {
  const int r = blockIdx.x, tid = threadIdx.x;
  const h4 xv = *(const h4*)(x + (size_t)r * 1024 + tid * 4);
  const float v0 = (float)xv[0], v1 = (float)xv[1], v2 = (float)xv[2], v3 = (float)xv[3];
  float ss = v0 * v0 + v1 * v1 + v2 * v2 + v3 * v3;
#pragma unroll
  for (int m = 1; m < 64; m <<= 1) ss += __shfl_xor(ss, m);
  __shared__ float red[4];
  if ((tid & 63) == 0) red[tid >> 6] = ss;
  __syncthreads();
  const float scale = rsqrtf((red[0] + red[1] + red[2] + red[3]) * (1.f / 1024.f) + 1e-6f);
  const float4 w4 = *(const float4*)(w + tid * 4);
  float o0 = v0 * scale * w4.x, o1 = v1 * scale * w4.y, o2 = v2 * scale * w4.z, o3 = v3 * scale * w4.w;
  if (OUT_F16) {
    h4 o = {(f16)o0, (f16)o1, (f16)o2, (f16)o3};
    *(h4*)((f16*)out + (size_t)r * 1024 + tid * 4) = o;
  } else {
    *(float4*)((float*)out + (size_t)r * 1024 + tid * 4) = make_float4(o0, o1, o2, o3);
  }
}

// ------- silu + per-head l2norm for q,k; silu for v (fused qkv layout) ------
__global__ __launch_bounds__(256) void qkv_epi(const f16* __restrict__ qkv, f16* __restrict__ qb,
                                               f16* __restrict__ kb, f16* __restrict__ vb) {
  const int r = blockIdx.x, tid = threadIdx.x;
  const int head = tid >> 5, l32 = tid & 31;
  const size_t src = (size_t)r * 3072 + head * 128 + l32 * 4;
  const size_t dst = (size_t)r * 1024 + head * 128 + l32 * 4;
  {
    const h4 v = *(const h4*)(qkv + src);
    float s0 = siluf((float)v[0]), s1 = siluf((float)v[1]), s2 = siluf((float)v[2]), s3 = siluf((float)v[3]);
    float ss = s0 * s0 + s1 * s1 + s2 * s2 + s3 * s3;
#pragma unroll
    for (int m = 1; m <= 16; m <<= 1) ss += __shfl_xor(ss, m);
    const float sc = rsqrtf(ss + 1e-6f);
    h4 o = {(f16)(s0 * sc), (f16)(s1 * sc), (f16)(s2 * sc), (f16)(s3 * sc)};
    *(h4*)(qb + dst) = o;
  }
  {
    const h4 v = *(const h4*)(qkv + src + 1024);
    float s0 = siluf((float)v[0]), s1 = siluf((float)v[1]), s2 = siluf((float)v[2]), s3 = siluf((float)v[3]);
    float ss = s0 * s0 + s1 * s1 + s2 * s2 + s3 * s3;
#pragma unroll
    for (int m = 1; m <= 16; m <<= 1) ss += __shfl_xor(ss, m);
    const float sc = rsqrtf(ss + 1e-6f);
    h4 o = {(f16)(s0 * sc), (f16)(s1 * sc), (f16)(s2 * sc), (f16)(s3 * sc)};
    *(h4*)(kb + dst) = o;
  }
  {
    const h4 v = *(const h4*)(qkv + (size_t)r * 3072 + 2048 + tid * 4);
    h4 o = {(f16)siluf((float)v[0]), (f16)siluf((float)v[1]), (f16)siluf((float)v[2]), (f16)siluf((float)v[3])};
    *(h4*)(vb + (size_t)r * 1024 + tid * 4) = o;
  }
}

// ---------------- per-head RMSNorm (DV=128) with shared weight -------------
__global__ __launch_bounds__(256) void onorm_k(const float* __restrict__ o, const float* __restrict__ w,
                                               f16* __restrict__ ob) {
  const int r = blockIdx.x, tid = threadIdx.x;
  const int head = tid >> 5, l32 = tid & 31;
  const size_t base = (size_t)r * 1024 + head * 128 + l32 * 4;
  const float4 v = *(const float4*)(o + base);
  float ss = v.x * v.x + v.y * v.y + v.z * v.z + v.w * v.w;
#pragma unroll
  for (int m = 1; m <= 16; m <<= 1) ss += __shfl_xor(ss, m);
  const float sc = rsqrtf(ss * (1.f / 128.f) + 1e-6f);
  const float4 w4 = *(const float4*)(w + l32 * 4);
  h4 out = {(f16)(v.x * sc * w4.x), (f16)(v.y * sc * w4.y), (f16)(v.z * sc * w4.z), (f16)(v.w * sc * w4.w)};
  *(h4*)(ob + base) = out;
}

// ---------------- beta = 2*sigmoid(h @ Wb), wave-per-row GEMV --------------
__global__ __launch_bounds__(256) void beta_k(const f16* __restrict__ hb, const float* __restrict__ Wb,
                                              float* __restrict__ beta) {
  const int tid = threadIdx.x, lane = tid & 63, wv = tid >> 6;
  const int r = blockIdx.x * 4 + wv;
  const f16* row = hb + (size_t)r * 1024 + lane * 16;
  const h8 v0 = *(const h8*)(row);
  const h8 v1 = *(const h8*)(row + 8);
  const float* wb = Wb + (size_t)(lane * 16) * 8;
  float acc[8] = {};
#pragma unroll
  for (int e = 0; e < 8; ++e) {
    const float x0 = (float)v0[e], x1 = (float)v1[e];
    const float4 w0a = *(const float4*)(wb + e * 8);
    const float4 w0b = *(const float4*)(wb + e * 8 + 4);
    const float4 w1a = *(const float4*)(wb + (e + 8) * 8);
    const float4 w1b = *(const float4*)(wb + (e + 8) * 8 + 4);
    acc[0] += x0 * w0a.x + x1 * w1a.x;  acc[1] += x0 * w0a.y + x1 * w1a.y;
    acc[2] += x0 * w0a.z + x1 * w1a.z;  acc[3] += x0 * w0a.w + x1 * w1a.w;
    acc[4] += x0 * w0b.x + x1 * w1b.x;  acc[5] += x0 * w0b.y + x1 * w1b.y;
    acc[6] += x0 * w0b.z + x1 * w1b.z;  acc[7] += x0 * w0b.w + x1 * w1b.w;
  }
#pragma unroll
  for (int j = 0; j < 8; ++j)
#pragma unroll
    for (int m = 1; m < 64; m <<= 1) acc[j] += __shfl_xor(acc[j], m);
  if (lane == 0) {
#pragma unroll
    for (int j = 0; j < 8; ++j) beta[(size_t)r * 8 + j] = 2.f / (1.f + expf(-acc[j]));
  }
}

// ---------------- W[K][N] f32 -> Wt[N][K] f16 ------------------------------
__global__ __launch_bounds__(256) void transpose_k(const float* __restrict__ W, f16* __restrict__ Wt,
                                                   int K, int N) {
  __shared__ float tile[32][33];
  const int n0 = blockIdx.x * 32, k0 = blockIdx.y * 32;
  const int tx = threadIdx.x & 31, ty = threadIdx.x >> 5;
#pragma unroll
  for (int i = 0; i < 32; i += 8) tile[ty + i][tx] = W[(size_t)(k0 + ty + i) * N + n0 + tx];
  __syncthreads();
#pragma unroll
  for (int i = 0; i < 32; i += 8) Wt[(size_t)(n0 + ty + i) * K + k0 + tx] = (f16)tile[tx][ty + i];
}

// ---------------- diagnostic fill ------------------------------------------
__global__ void fill_k(float* p, int n, float v) {
  const int i = blockIdx.x * 256 + threadIdx.x;
  if (i < n) p[i] = v;
}

// ---------------- Phase A: per-(bh,chunk) WY transform ---------------------
DEV f4 mm16(const f16* A, int as, const f16* B, f4 c, int l15, int l4) {
  h4 a = *(const h4*)(A + l15 * as + l4 * 4);
  h4 b = *(const h4*)(B + l15 * 20 + l4 * 4);
  return __builtin_amdgcn_mfma_f32_16x16x16f16(a, b, c, 0, 0, 0);
}
DEV void wr_T(f16* slot, f4 acc, int l15, int l4, float sgn) {
  h4 v = {(f16)(sgn * acc[0]), (f16)(sgn * acc[1]), (f16)(sgn * acc[2]), (f16)(sgn * acc[3])};
  *(h4*)(slot + l15 * 20 + l4 * 4) = v;
}
DEV void wr_Tb(f16* Tb, int bi, int bj, f4 acc, const float* betas, int l15, int l4, float sgn) {
  const float bc = betas[bj * 16 + l15];
#pragma unroll
  for (int q = 0; q < 4; ++q)
    Tb[(bi * 16 + l4 * 4 + q) * 72 + bj * 16 + l15] = (f16)(sgn * acc[q] * bc);
}

__global__ __launch_bounds__(256) void phaseA(const f16* __restrict__ kb, const f16* __restrict__ qb,
                                              const f16* __restrict__ vb, const float* __restrict__ beta,
                                              f16* __restrict__ wbuf, f16* __restrict__ ubuf,
                                              f16* __restrict__ pbuf) {
  const int blk = blockIdx.x;
  const int c = blk >> 5, bh = blk & 31;
  const int b = bh >> 3, h = bh & 7;
  const int tid = threadIdx.x, lane = tid & 63, wv = tid >> 6;
  const int l15 = lane & 15, l4 = lane >> 4;

  __shared__ __align__(16) f16 Ks[64 * 128];
  __shared__ __align__(16) f16 QVs[64 * 128];
  __shared__ __align__(16) f16 Abuf[64 * 68];
  __shared__ __align__(16) f16 Dr[4][16 * 20];
  __shared__ __align__(16) f16 Dt[4][16 * 20];
  __shared__ __align__(16) f16 Tp[3][16 * 20];
  __shared__ __align__(16) f16 Xp[3][16 * 20];
  __shared__ __align__(16) f16 Tb[64 * 72];
  __shared__ float betas[64];

  const size_t rowstr = (size_t)Bb_ * Dd;
  const size_t gbase = ((size_t)(c * 64) * Bb_ + b) * Dd + h * 128;

#pragma unroll
  for (int i = 0; i < 4; ++i) {
    const int ch = tid + i * 256;
    const int rr = ch >> 4, kc = ch & 15;
    *(h8*)(Ks + ch * 8) = *(const h8*)(kb + gbase + (size_t)rr * rowstr + kc * 8);
    *(h8*)(QVs + ch * 8) = *(const h8*)(qb + gbase + (size_t)rr * rowstr + kc * 8);
  }
  for (int i = tid; i < 64 * 72; i += 256) Tb[i] = (f16)0.f;
  if (tid < 64) betas[tid] = beta[((size_t)(c * 64 + tid) * Bb_ + b) * Hh + h];
  __syncthreads();

  f4 accS[4] = {}, accP[4] = {};
  const int arow = wv * 16 + l15;
  const int koff = l4 * 8;
#pragma unroll
  for (int kc = 0; kc < 4; ++kc) {
    const h8 aK = *(const h8*)(Ks + arow * 128 + kc * 32 + koff);
    const h8 aQ = *(const h8*)(QVs + arow * 128 + kc * 32 + koff);
#pragma unroll
    for (int f = 0; f < 4; ++f) {
      const h8 bK = *(const h8*)(Ks + (f * 16 + l15) * 128 + kc * 32 + koff);
      accS[f] = __builtin_amdgcn_mfma_f32_16x16x32_f16(aK, bK, accS[f], 0, 0, 0);
      accP[f] = __builtin_amdgcn_mfma_f32_16x16x32_f16(aQ, bK, accP[f], 0, 0, 0);
    }
  }
  const size_t pbase = (((size_t)bh * NC + c) * 64) * 64;
#pragma unroll
  for (int f = 0; f < 4; ++f) {
#pragma unroll
    for (int q = 0; q < 4; ++q) {
      const int i = wv * 16 + l4 * 4 + q;
      const int j = f * 16 + l15;
      Abuf[i * 68 + j] = (f16)((j < i) ? betas[i] * accS[f][q] : 0.f);
      pbuf[pbase + (size_t)i * 64 + j] = (f16)((j <= i) ? accP[f][q] : 0.f);
    }
  }
  __syncthreads();

#pragma unroll
  for (int i = 0; i < 4; ++i) {
    const int ch = tid + i * 256;
    const int rr = ch >> 4, kc = ch & 15;
    *(h8*)(QVs + ch * 8) = *(const h8*)(vb + gbase + (size_t)rr * rowstr + kc * 8);
  }

  {
    const int bi = wv;
    const int cc = l15;
    const f16* Ad = Abuf + (bi * 16) * 68 + bi * 16;
    float t[16];
    t[0] = (cc == 0) ? 1.f : 0.f;
#pragma unroll
    for (int i = 1; i < 16; ++i) {
      float s = (cc == i) ? 1.f : 0.f;
#pragma unroll
      for (int j = 0; j < i; ++j) s -= (float)Ad[i * 68 + j] * t[j];
      t[i] = s;
    }
    if (lane < 16) {
#pragma unroll
      for (int j4 = 0; j4 < 4; ++j4) {
        h4 v = {(f16)t[j4 * 4], (f16)t[j4 * 4 + 1], (f16)t[j4 * 4 + 2], (f16)t[j4 * 4 + 3]};
        *(h4*)(&Dt[bi][cc * 20 + j4 * 4]) = v;
      }
      const float bc = betas[bi * 16 + cc];
#pragma unroll
      for (int j = 0; j < 16; ++j) {
        Dr[bi][j * 20 + cc] = (f16)t[j];
        Tb[(bi * 16 + j) * 72 + bi * 16 + cc] = (f16)(t[j] * bc);
      }
    }
  }
  __syncthreads();

  const f16* AB10 = Abuf + 16 * 68 + 0;
  const f16* AB20 = Abuf + 32 * 68 + 0;
  const f16* AB21 = Abuf + 32 * 68 + 16;
  const f16* AB30 = Abuf + 48 * 68 + 0;
  const f16* AB31 = Abuf + 48 * 68 + 16;
  const f16* AB32 = Abuf + 48 * 68 + 32;
  f4 z = {};
  f4 x20, x30;

  if (wv == 0) wr_T(Xp[0], mm16(AB10, 68, Dt[0], z, l15, l4), l15, l4, 1.f);
  if (wv == 1) wr_T(Xp[1], mm16(AB21, 68, Dt[1], z, l15, l4), l15, l4, 1.f);
  if (wv == 2) wr_T(Xp[2], mm16(AB32, 68, Dt[2], z, l15, l4), l15, l4, 1.f);
  if (wv == 3) x20 = mm16(AB20, 68, Dt[0], z, l15, l4);
  __syncthreads();
  if (wv == 0) { f4 r = mm16(Dr[1], 20, Xp[0], z, l15, l4); wr_T(Tp[0], r, l15, l4, -1.f); wr_Tb(Tb, 1, 0, r, betas, l15, l4, -1.f); }
  if (wv == 1) { f4 r = mm16(Dr[2], 20, Xp[1], z, l15, l4); wr_T(Tp[1], r, l15, l4, -1.f); wr_Tb(Tb, 2, 1, r, betas, l15, l4, -1.f); }
  if (wv == 2) { f4 r = mm16(Dr[3], 20, Xp[2], z, l15, l4); wr_Tb(Tb, 3, 2, r, betas, l15, l4, -1.f); }
  if (wv == 3) x30 = mm16(AB30, 68, Dt[0], z, l15, l4);
  __syncthreads();
  if (wv == 3) wr_T(Xp[0], mm16(AB21, 68, Tp[0], x20, l15, l4), l15, l4, 1.f);
  if (wv == 1) { f4 r = mm16(AB31, 68, Dt[1], z, l15, l4); r = mm16(AB32, 68, Tp[1], r, l15, l4); wr_T(Xp[1], r, l15, l4, 1.f); }
  __syncthreads();
  if (wv == 3) { f4 r = mm16(Dr[2], 20, Xp[0], z, l15, l4); wr_T(Tp[2], r, l15, l4, -1.f); wr_Tb(Tb, 2, 0, r, betas, l15, l4, -1.f); }
  if (wv == 1) { f4 r = mm16(Dr[3], 20, Xp[1], z, l15, l4); wr_Tb(Tb, 3, 1, r, betas, l15, l4, -1.f); }
  __syncthreads();
  if (wv == 3) { f4 r = mm16(AB31, 68, Tp[0], x30, l15, l4); r = mm16(AB32, 68, Tp[2], r, l15, l4); wr_T(Xp[2], r, l15, l4, 1.f); }
  __syncthreads();
  if (wv == 3) { f4 r = mm16(Dr[3], 20, Xp[2], z, l15, l4); wr_Tb(Tb, 3, 0, r, betas, l15, l4, -1.f); }
  __syncthreads();

  const size_t wub = ((size_t)bh * Tt + c * 64) * 128;
  f4 wacc[8] = {}, uacc[8] = {};
#pragma unroll
  for (int kc = 0; kc < 2; ++kc) {
    const h8 aT = *(const h8*)(Tb + (wv * 16 + l15) * 72 + kc * 32 + koff);
#pragma unroll
    for (int f = 0; f < 8; ++f) {
      h8 bK, bV;
#pragma unroll
      for (int j = 0; j < 8; ++j) {
        const int t2 = kc * 32 + koff + j;
        const int d = f * 16 + l15;
        bK[j] = Ks[t2 * 128 + d];
        bV[j] = QVs[t2 * 128 + d];
      }
      wacc[f] = __builtin_amdgcn_mfma_f32_16x16x32_f16(aT, bK, wacc[f], 0, 0, 0);
      uacc[f] = __builtin_amdgcn_mfma_f32_16x16x32_f16(aT, bV, uacc[f], 0, 0, 0);
    }
  }
#pragma unroll
  for (int f = 0; f < 8; ++f)
#pragma unroll
    for (int q = 0; q < 4; ++q) {
      const int i = wv * 16 + l4 * 4 + q;
      const int d = f * 16 + l15;
      wbuf[wub + (size_t)i * 128 + d] = (f16)wacc[f][q];
      ubuf[wub + (size_t)i * 128 + d] = (f16)uacc[f][q];
    }
}

// ---------------- Phase B: sequential chunk recurrence ---------------------
__global__ __launch_bounds__(256) void phaseB(const f16* __restrict__ qb, const f16* __restrict__ kb,
                                              const f16* __restrict__ wbuf, const f16* __restrict__ ubuf,
                                              const f16* __restrict__ pbuf, float* __restrict__ obuf) {
  const int blk = blockIdx.x;
  const int bh = blk >> 2, g = blk & 3;
  const int b = bh >> 3, h = bh & 7;
  const int tid = threadIdx.x, lane = tid & 63, wv = tid >> 6;
  const int l15 = lane & 15, l4 = lane >> 4;

  __shared__ __align__(16) f16 Ws[64 * 128];
  __shared__ __align__(16) f16 Qs[64 * 128];
  __shared__ __align__(16) f16 Ks[64 * 128];
  __shared__ __align__(16) f16 Ps[64 * 64];
  __shared__ __align__(16) f16 Rt[32 * 72];
  __shared__ __align__(16) f16 Ms[32 * 136];

  for (int i = tid; i < 32 * 136; i += 256) Ms[i] = (f16)0.f;
  f4 macc[2][2] = {};

  const size_t rowstr = (size_t)Bb_ * Dd;
  const size_t qk0 = (size_t)b * Dd + h * 128;
  const int arow = wv * 16 + l15;
  const int koff = l4 * 8;
  __syncthreads();

  for (int c = 0; c < NC; ++c) {
    const size_t wub = ((size_t)bh * Tt + c * 64) * 128;
    const size_t pbase = (((size_t)bh * NC + c) * 64) * 64;
#pragma unroll
    for (int i = 0; i < 4; ++i) {
      const int ch = tid + i * 256;
      const int rr = ch >> 4, kc = ch & 15;
      *(h8*)(Ws + ch * 8) = *(const h8*)(wbuf + wub + ch * 8);
      *(h8*)(Qs + ch * 8) = *(const h8*)(qb + qk0 + (size_t)(c * 64 + rr) * rowstr + kc * 8);
      *(h8*)(Ks + ch * 8) = *(const h8*)(kb + qk0 + (size_t)(c * 64 + rr) * rowstr + kc * 8);
    }
#pragma unroll
    for (int i = 0; i < 2; ++i) {
      const int ch = tid + i * 256;
      *(h8*)(Ps + ch * 8) = *(const h8*)(pbuf + pbase + ch * 8);
    }
    __syncthreads();

    f4 accR[2] = {}, accO[2] = {};
#pragma unroll
    for (int kc = 0; kc < 4; ++kc) {
      const h8 aW = *(const h8*)(Ws + arow * 128 + kc * 32 + koff);
      const h8 aQ = *(const h8*)(Qs + arow * 128 + kc * 32 + koff);
#pragma unroll
      for (int f = 0; f < 2; ++f) {
        const h8 bM = *(const h8*)(Ms + (f * 16 + l15) * 136 + kc * 32 + koff);
        accR[f] = __builtin_amdgcn_mfma_f32_16x16x32_f16(aW, bM, accR[f], 0, 0, 0);
        accO[f] = __builtin_amdgcn_mfma_f32_16x16x32_f16(aQ, bM, accO[f], 0, 0, 0);
      }
    }
#pragma unroll
    for (int f = 0; f < 2; ++f) {
#pragma unroll
      for (int q = 0; q < 4; ++q) {
        const int i = wv * 16 + l4 * 4 + q;
        const int cc = f * 16 + l15;
        const float uv = (float)ubuf[wub + (size_t)i * 128 + g * 32 + cc];
        const float rv = uv - accR[f][q];
        accR[f][q] = rv;
        Rt[cc * 72 + i] = (f16)rv;
      }
    }
    __syncthreads();

#pragma unroll
    for (int kc = 0; kc < 2; ++kc) {
      const h8 aP = *(const h8*)(Ps + arow * 64 + kc * 32 + koff);
#pragma unroll
      for (int f = 0; f < 2; ++f) {
        const h8 bR = *(const h8*)(Rt + (f * 16 + l15) * 72 + kc * 32 + koff);
        accO[f] = __builtin_amdgcn_mfma_f32_16x16x32_f16(aP, bR, accO[f], 0, 0, 0);
      }
    }
#pragma unroll
    for (int f = 0; f < 2; ++f)
#pragma unroll
      for (int q = 0; q < 4; ++q) {
        const int i = wv * 16 + l4 * 4 + q;
        const int cc = f * 16 + l15;
        obuf[((size_t)(c * 64 + i) * Bb_ + b) * Dd + h * 128 + g * 32 + cc] = accO[f][q];
      }

#pragma unroll
    for (int kc = 0; kc < 2; ++kc) {
      const h8 aR0 = *(const h8*)(Rt + l15 * 72 + kc * 32 + koff);
      const h8 aR1 = *(const h8*)(Rt + (16 + l15) * 72 + kc * 32 + koff);
#pragma unroll
      for (int cf = 0; cf < 2; ++cf) {
        const int kcol = wv * 32 + cf * 16 + l15;
        h8 bKv;
#pragma unroll
        for (int j = 0; j < 8; ++j) bKv[j] = Ks[(kc * 32 + koff + j) * 128 + kcol];
        macc[0][cf] = __builtin_amdgcn_mfma_f32_16x16x32_f16(aR0, bKv, macc[0][cf], 0, 0, 0);
        macc[1][cf] = __builtin_amdgcn_mfma_f32_16x16x32_f16(aR1, bKv, macc[1][cf], 0, 0, 0);
      }
    }
#pragma unroll
    for (int rf = 0; rf < 2; ++rf)
#pragma unroll
      for (int cf = 0; cf < 2; ++cf)
#pragma unroll
        for (int q = 0; q < 4; ++q) {
          const int cr = rf * 16 + l4 * 4 + q;
          const int kcol = wv * 32 + cf * 16 + l15;
          Ms[cr * 136 + kcol] = (f16)macc[rf][cf][q];
        }
    __syncthreads();
  }
}

// ---------------------------------------------------------------------------
extern "C" void kernel_launch(void* const* d_in, const int* in_sizes, int n_in,
                              void* d_out, int out_size, void* d_ws, size_t ws_size,
                              hipStream_t stream) {
  (void)in_sizes; (void)n_in;
  const float* input = (const float*)d_in[0];
  const float* Wq = (const float*)d_in[1];
  const float* Wk = (const float*)d_in[2];
  const float* Wv = (const float*)d_in[3];
  const float* Wb = (const float*)d_in[4];
  const float* Wo = (const float*)d_in[5];
  const float* onw = (const float*)d_in[6];
  const float* n1w = (const float*)d_in[7];
  const float* n2w = (const float*)d_in[8];
  const float* Wg = (const float*)d_in[9];
  const float* Wd = (const float*)d_in[10];
  const float* fnw = (const float*)d_in[11];

  char* ws = (char*)d_ws;
  size_t off = 0;
  auto alloc = [&](size_t bytes) { void* p = ws + off; off += (bytes + 255) & ~(size_t)255; return p; };
  const size_t RD = 8192ull * 1024ull;
  f16*  x     = (f16*)alloc(RD * 2);                   // residual stream, f16
  f16*  hb    = (f16*)alloc(RD * 2);
  f16*  qb    = (f16*)alloc(RD * 2);
  f16*  kbuf  = (f16*)alloc(RD * 2);
  f16*  vbuf  = (f16*)alloc(RD * 2);
  float* beta = (float*)alloc(8192ull * 8 * 4);
  f16*  wbuf  = (f16*)alloc(RD * 2);
  f16*  ubuf  = (f16*)alloc(RD * 2);
  f16*  pbuf  = (f16*)alloc(32ull * 32 * 64 * 64 * 2);
  char* arena = (char*)alloc(3 * RD * 2);              // {qkv fused}|{obuf}|{Y}
  f16*  WqkvT = (f16*)alloc(3072ull * 1024 * 2);
  f16*  WoT   = (f16*)alloc(1024ull * 1024 * 2);
  f16*  WgT   = (f16*)alloc(5632ull * 1024 * 2);
  f16*  WdT   = (f16*)alloc(1024ull * 2816 * 2);
  if (off > ws_size) {
    fill_k<<<(out_size + 255) / 256, 256, 0, stream>>>((float*)d_out, out_size, 1.0e6f);
    return;
  }
  f16* qkvraw = (f16*)arena;       // [8192][3072]
  float* obuf = (float*)arena;
  f16* Ybuf = (f16*)arena;         // [8192][2816]
  f16* my = qb;                    // qb/kbuf/vbuf dead by then
  f16* ob = wbuf;                  // wbuf dead after phaseB

  cvt_k<<<4096, 256, 0, stream>>>(input, x);

  for (int l = 0; l < 2; ++l) {
    const size_t o2 = (size_t)l * 1024 * 1024;
    transpose_k<<<dim3(32, 32), 256, 0, stream>>>(Wq + o2, WqkvT, 1024, 1024);
    transpose_k<<<dim3(32, 32), 256, 0, stream>>>(Wk + o2, WqkvT + 1024ull * 1024, 1024, 1024);
    transpose_k<<<dim3(32, 32), 256, 0, stream>>>(Wv + o2, WqkvT + 2048ull * 1024, 1024, 1024);
    transpose_k<<<dim3(32, 32), 256, 0, stream>>>(Wo + o2, WoT, 1024, 1024);
    transpose_k<<<dim3(176, 32), 256, 0, stream>>>(Wg + (size_t)l * 1024 * 5632, WgT, 1024, 5632);
    transpose_k<<<dim3(32, 88), 256, 0, stream>>>(Wd + (size_t)l * 2816 * 1024, WdT, 2816, 1024);

    rmsnorm_k<1><<<8192, 256, 0, stream>>>(x, n1w + l * 1024, hb);
    gemm2<2, 256><<<32 * 12, 512, 0, stream>>>(hb, WqkvT, qkvraw, nullptr, 8192, 3072, 1024, 12);
    beta_k<<<2048, 256, 0, stream>>>(hb, Wb + (size_t)l * 1024 * 8, beta);
    qkv_epi<<<8192, 256, 0, stream>>>(qkvraw, qb, kbuf, vbuf);
    phaseA<<<1024, 256, 0, stream>>>(kbuf, qb, vbuf, beta, wbuf, ubuf, pbuf);
    phaseB<<<128, 256, 0, stream>>>(qb, kbuf, wbuf, ubuf, pbuf, obuf);
    onorm_k<<<8192, 256, 0, stream>>>(obuf, onw + l * 128, ob);
    gemm2<1, 128><<<32 * 8, 512, 0, stream>>>(ob, WoT, x, nullptr, 8192, 1024, 1024, 8);

    rmsnorm_k<1><<<8192, 256, 0, stream>>>(x, n2w + l * 1024, hb);
    gemm2<2, 256><<<32 * 11, 512, 0, stream>>>(hb, WgT + 2816ull * 1024, Ybuf, nullptr, 8192, 2816, 1024, 11);
    gemm2<3, 256><<<32 * 11, 512, 0, stream>>>(hb, WgT, my, Ybuf, 8192, 2816, 1024, 11);
    gemm2<1, 128><<<32 * 8, 512, 0, stream>>>(my, WdT, x, nullptr, 8192, 1024, 2816, 8);
  }
  rmsnorm_k<0><<<8192, 256, 0, stream>>>(x, fnw, d_out);
}

// Round 8
// 1064.453 us; speedup vs baseline: 1.6168x; 1.0729x over previous
//
#include <hip/hip_runtime.h>
#include <hip/hip_bf16.h>
#include <cstdint>

// DeltaNet forward, MI355X. Round 8: phaseB LDS-conflict fix — global chunk
// swizzle for q/k/v/w, K^T+u^T materialized in phaseA, P/u in regs,
// counted-vmcnt double-buffered staging in phaseB. obuf f16.

typedef _Float16 f16;
typedef __attribute__((ext_vector_type(8))) _Float16 h8;
typedef __attribute__((ext_vector_type(4))) _Float16 h4;
typedef __attribute__((ext_vector_type(4))) float f4;

#define DEV __device__ __forceinline__

static constexpr int Bb_ = 4;     // batch
static constexpr int Hh  = 8;     // heads
static constexpr int Dd  = 1024;  // hidden
static constexpr int Tt  = 2048;  // seq
static constexpr int NC  = 32;    // chunks (T/64)

DEV float siluf(float x) { return x / (1.f + expf(-x)); }
// chunk swizzle for [64][128] tiles (16 chunks of 8 f16 per row)
DEV int swz16(int row, int c) { return (c & 8) | ((c & 7) ^ (row & 7)); }

#define AS1(p) ((const __attribute__((address_space(1))) void*)(uintptr_t)(p))
#define AS3(p) ((__attribute__((address_space(3))) void*)(uint32_t)(uintptr_t)(p))

// ================= 8-phase GEMM (unchanged from R7) ========================
DEV void stage_half(const f16* __restrict__ srcRowBase, int K, int kt,
                    f16* dstHalf, int tid) {
#pragma unroll
  for (int i = 0; i < 2; ++i) {
    const int q = i * 512 + tid;
    const int r = q >> 3, cs = q & 7;
    const int cl = cs ^ (r & 7);
    __builtin_amdgcn_global_load_lds(AS1(srcRowBase + (size_t)r * K + kt * 64 + cl * 8),
                                     AS3(dstHalf + q * 8), 16, 0, 0);
  }
}
DEV h8 rd_sw(const f16* T, int row, int chunk) {
  return *(const h8*)(T + (((row << 3) | (chunk ^ (row & 7))) * 8));
}

template<int EPI, int BN>
__global__ __launch_bounds__(512, 2) void gemm2(const f16* __restrict__ A, const f16* __restrict__ Bt,
                                                void* __restrict__ C, const f16* __restrict__ Yp,
                                                int M, int N, int K, int gx) {
  constexpr int NCF = BN / 64;
  __shared__ __align__(16) f16 ldsA[2][16384];
  __shared__ __align__(16) f16 ldsB[2][BN * 64];
  const int tid = threadIdx.x, lane = tid & 63, w = tid >> 6;
  const int l15 = lane & 15, l4 = lane >> 4;
  const int wr = w >> 2, wc = w & 3;
  const int nwg = gridDim.x;
  int flat = blockIdx.x;
  if ((nwg & 7) == 0) flat = (flat & 7) * (nwg >> 3) + (flat >> 3);
  const int bx = flat % gx, by = flat / gx;

  const f16* Ab = A + (size_t)by * 256 * K;
  const f16* Bb = Bt + (size_t)bx * BN * K;
  const int NT = K >> 6;
  f4 acc[8][NCF] = {};

  stage_half(Bb, K, 0, ldsB[0], tid);
  if (BN == 256) stage_half(Bb + (size_t)128 * K, K, 0, ldsB[0] + 8192, tid);
  stage_half(Ab, K, 0, ldsA[0], tid);
  stage_half(Ab + (size_t)128 * K, K, 0, ldsA[0] + 8192, tid);
  if (NT > 1) {
    stage_half(Bb, K, 1, ldsB[1], tid);
    if (BN == 256) stage_half(Bb + (size_t)128 * K, K, 1, ldsB[1] + 8192, tid);
    if (BN == 256) asm volatile("s_waitcnt vmcnt(4)");
    else           asm volatile("s_waitcnt vmcnt(2)");
  } else {
    asm volatile("s_waitcnt vmcnt(0)");
  }
  __builtin_amdgcn_s_barrier();

  for (int t = 0; t < NT; ++t) {
    const int cur = t & 1, nxt = cur ^ 1;
    const f16* cA = ldsA[cur];
    const f16* cB = ldsB[cur];
    h8 b[NCF][2];
    h8 a[2][2];
#pragma unroll
    for (int cf = 0; cf < NCF; ++cf)
#pragma unroll
      for (int ks = 0; ks < 2; ++ks)
        b[cf][ks] = rd_sw(cB, wc * (BN / 4) + cf * 16 + l15, ks * 4 + l4);
#pragma unroll
    for (int fr = 0; fr < 2; ++fr)
#pragma unroll
      for (int ks = 0; ks < 2; ++ks)
        a[fr][ks] = rd_sw(cA, wr * 128 + fr * 16 + l15, ks * 4 + l4);
    if (t + 1 < NT) stage_half(Ab, K, t + 1, ldsA[nxt], tid);
    __builtin_amdgcn_s_barrier();
    asm volatile("s_waitcnt lgkmcnt(0)");
    __builtin_amdgcn_s_setprio(1);
#pragma unroll
    for (int fr = 0; fr < 2; ++fr)
#pragma unroll
      for (int cf = 0; cf < NCF; ++cf)
#pragma unroll
        for (int ks = 0; ks < 2; ++ks)
          acc[fr][cf] = __builtin_amdgcn_mfma_f32_16x16x32_f16(a[fr][ks], b[cf][ks], acc[fr][cf], 0, 0, 0);
    __builtin_amdgcn_s_setprio(0);
    __builtin_amdgcn_s_barrier();
#pragma unroll
    for (int p = 1; p < 4; ++p) {
#pragma unroll
      for (int fr = 0; fr < 2; ++fr)
#pragma unroll
        for (int ks = 0; ks < 2; ++ks)
          a[fr][ks] = rd_sw(cA, wr * 128 + p * 32 + fr * 16 + l15, ks * 4 + l4);
      if (p == 1 && t + 1 < NT) stage_half(Ab + (size_t)128 * K, K, t + 1, ldsA[nxt] + 8192, tid);
      if (p == 2 && t + 2 < NT) stage_half(Bb, K, t + 2, ldsB[cur], tid);
      if (BN == 256 && p == 3 && t + 2 < NT) stage_half(Bb + (size_t)128 * K, K, t + 2, ldsB[cur] + 8192, tid);
      __builtin_amdgcn_s_barrier();
      asm volatile("s_waitcnt lgkmcnt(0)");
      __builtin_amdgcn_s_setprio(1);
#pragma unroll
      for (int fr = 0; fr < 2; ++fr)
#pragma unroll
        for (int cf = 0; cf < NCF; ++cf)
#pragma unroll
          for (int ks = 0; ks < 2; ++ks)
            acc[p * 2 + fr][cf] = __builtin_amdgcn_mfma_f32_16x16x32_f16(a[fr][ks], b[cf][ks], acc[p * 2 + fr][cf], 0, 0, 0);
      __builtin_amdgcn_s_setprio(0);
      if (p == 3) {
        if (t + 2 < NT) {
          if (BN == 256) asm volatile("s_waitcnt vmcnt(4)");
          else           asm volatile("s_waitcnt vmcnt(2)");
        } else if (t + 1 < NT) {
          asm volatile("s_waitcnt vmcnt(0)");
        }
      }
      __builtin_amdgcn_s_barrier();
    }
  }

#pragma unroll
  for (int fr = 0; fr < 8; ++fr) {
#pragma unroll
    for (int cf = 0; cf < NCF; ++cf) {
      const int row0 = by * 256 + wr * 128 + fr * 16 + l4 * 4;
      const int col = bx * BN + wc * (BN / 4) + cf * 16 + l15;
#pragma unroll
      for (int q = 0; q < 4; ++q) {
        const size_t idx = (size_t)(row0 + q) * N + col;
        const float v = acc[fr][cf][q];
        if (EPI == 0) ((float*)C)[idx] = v;
        if (EPI == 1) ((f16*)C)[idx] = (f16)((float)((f16*)C)[idx] + v);
        if (EPI == 2) ((f16*)C)[idx] = (f16)v;
        if (EPI == 3) ((f16*)C)[idx] = (f16)(siluf(v) * (float)Yp[idx]);
      }
    }
  }
}

// ---------------- f32 -> f16 convert ---------------------------------------
__global__ __launch_bounds__(256) void cvt_k(const float* __restrict__ in, f16* __restrict__ out) {
  const size_t i = ((size_t)blockIdx.x * 256 + threadIdx.x) * 8;
  const float4 a = *(const float4*)(in + i);
  const float4 b = *(const float4*)(in + i + 4);
  h8 o = {(f16)a.x, (f16)a.y, (f16)a.z, (f16)a.w, (f16)b.x, (f16)b.y, (f16)b.z, (f16)b.w};
  *(h8*)(out + i) = o;
}

// ---------------- RMSNorm over D=1024, f16 in ------------------------------
template<int OUT_F16>
__global__ __launch_bounds__(256) void rmsnorm_k(const f16* __restrict__ x, const float* __restrict__ w,
                                                 void* __restrict__ out) {
  const int r = blockIdx.x, tid = threadIdx.x;
  const h4 xv = *(const h4*)(x + (size_t)r * 1024 + tid * 4);
  const float v0 = (float)xv[0], v1 = (float)xv[1], v2 = (float)xv[2], v3 = (float)xv[3];
  float ss = v0 * v0 + v1 * v1 + v2 * v2 + v3 * v3;
#pragma unroll
  for (int m = 1; m < 64; m <<= 1) ss += __shfl_xor(ss, m);
  __shared__ float red[4];
  if ((tid & 63) == 0) red[tid >> 6] = ss;
  __syncthreads();
  const float scale = rsqrtf((red[0] + red[1] + red[2] + red[3]) * (1.f / 1024.f) + 1e-6f);
  const float4 w4 = *(const float4*)(w + tid * 4);
  float o0 = v0 * scale * w4.x, o1 = v1 * scale * w4.y, o2 = v2 * scale * w4.z, o3 = v3 * scale * w4.w;
  if (OUT_F16) {
    h4 o = {(f16)o0, (f16)o1, (f16)o2, (f16)o3};
    *(h4*)((f16*)out + (size_t)r * 1024 + tid * 4) = o;
  } else {
    *(float4*)((float*)out + (size_t)r * 1024 + tid * 4) = make_float4(o0, o1, o2, o3);
  }
}

// ------- silu + l2norm epilogue; writes q/k/v CHUNK-SWIZZLED ---------------
__global__ __launch_bounds__(256) void qkv_epi(const f16* __restrict__ qkv, f16* __restrict__ qb,
                                               f16* __restrict__ kb, f16* __restrict__ vb) {
  const int r = blockIdx.x, tid = threadIdx.x;
  const int head = tid >> 5, l32 = tid & 31;
  const int i = (r >> 2) & 63;              // row within chunk
  const size_t src = (size_t)r * 3072 + head * 128 + l32 * 4;
  {  // q
    const h4 v = *(const h4*)(qkv + src);
    float s0 = siluf((float)v[0]), s1 = siluf((float)v[1]), s2 = siluf((float)v[2]), s3 = siluf((float)v[3]);
    float ss = s0 * s0 + s1 * s1 + s2 * s2 + s3 * s3;
#pragma unroll
    for (int m = 1; m <= 16; m <<= 1) ss += __shfl_xor(ss, m);
    const float sc = rsqrtf(ss + 1e-6f);
    h4 o = {(f16)(s0 * sc), (f16)(s1 * sc), (f16)(s2 * sc), (f16)(s3 * sc)};
    const int c = l32 >> 1, off = (l32 & 1) * 4;
    *(h4*)(qb + (size_t)r * 1024 + head * 128 + swz16(i, c) * 8 + off) = o;
  }
  {  // k
    const h4 v = *(const h4*)(qkv + src + 1024);
    float s0 = siluf((float)v[0]), s1 = siluf((float)v[1]), s2 = siluf((float)v[2]), s3 = siluf((float)v[3]);
    float ss = s0 * s0 + s1 * s1 + s2 * s2 + s3 * s3;
#pragma unroll
    for (int m = 1; m <= 16; m <<= 1) ss += __shfl_xor(ss, m);
    const float sc = rsqrtf(ss + 1e-6f);
    h4 o = {(f16)(s0 * sc), (f16)(s1 * sc), (f16)(s2 * sc), (f16)(s3 * sc)};
    const int c = l32 >> 1, off = (l32 & 1) * 4;
    *(h4*)(kb + (size_t)r * 1024 + head * 128 + swz16(i, c) * 8 + off) = o;
  }
  {  // v
    const h4 v = *(const h4*)(qkv + (size_t)r * 3072 + 2048 + tid * 4);
    h4 o = {(f16)siluf((float)v[0]), (f16)siluf((float)v[1]), (f16)siluf((float)v[2]), (f16)siluf((float)v[3])};
    const int hd = tid >> 5, dh = (tid & 31) * 4;
    const int c = dh >> 3, off = dh & 7;
    *(h4*)(vb + (size_t)r * 1024 + hd * 128 + swz16(i, c) * 8 + off) = o;
  }
}

// ---------------- per-head RMSNorm (obuf f16 in) ---------------------------
__global__ __launch_bounds__(256) void onorm_k(const f16* __restrict__ o, const float* __restrict__ w,
                                               f16* __restrict__ ob) {
  const int r = blockIdx.x, tid = threadIdx.x;
  const int head = tid >> 5, l32 = tid & 31;
  const size_t base = (size_t)r * 1024 + head * 128 + l32 * 4;
  const h4 xv = *(const h4*)(o + base);
  const float v0 = (float)xv[0], v1 = (float)xv[1], v2 = (float)xv[2], v3 = (float)xv[3];
  float ss = v0 * v0 + v1 * v1 + v2 * v2 + v3 * v3;
#pragma unroll
  for (int m = 1; m <= 16; m <<= 1) ss += __shfl_xor(ss, m);
  const float sc = rsqrtf(ss * (1.f / 128.f) + 1e-6f);
  const float4 w4 = *(const float4*)(w + l32 * 4);
  h4 out = {(f16)(v0 * sc * w4.x), (f16)(v1 * sc * w4.y), (f16)(v2 * sc * w4.z), (f16)(v3 * sc * w4.w)};
  *(h4*)(ob + base) = out;
}

// ---------------- beta = 2*sigmoid(h @ Wb) ---------------------------------
__global__ __launch_bounds__(256) void beta_k(const f16* __restrict__ hb, const float* __restrict__ Wb,
                                              float* __restrict__ beta) {
  const int tid = threadIdx.x, lane = tid & 63, wv = tid >> 6;
  const int r = blockIdx.x * 4 + wv;
  const f16* row = hb + (size_t)r * 1024 + lane * 16;
  const h8 v0 = *(const h8*)(row);
  const h8 v1 = *(const h8*)(row + 8);
  const float* wb = Wb + (size_t)(lane * 16) * 8;
  float acc[8] = {};
#pragma unroll
  for (int e = 0; e < 8; ++e) {
    const float x0 = (float)v0[e], x1 = (float)v1[e];
    const float4 w0a = *(const float4*)(wb + e * 8);
    const float4 w0b = *(const float4*)(wb + e * 8 + 4);
    const float4 w1a = *(const float4*)(wb + (e + 8) * 8);
    const float4 w1b = *(const float4*)(wb + (e + 8) * 8 + 4);
    acc[0] += x0 * w0a.x + x1 * w1a.x;  acc[1] += x0 * w0a.y + x1 * w1a.y;
    acc[2] += x0 * w0a.z + x1 * w1a.z;  acc[3] += x0 * w0a.w + x1 * w1a.w;
    acc[4] += x0 * w0b.x + x1 * w1b.x;  acc[5] += x0 * w0b.y + x1 * w1b.y;
    acc[6] += x0 * w0b.z + x1 * w1b.z;  acc[7] += x0 * w0b.w + x1 * w1b.w;
  }
#pragma unroll
  for (int j = 0; j < 8; ++j)
#pragma unroll
    for (int m = 1; m < 64; m <<= 1) acc[j] += __shfl_xor(acc[j], m);
  if (lane == 0) {
#pragma unroll
    for (int j = 0; j < 8; ++j) beta[(size_t)r * 8 + j] = 2.f / (1.f + expf(-acc[j]));
  }
}

// ---------------- W[K][N] f32 -> Wt[N][K] f16 ------------------------------
__global__ __launch_bounds__(256) void transpose_k(const float* __restrict__ W, f16* __restrict__ Wt,
                                                   int K, int N) {
  __shared__ float tile[32][33];
  const int n0 = blockIdx.x * 32, k0 = blockIdx.y * 32;
  const int tx = threadIdx.x & 31, ty = threadIdx.x >> 5;
#pragma unroll
  for (int i = 0; i < 32; i += 8) tile[ty + i][tx] = W[(size_t)(k0 + ty + i) * N + n0 + tx];
  __syncthreads();
#pragma unroll
  for (int i = 0; i < 32; i += 8) Wt[(size_t)(n0 + ty + i) * K + k0 + tx] = (f16)tile[tx][ty + i];
}

__global__ void fill_k(float* p, int n, float v) {
  const int i = blockIdx.x * 256 + threadIdx.x;
  if (i < n) p[i] = v;
}

// ---------------- Phase A: WY transform ------------------------------------
DEV f4 mm16(const f16* A, int as, const f16* B, f4 c, int l15, int l4) {
  h4 a = *(const h4*)(A + l15 * as + l4 * 4);
  h4 b = *(const h4*)(B + l15 * 20 + l4 * 4);
  return __builtin_amdgcn_mfma_f32_16x16x16f16(a, b, c, 0, 0, 0);
}
DEV void wr_T(f16* slot, f4 acc, int l15, int l4, float sgn) {
  h4 v = {(f16)(sgn * acc[0]), (f16)(sgn * acc[1]), (f16)(sgn * acc[2]), (f16)(sgn * acc[3])};
  *(h4*)(slot + l15 * 20 + l4 * 4) = v;
}
DEV void wr_Tb(f16* Tb, int bi, int bj, f4 acc, const float* betas, int l15, int l4, float sgn) {
  const float bc = betas[bj * 16 + l15];
#pragma unroll
  for (int q = 0; q < 4; ++q)
    Tb[(bi * 16 + l4 * 4 + q) * 72 + bj * 16 + l15] = (f16)(sgn * acc[q] * bc);
}

__global__ __launch_bounds__(256) void phaseA(const f16* __restrict__ kb, const f16* __restrict__ qb,
                                              const f16* __restrict__ vb, const float* __restrict__ beta,
                                              f16* __restrict__ wbuf, f16* __restrict__ utbuf,
                                              f16* __restrict__ pbuf, f16* __restrict__ ktbuf) {
  const int blk = blockIdx.x;
  const int c = blk >> 5, bh = blk & 31;
  const int b = bh >> 3, h = bh & 7;
  const int tid = threadIdx.x, lane = tid & 63, wv = tid >> 6;
  const int l15 = lane & 15, l4 = lane >> 4;

  __shared__ __align__(16) f16 Ks[64 * 128];
  __shared__ __align__(16) f16 QVs[64 * 128];
  __shared__ __align__(16) f16 Abuf[64 * 68];
  __shared__ __align__(16) f16 Dr[4][16 * 20];
  __shared__ __align__(16) f16 Dt[4][16 * 20];
  __shared__ __align__(16) f16 Tp[3][16 * 20];
  __shared__ __align__(16) f16 Xp[3][16 * 20];
  __shared__ __align__(16) f16 Tb[64 * 72];
  __shared__ float betas[64];

  const size_t rowstr = (size_t)Bb_ * Dd;
  const size_t gbase = ((size_t)(c * 64) * Bb_ + b) * Dd + h * 128;

  // linear copies preserve the global chunk swizzle
#pragma unroll
  for (int i = 0; i < 4; ++i) {
    const int ch = tid + i * 256;
    const int rr = ch >> 4, kc = ch & 15;
    *(h8*)(Ks + ch * 8) = *(const h8*)(kb + gbase + (size_t)rr * rowstr + kc * 8);
    *(h8*)(QVs + ch * 8) = *(const h8*)(qb + gbase + (size_t)rr * rowstr + kc * 8);
  }
  for (int i = tid; i < 64 * 72; i += 256) Tb[i] = (f16)0.f;
  if (tid < 64) betas[tid] = beta[((size_t)(c * 64 + tid) * Bb_ + b) * Hh + h];
  __syncthreads();

  f4 accS[4] = {}, accP[4] = {};
  const int arow = wv * 16 + l15;
#pragma unroll
  for (int kc = 0; kc < 4; ++kc) {
    const int c4 = kc * 4 + l4;
    const h8 aK = *(const h8*)(Ks + arow * 128 + swz16(arow, c4) * 8);
    const h8 aQ = *(const h8*)(QVs + arow * 128 + swz16(arow, c4) * 8);
#pragma unroll
    for (int f = 0; f < 4; ++f) {
      const int brow = f * 16 + l15;
      const h8 bK = *(const h8*)(Ks + brow * 128 + swz16(brow, c4) * 8);
      accS[f] = __builtin_amdgcn_mfma_f32_16x16x32_f16(aK, bK, accS[f], 0, 0, 0);
      accP[f] = __builtin_amdgcn_mfma_f32_16x16x32_f16(aQ, bK, accP[f], 0, 0, 0);
    }
  }
  const size_t pbase = (((size_t)bh * NC + c) * 64) * 64;
#pragma unroll
  for (int f = 0; f < 4; ++f) {
#pragma unroll
    for (int q = 0; q < 4; ++q) {
      const int i = wv * 16 + l4 * 4 + q;
      const int j = f * 16 + l15;
      Abuf[i * 68 + j] = (f16)((j < i) ? betas[i] * accS[f][q] : 0.f);
      pbuf[pbase + (size_t)i * 64 + j] = (f16)((j <= i) ? accP[f][q] : 0.f);
    }
  }
  __syncthreads();

#pragma unroll
  for (int i = 0; i < 4; ++i) {
    const int ch = tid + i * 256;
    const int rr = ch >> 4, kc = ch & 15;
    *(h8*)(QVs + ch * 8) = *(const h8*)(vb + gbase + (size_t)rr * rowstr + kc * 8);
  }

  {
    const int bi = wv;
    const int cc = l15;
    const f16* Ad = Abuf + (bi * 16) * 68 + bi * 16;
    float t[16];
    t[0] = (cc == 0) ? 1.f : 0.f;
#pragma unroll
    for (int i = 1; i < 16; ++i) {
      float s = (cc == i) ? 1.f : 0.f;
#pragma unroll
      for (int j = 0; j < i; ++j) s -= (float)Ad[i * 68 + j] * t[j];
      t[i] = s;
    }
    if (lane < 16) {
#pragma unroll
      for (int j4 = 0; j4 < 4; ++j4) {
        h4 v = {(f16)t[j4 * 4], (f16)t[j4 * 4 + 1], (f16)t[j4 * 4 + 2], (f16)t[j4 * 4 + 3]};
        *(h4*)(&Dt[bi][cc * 20 + j4 * 4]) = v;
      }
      const float bc = betas[bi * 16 + cc];
#pragma unroll
      for (int j = 0; j < 16; ++j) {
        Dr[bi][j * 20 + cc] = (f16)t[j];
        Tb[(bi * 16 + j) * 72 + bi * 16 + cc] = (f16)(t[j] * bc);
      }
    }
  }
  __syncthreads();

  const f16* AB10 = Abuf + 16 * 68 + 0;
  const f16* AB20 = Abuf + 32 * 68 + 0;
  const f16* AB21 = Abuf + 32 * 68 + 16;
  const f16* AB30 = Abuf + 48 * 68 + 0;
  const f16* AB31 = Abuf + 48 * 68 + 16;
  const f16* AB32 = Abuf + 48 * 68 + 32;
  f4 z = {};
  f4 x20, x30;

  if (wv == 0) wr_T(Xp[0], mm16(AB10, 68, Dt[0], z, l15, l4), l15, l4, 1.f);
  if (wv == 1) wr_T(Xp[1], mm16(AB21, 68, Dt[1], z, l15, l4), l15, l4, 1.f);
  if (wv == 2) wr_T(Xp[2], mm16(AB32, 68, Dt[2], z, l15, l4), l15, l4, 1.f);
  if (wv == 3) x20 = mm16(AB20, 68, Dt[0], z, l15, l4);
  __syncthreads();
  if (wv == 0) { f4 r = mm16(Dr[1], 20, Xp[0], z, l15, l4); wr_T(Tp[0], r, l15, l4, -1.f); wr_Tb(Tb, 1, 0, r, betas, l15, l4, -1.f); }
  if (wv == 1) { f4 r = mm16(Dr[2], 20, Xp[1], z, l15, l4); wr_T(Tp[1], r, l15, l4, -1.f); wr_Tb(Tb, 2, 1, r, betas, l15, l4, -1.f); }
  if (wv == 2) { f4 r = mm16(Dr[3], 20, Xp[2], z, l15, l4); wr_Tb(Tb, 3, 2, r, betas, l15, l4, -1.f); }
  if (wv == 3) x30 = mm16(AB30, 68, Dt[0], z, l15, l4);
  __syncthreads();
  if (wv == 3) wr_T(Xp[0], mm16(AB21, 68, Tp[0], x20, l15, l4), l15, l4, 1.f);
  if (wv == 1) { f4 r = mm16(AB31, 68, Dt[1], z, l15, l4); r = mm16(AB32, 68, Tp[1], r, l15, l4); wr_T(Xp[1], r, l15, l4, 1.f); }
  __syncthreads();
  if (wv == 3) { f4 r = mm16(Dr[2], 20, Xp[0], z, l15, l4); wr_T(Tp[2], r, l15, l4, -1.f); wr_Tb(Tb, 2, 0, r, betas, l15, l4, -1.f); }
  if (wv == 1) { f4 r = mm16(Dr[3], 20, Xp[1], z, l15, l4); wr_Tb(Tb, 3, 1, r, betas, l15, l4, -1.f); }
  __syncthreads();
  if (wv == 3) { f4 r = mm16(AB31, 68, Tp[0], x30, l15, l4); r = mm16(AB32, 68, Tp[2], r, l15, l4); wr_T(Xp[2], r, l15, l4, 1.f); }
  __syncthreads();
  if (wv == 3) { f4 r = mm16(Dr[3], 20, Xp[2], z, l15, l4); wr_Tb(Tb, 3, 0, r, betas, l15, l4, -1.f); }
  __syncthreads();

  // ---- w = Tb K, u = Tb V ----
  const size_t wub = ((size_t)bh * NC + c) * 8192;
  const int koff = l4 * 8;
  f4 wacc[8] = {}, uacc[8] = {};
#pragma unroll
  for (int kc = 0; kc < 2; ++kc) {
    const h8 aT = *(const h8*)(Tb + (wv * 16 + l15) * 72 + kc * 32 + koff);
#pragma unroll
    for (int f = 0; f < 8; ++f) {
      const int d = f * 16 + l15, cD = d >> 3, d7 = d & 7;
      h8 bK, bV;
#pragma unroll
      for (int j = 0; j < 8; ++j) {
        const int t2 = kc * 32 + koff + j;
        const int pos = t2 * 128 + swz16(t2, cD) * 8 + d7;
        bK[j] = Ks[pos];
        bV[j] = QVs[pos];
      }
      wacc[f] = __builtin_amdgcn_mfma_f32_16x16x32_f16(aT, bK, wacc[f], 0, 0, 0);
      uacc[f] = __builtin_amdgcn_mfma_f32_16x16x32_f16(aT, bV, uacc[f], 0, 0, 0);
    }
  }
#pragma unroll
  for (int f = 0; f < 8; ++f) {
    const int d = f * 16 + l15, cD = d >> 3, d7 = d & 7;
#pragma unroll
    for (int q = 0; q < 4; ++q) {
      const int i = wv * 16 + l4 * 4 + q;
      wbuf[wub + (size_t)i * 128 + swz16(i, cD) * 8 + d7] = (f16)wacc[f][q];  // swizzled
    }
    h4 uv = {(f16)uacc[f][0], (f16)uacc[f][1], (f16)uacc[f][2], (f16)uacc[f][3]};
    *(h4*)(utbuf + wub + (size_t)d * 64 + wv * 16 + l4 * 4) = uv;            // u^T
  }

  // ---- K^T export (swizzled for phaseB column reads) ----
#pragma unroll
  for (int i2 = 0; i2 < 4; ++i2) {
    const int ch = tid + i2 * 256;      // 0..1023
    const int dp = ch & 127, c2 = ch >> 7;  // row d', i-chunk
    h8 v;
#pragma unroll
    for (int j = 0; j < 8; ++j) {
      const int i = c2 * 8 + j;
      v[j] = Ks[i * 128 + swz16(i, dp >> 3) * 8 + (dp & 7)];
    }
    *(h8*)(ktbuf + wub + (size_t)dp * 64 + (c2 ^ (dp & 7)) * 8) = v;
  }
}

// ---------------- Phase B: chunk recurrence (conflict-free LDS) ------------
__global__ __launch_bounds__(256) void phaseB(const f16* __restrict__ qb, const f16* __restrict__ ktbuf,
                                              const f16* __restrict__ wbuf, const f16* __restrict__ utbuf,
                                              const f16* __restrict__ pbuf, f16* __restrict__ obuf) {
  const int blk = blockIdx.x;
  const int bh = blk >> 2, g = blk & 3;
  const int b = bh >> 3, h = bh & 7;
  const int tid = threadIdx.x, lane = tid & 63, wv = tid >> 6;
  const int l15 = lane & 15, l4 = lane >> 4;

  __shared__ __align__(16) f16 Ws[2][8192];
  __shared__ __align__(16) f16 Qs[2][8192];
  __shared__ __align__(16) f16 Kts[2][8192];
  __shared__ __align__(16) f16 Rt[32 * 72];
  __shared__ __align__(16) f16 Ms[32 * 136];

  for (int i = tid; i < 32 * 136; i += 256) Ms[i] = (f16)0.f;
  f4 macc[2][2] = {};

  const int arow = wv * 16 + l15;
  const int koff = l4 * 8;

  auto STAGE = [&](int c2, int buf) {
#pragma unroll
    for (int i = 0; i < 4; ++i) {
      const int ch = tid + i * 256;
      const size_t tb = ((size_t)bh * NC + c2) * 8192;
      __builtin_amdgcn_global_load_lds(AS1(wbuf + tb + ch * 8), AS3(Ws[buf] + ch * 8), 16, 0, 0);
      __builtin_amdgcn_global_load_lds(AS1(ktbuf + tb + ch * 8), AS3(Kts[buf] + ch * 8), 16, 0, 0);
      const int rr = ch >> 4, kc2 = ch & 15;
      __builtin_amdgcn_global_load_lds(AS1(qb + ((size_t)((c2 * 64 + rr) * 4 + b)) * 1024 + h * 128 + kc2 * 8),
                                       AS3(Qs[buf] + ch * 8), 16, 0, 0);
    }
  };

  STAGE(0, 0);
  asm volatile("s_waitcnt vmcnt(0)" ::: "memory");
  __builtin_amdgcn_s_barrier();

  for (int c = 0; c < NC; ++c) {
    const int cur = c & 1, nxt = cur ^ 1;
    // P, u -> regs (4 VMEM ops, issued before the top wait)
    const size_t pcb = ((size_t)bh * NC + c) * 4096;
    const h8 aP0 = *(const h8*)(pbuf + pcb + arow * 64 + koff);
    const h8 aP1 = *(const h8*)(pbuf + pcb + arow * 64 + 32 + koff);
    const size_t ucb = ((size_t)bh * NC + c) * 8192;
    const h4 u0 = *(const h4*)(utbuf + ucb + (size_t)(g * 32 + l15) * 64 + wv * 16 + l4 * 4);
    const h4 u1 = *(const h4*)(utbuf + ucb + (size_t)(g * 32 + 16 + l15) * 64 + wv * 16 + l4 * 4);
    asm volatile("s_waitcnt vmcnt(4)" ::: "memory");   // prev stage (12) retired
    asm volatile("s_waitcnt lgkmcnt(0)" ::: "memory"); // Ms export visible
    __builtin_amdgcn_s_barrier();
    if (c + 1 < NC) STAGE(c + 1, nxt);

    // phase1: accR = w@S, accO = Q@S
    f4 accR[2] = {}, accO[2] = {};
    __builtin_amdgcn_s_setprio(1);
#pragma unroll
    for (int kc = 0; kc < 4; ++kc) {
      const int c4 = kc * 4 + l4;
      const h8 aW = *(const h8*)(Ws[cur] + arow * 128 + swz16(arow, c4) * 8);
      const h8 aQ = *(const h8*)(Qs[cur] + arow * 128 + swz16(arow, c4) * 8);
#pragma unroll
      for (int f = 0; f < 2; ++f) {
        const h8 bM = *(const h8*)(Ms + (f * 16 + l15) * 136 + kc * 32 + koff);
        accR[f] = __builtin_amdgcn_mfma_f32_16x16x32_f16(aW, bM, accR[f], 0, 0, 0);
        accO[f] = __builtin_amdgcn_mfma_f32_16x16x32_f16(aQ, bM, accO[f], 0, 0, 0);
      }
    }
    __builtin_amdgcn_s_setprio(0);
    if (c + 1 < NC) asm volatile("s_waitcnt vmcnt(12)" ::: "memory");  // u,P arrived
    else            asm volatile("s_waitcnt vmcnt(0)" ::: "memory");
#pragma unroll
    for (int f = 0; f < 2; ++f) {
      const h4 uu = f ? u1 : u0;
      h4 rw;
#pragma unroll
      for (int q = 0; q < 4; ++q) {
        const float rv = (float)uu[q] - accR[f][q];
        accR[f][q] = rv;
        rw[q] = (f16)rv;
      }
      *(h4*)(Rt + (f * 16 + l15) * 72 + wv * 16 + l4 * 4) = rw;
    }
    asm volatile("s_waitcnt lgkmcnt(0)" ::: "memory");
    __builtin_amdgcn_s_barrier();

    // phase2: accO += P@R
#pragma unroll
    for (int kc = 0; kc < 2; ++kc) {
      const h8 aP = kc ? aP1 : aP0;
#pragma unroll
      for (int f = 0; f < 2; ++f) {
        const h8 bR = *(const h8*)(Rt + (f * 16 + l15) * 72 + kc * 32 + koff);
        accO[f] = __builtin_amdgcn_mfma_f32_16x16x32_f16(aP, bR, accO[f], 0, 0, 0);
      }
    }
#pragma unroll
    for (int f = 0; f < 2; ++f)
#pragma unroll
      for (int q = 0; q < 4; ++q) {
        const int i = wv * 16 + l4 * 4 + q;
        const int cc = f * 16 + l15;
        obuf[((size_t)(c * 64 + i) * Bb_ + b) * Dd + h * 128 + g * 32 + cc] = (f16)accO[f][q];
      }

    // macc: M += R^T K  (bKv from swizzled K^T tile)
#pragma unroll
    for (int kc = 0; kc < 2; ++kc) {
      const h8 aR0 = *(const h8*)(Rt + l15 * 72 + kc * 32 + koff);
      const h8 aR1 = *(const h8*)(Rt + (16 + l15) * 72 + kc * 32 + koff);
#pragma unroll
      for (int cf = 0; cf < 2; ++cf) {
        const int kcol = wv * 32 + cf * 16 + l15;
        const int c2 = kc * 4 + l4;
        const h8 bKv = *(const h8*)(Kts[cur] + kcol * 64 + (c2 ^ (kcol & 7)) * 8);
        macc[0][cf] = __builtin_amdgcn_mfma_f32_16x16x32_f16(aR0, bKv, macc[0][cf], 0, 0, 0);
        macc[1][cf] = __builtin_amdgcn_mfma_f32_16x16x32_f16(aR1, bKv, macc[1][cf], 0, 0, 0);
      }
    }
#pragma unroll
    for (int rf = 0; rf < 2; ++rf)
#pragma unroll
      for (int cf = 0; cf < 2; ++cf)
#pragma unroll
        for (int q = 0; q < 4; ++q) {
          const int cr = rf * 16 + l4 * 4 + q;
          const int kcol = wv * 32 + cf * 16 + l15;
          Ms[cr * 136 + kcol] = (f16)macc[rf][cf][q];
        }
    // next-iteration top lgkm+barrier protects Ms/Rt reuse
  }
}

// ---------------------------------------------------------------------------
extern "C" void kernel_launch(void* const* d_in, const int* in_sizes, int n_in,
                              void* d_out, int out_size, void* d_ws, size_t ws_size,
                              hipStream_t stream) {
  (void)in_sizes; (void)n_in;
  const float* input = (const float*)d_in[0];
  const float* Wq = (const float*)d_in[1];
  const float* Wk = (const float*)d_in[2];
  const float* Wv = (const float*)d_in[3];
  const float* Wb = (const float*)d_in[4];
  const float* Wo = (const float*)d_in[5];
  const float* onw = (const float*)d_in[6];
  const float* n1w = (const float*)d_in[7];
  const float* n2w = (const float*)d_in[8];
  const float* Wg = (const float*)d_in[9];
  const float* Wd = (const float*)d_in[10];
  const float* fnw = (const float*)d_in[11];

  char* ws = (char*)d_ws;
  size_t off = 0;
  auto alloc = [&](size_t bytes) { void* p = ws + off; off += (bytes + 255) & ~(size_t)255; return p; };
  const size_t RD = 8192ull * 1024ull;
  f16*  x     = (f16*)alloc(RD * 2);
  f16*  hb    = (f16*)alloc(RD * 2);
  f16*  qb    = (f16*)alloc(RD * 2);
  f16*  kbuf  = (f16*)alloc(RD * 2);
  f16*  vbuf  = (f16*)alloc(RD * 2);
  float* beta = (float*)alloc(8192ull * 8 * 4);
  f16*  wbuf  = (f16*)alloc(RD * 2);
  f16*  utbuf = (f16*)alloc(RD * 2);
  f16*  ktbuf = (f16*)alloc(RD * 2);
  f16*  pbuf  = (f16*)alloc(32ull * 32 * 64 * 64 * 2);
  char* arena = (char*)alloc(3 * RD * 2);
  f16*  WqkvT = (f16*)alloc(3072ull * 1024 * 2);
  f16*  WoT   = (f16*)alloc(1024ull * 1024 * 2);
  f16*  WgT   = (f16*)alloc(5632ull * 1024 * 2);
  f16*  WdT   = (f16*)alloc(1024ull * 2816 * 2);
  if (off > ws_size) {
    fill_k<<<(out_size + 255) / 256, 256, 0, stream>>>((float*)d_out, out_size, 1.0e6f);
    return;
  }
  f16* qkvraw = (f16*)arena;
  f16* obuf = (f16*)arena;
  f16* Ybuf = (f16*)arena;
  f16* my = qb;
  f16* ob = wbuf;   // wbuf dead after phaseB; onorm/gemm use it linearly

  cvt_k<<<4096, 256, 0, stream>>>(input, x);

  for (int l = 0; l < 2; ++l) {
    const size_t o2 = (size_t)l * 1024 * 1024;
    transpose_k<<<dim3(32, 32), 256, 0, stream>>>(Wq + o2, WqkvT, 1024, 1024);
    transpose_k<<<dim3(32, 32), 256, 0, stream>>>(Wk + o2, WqkvT + 1024ull * 1024, 1024, 1024);
    transpose_k<<<dim3(32, 32), 256, 0, stream>>>(Wv + o2, WqkvT + 2048ull * 1024, 1024, 1024);
    transpose_k<<<dim3(32, 32), 256, 0, stream>>>(Wo + o2, WoT, 1024, 1024);
    transpose_k<<<dim3(176, 32), 256, 0, stream>>>(Wg + (size_t)l * 1024 * 5632, WgT, 1024, 5632);
    transpose_k<<<dim3(32, 88), 256, 0, stream>>>(Wd + (size_t)l * 2816 * 1024, WdT, 2816, 1024);

    rmsnorm_k<1><<<8192, 256, 0, stream>>>(x, n1w + l * 1024, hb);
    gemm2<2, 256><<<32 * 12, 512, 0, stream>>>(hb, WqkvT, qkvraw, nullptr, 8192, 3072, 1024, 12);
    beta_k<<<2048, 256, 0, stream>>>(hb, Wb + (size_t)l * 1024 * 8, beta);
    qkv_epi<<<8192, 256, 0, stream>>>(qkvraw, qb, kbuf, vbuf);
    phaseA<<<1024, 256, 0, stream>>>(kbuf, qb, vbuf, beta, wbuf, utbuf, pbuf, ktbuf);
    phaseB<<<128, 256, 0, stream>>>(qb, ktbuf, wbuf, utbuf, pbuf, obuf);
    onorm_k<<<8192, 256, 0, stream>>>(obuf, onw + l * 128, ob);
    gemm2<1, 128><<<32 * 8, 512, 0, stream>>>(ob, WoT, x, nullptr, 8192, 1024, 1024, 8);

    rmsnorm_k<1><<<8192, 256, 0, stream>>>(x, n2w + l * 1024, hb);
    gemm2<2, 256><<<32 * 11, 512, 0, stream>>>(hb, WgT + 2816ull * 1024, Ybuf, nullptr, 8192, 2816, 1024, 11);
    gemm2<3, 256><<<32 * 11, 512, 0, stream>>>(hb, WgT, my, Ybuf, 8192, 2816, 1024, 11);
    gemm2<1, 128><<<32 * 8, 512, 0, stream>>>(my, WdT, x, nullptr, 8192, 1024, 2816, 8);
  }
  rmsnorm_k<0><<<8192, 256, 0, stream>>>(x, fnw, d_out);
}

// Round 9
// 993.713 us; speedup vs baseline: 1.7319x; 1.0712x over previous
//
#include <hip/hip_runtime.h>
#include <hip/hip_bf16.h>
#include <cstdint>

// DeltaNet forward, MI355X. Round 9: fused GLU GEMM (g+y one pass, no Y HBM
// round-trip), QKV BN=128 (exact 3 rounds), mid-barrier removed (4/tile),
// hoisted stage addressing.

typedef _Float16 f16;
typedef __attribute__((ext_vector_type(8))) _Float16 h8;
typedef __attribute__((ext_vector_type(4))) _Float16 h4;
typedef __attribute__((ext_vector_type(4))) float f4;

#define DEV __device__ __forceinline__

static constexpr int Bb_ = 4;
static constexpr int Hh  = 8;
static constexpr int Dd  = 1024;
static constexpr int Tt  = 2048;
static constexpr int NC  = 32;

DEV float siluf(float x) { return x / (1.f + expf(-x)); }
DEV int swz16(int row, int c) { return (c & 8) | ((c & 7) ^ (row & 7)); }

#define AS1(p) ((const __attribute__((address_space(1))) void*)(uintptr_t)(p))
#define AS3(p) ((__attribute__((address_space(3))) void*)(uint32_t)(uintptr_t)(p))

DEV h8 rd_sw(const f16* T, int row, int chunk) {
  return *(const h8*)(T + (((row << 3) | (chunk ^ (row & 7))) * 8));
}

// ================= 8-phase GEMM: C[M,N] op= A[M,K]*Bt[N,K]^T ================
// EPI 0: f32 store; 1: f16 +=; 2: f16 store.
template<int EPI, int BN>
__global__ __launch_bounds__(512, 2) void gemm2(const f16* __restrict__ A, const f16* __restrict__ Bt,
                                                void* __restrict__ C, int M, int N, int K, int gx) {
  __shared__ __align__(16) f16 ldsA[2][16384];
  __shared__ __align__(16) f16 ldsB[2][BN * 64];
  const int tid = threadIdx.x, lane = tid & 63, w = tid >> 6;
  const int l15 = lane & 15, l4 = lane >> 4;
  const int wr = w >> 2, wc = w & 3;
  const int nwg = gridDim.x;
  int flat = blockIdx.x;
  if ((nwg & 7) == 0) flat = (flat & 7) * (nwg >> 3) + (flat >> 3);
  const int bx = flat % gx, by = flat / gx;

  const f16* Ab = A + (size_t)by * 256 * K;
  const f16* Bb = Bt + (size_t)bx * BN * K;
  const int NT = K >> 6;
  constexpr int NCF = BN / 64;
  f4 acc[8][NCF] = {};

  // thread-invariant staging offsets (half = 128 rows x 64 cols, 1024 chunks)
  const int r0 = tid >> 3;
  const size_t soff0 = (size_t)r0 * K + (size_t)(((tid & 7) ^ (r0 & 7)) * 8);
  const size_t soff1 = soff0 + (size_t)64 * K;
  const int dof = tid * 8;
  auto STG = [&](const f16* base, f16* dst) {   // one 128x64 half
    __builtin_amdgcn_global_load_lds(AS1(base + soff0), AS3(dst + dof), 16, 0, 0);
    __builtin_amdgcn_global_load_lds(AS1(base + soff1), AS3(dst + 4096 + dof), 16, 0, 0);
  };

  // ---- prologue ----
  STG(Bb, ldsB[0]);
  if (BN == 256) STG(Bb + (size_t)128 * K, ldsB[0] + 8192);
  STG(Ab, ldsA[0]);
  STG(Ab + (size_t)128 * K, ldsA[0] + 8192);
  if (NT > 1) {
    STG(Bb + 64, ldsB[1]);
    if (BN == 256) STG(Bb + (size_t)128 * K + 64, ldsB[1] + 8192);
    if (BN == 256) asm volatile("s_waitcnt vmcnt(4)");
    else           asm volatile("s_waitcnt vmcnt(2)");
  } else {
    asm volatile("s_waitcnt vmcnt(0)");
  }
  __builtin_amdgcn_s_barrier();

  for (int t = 0; t < NT; ++t) {
    const int cur = t & 1, nxt = cur ^ 1;
    const f16* cA = ldsA[cur];
    const f16* cB = ldsB[cur];
    h8 b[NCF][2];
    h8 a[2][2];
#pragma unroll
    for (int cf = 0; cf < NCF; ++cf)
#pragma unroll
      for (int ks = 0; ks < 2; ++ks)
        b[cf][ks] = rd_sw(cB, wc * (BN / 4) + cf * 16 + l15, ks * 4 + l4);
#pragma unroll
    for (int fr = 0; fr < 2; ++fr)
#pragma unroll
      for (int ks = 0; ks < 2; ++ks)
        a[fr][ks] = rd_sw(cA, wr * 128 + fr * 16 + l15, ks * 4 + l4);
    if (t + 1 < NT) STG(Ab + (t + 1) * 64, ldsA[nxt]);
    asm volatile("s_waitcnt lgkmcnt(0)");
    __builtin_amdgcn_s_setprio(1);
#pragma unroll
    for (int fr = 0; fr < 2; ++fr)
#pragma unroll
      for (int cf = 0; cf < NCF; ++cf)
#pragma unroll
        for (int ks = 0; ks < 2; ++ks)
          acc[fr][cf] = __builtin_amdgcn_mfma_f32_16x16x32_f16(a[fr][ks], b[cf][ks], acc[fr][cf], 0, 0, 0);
    __builtin_amdgcn_s_setprio(0);
    __builtin_amdgcn_s_barrier();
#pragma unroll
    for (int p = 1; p < 4; ++p) {
#pragma unroll
      for (int fr = 0; fr < 2; ++fr)
#pragma unroll
        for (int ks = 0; ks < 2; ++ks)
          a[fr][ks] = rd_sw(cA, wr * 128 + p * 32 + fr * 16 + l15, ks * 4 + l4);
      if (p == 1 && t + 1 < NT) STG(Ab + (size_t)128 * K + (t + 1) * 64, ldsA[nxt] + 8192);
      if (p == 2 && t + 2 < NT) STG(Bb + (t + 2) * 64, ldsB[cur]);
      if (BN == 256 && p == 3 && t + 2 < NT) STG(Bb + (size_t)128 * K + (t + 2) * 64, ldsB[cur] + 8192);
      asm volatile("s_waitcnt lgkmcnt(0)");
      __builtin_amdgcn_s_setprio(1);
#pragma unroll
      for (int fr = 0; fr < 2; ++fr)
#pragma unroll
        for (int cf = 0; cf < NCF; ++cf)
#pragma unroll
          for (int ks = 0; ks < 2; ++ks)
            acc[p * 2 + fr][cf] = __builtin_amdgcn_mfma_f32_16x16x32_f16(a[fr][ks], b[cf][ks], acc[p * 2 + fr][cf], 0, 0, 0);
      __builtin_amdgcn_s_setprio(0);
      if (p == 3) {
        if (t + 2 < NT) {
          if (BN == 256) asm volatile("s_waitcnt vmcnt(4)");
          else           asm volatile("s_waitcnt vmcnt(2)");
        } else if (t + 1 < NT) {
          asm volatile("s_waitcnt vmcnt(0)");
        }
      }
      __builtin_amdgcn_s_barrier();
    }
  }

#pragma unroll
  for (int fr = 0; fr < 8; ++fr) {
#pragma unroll
    for (int cf = 0; cf < NCF; ++cf) {
      const int row0 = by * 256 + wr * 128 + fr * 16 + l4 * 4;
      const int col = bx * BN + wc * (BN / 4) + cf * 16 + l15;
#pragma unroll
      for (int q = 0; q < 4; ++q) {
        const size_t idx = (size_t)(row0 + q) * N + col;
        const float v = acc[fr][cf][q];
        if (EPI == 0) ((float*)C)[idx] = v;
        if (EPI == 1) ((f16*)C)[idx] = (f16)((float)((f16*)C)[idx] + v);
        if (EPI == 2) ((f16*)C)[idx] = (f16)v;
      }
    }
  }
}

// ============ fused GLU GEMM: my = silu(A Wg_g^T) * (A Wg_y^T) ==============
// per block: g-tile 256x128 and y-tile 256x128 (same cols), K=1024.
__global__ __launch_bounds__(512, 2) void gemmGLU(const f16* __restrict__ A, const f16* __restrict__ WgT,
                                                  f16* __restrict__ my, int K, int gx) {
  __shared__ __align__(16) f16 ldsA[2][16384];
  __shared__ __align__(16) f16 ldsG[2][8192];
  __shared__ __align__(16) f16 ldsY[2][8192];
  const int tid = threadIdx.x, lane = tid & 63, w = tid >> 6;
  const int l15 = lane & 15, l4 = lane >> 4;
  const int wr = w >> 2, wc = w & 3;
  const int nwg = gridDim.x;
  int flat = blockIdx.x;
  if ((nwg & 7) == 0) flat = (flat & 7) * (nwg >> 3) + (flat >> 3);
  const int bx = flat % gx, by = flat / gx;

  const f16* Ab = A + (size_t)by * 256 * K;
  const f16* Gb = WgT + (size_t)bx * 128 * K;
  const f16* Yb = WgT + (size_t)(2816 + bx * 128) * K;
  const int NT = K >> 6;
  f4 accG[8][2] = {}, accY[8][2] = {};

  const int r0 = tid >> 3;
  const size_t soff0 = (size_t)r0 * K + (size_t)(((tid & 7) ^ (r0 & 7)) * 8);
  const size_t soff1 = soff0 + (size_t)64 * K;
  const int dof = tid * 8;
  auto STG = [&](const f16* base, f16* dst) {
    __builtin_amdgcn_global_load_lds(AS1(base + soff0), AS3(dst + dof), 16, 0, 0);
    __builtin_amdgcn_global_load_lds(AS1(base + soff1), AS3(dst + 4096 + dof), 16, 0, 0);
  };

  // prologue: G(0),Y(0),A(0) both halves; G(1),Y(1); vmcnt(4)
  STG(Gb, ldsG[0]);
  STG(Yb, ldsY[0]);
  STG(Ab, ldsA[0]);
  STG(Ab + (size_t)128 * K, ldsA[0] + 8192);
  if (NT > 1) {
    STG(Gb + 64, ldsG[1]);
    STG(Yb + 64, ldsY[1]);
    asm volatile("s_waitcnt vmcnt(4)");
  } else {
    asm volatile("s_waitcnt vmcnt(0)");
  }
  __builtin_amdgcn_s_barrier();

  for (int t = 0; t < NT; ++t) {
    const int cur = t & 1, nxt = cur ^ 1;
    const f16* cA = ldsA[cur];
    h8 bg[2][2], byv[2][2];
    h8 a[2][2];
#pragma unroll
    for (int cf = 0; cf < 2; ++cf)
#pragma unroll
      for (int ks = 0; ks < 2; ++ks) {
        bg[cf][ks] = rd_sw(ldsG[cur], wc * 32 + cf * 16 + l15, ks * 4 + l4);
        byv[cf][ks] = rd_sw(ldsY[cur], wc * 32 + cf * 16 + l15, ks * 4 + l4);
      }
#pragma unroll
    for (int fr = 0; fr < 2; ++fr)
#pragma unroll
      for (int ks = 0; ks < 2; ++ks)
        a[fr][ks] = rd_sw(cA, wr * 128 + fr * 16 + l15, ks * 4 + l4);
    if (t + 1 < NT) STG(Ab + (t + 1) * 64, ldsA[nxt]);
    asm volatile("s_waitcnt lgkmcnt(0)");
    __builtin_amdgcn_s_setprio(1);
#pragma unroll
    for (int fr = 0; fr < 2; ++fr)
#pragma unroll
      for (int cf = 0; cf < 2; ++cf)
#pragma unroll
        for (int ks = 0; ks < 2; ++ks) {
          accG[fr][cf] = __builtin_amdgcn_mfma_f32_16x16x32_f16(a[fr][ks], bg[cf][ks], accG[fr][cf], 0, 0, 0);
          accY[fr][cf] = __builtin_amdgcn_mfma_f32_16x16x32_f16(a[fr][ks], byv[cf][ks], accY[fr][cf], 0, 0, 0);
        }
    __builtin_amdgcn_s_setprio(0);
    __builtin_amdgcn_s_barrier();
#pragma unroll
    for (int p = 1; p < 4; ++p) {
#pragma unroll
      for (int fr = 0; fr < 2; ++fr)
#pragma unroll
        for (int ks = 0; ks < 2; ++ks)
          a[fr][ks] = rd_sw(cA, wr * 128 + p * 32 + fr * 16 + l15, ks * 4 + l4);
      if (p == 1 && t + 1 < NT) STG(Ab + (size_t)128 * K + (t + 1) * 64, ldsA[nxt] + 8192);
      if (p == 2 && t + 2 < NT) STG(Gb + (t + 2) * 64, ldsG[cur]);
      if (p == 3 && t + 2 < NT) STG(Yb + (t + 2) * 64, ldsY[cur]);
      asm volatile("s_waitcnt lgkmcnt(0)");
      __builtin_amdgcn_s_setprio(1);
#pragma unroll
      for (int fr = 0; fr < 2; ++fr)
#pragma unroll
        for (int cf = 0; cf < 2; ++cf)
#pragma unroll
          for (int ks = 0; ks < 2; ++ks) {
            accG[p * 2 + fr][cf] = __builtin_amdgcn_mfma_f32_16x16x32_f16(a[fr][ks], bg[cf][ks], accG[p * 2 + fr][cf], 0, 0, 0);
            accY[p * 2 + fr][cf] = __builtin_amdgcn_mfma_f32_16x16x32_f16(a[fr][ks], byv[cf][ks], accY[p * 2 + fr][cf], 0, 0, 0);
          }
      __builtin_amdgcn_s_setprio(0);
      if (p == 3) {
        if (t + 2 < NT) asm volatile("s_waitcnt vmcnt(4)");
        else if (t + 1 < NT) asm volatile("s_waitcnt vmcnt(0)");
      }
      __builtin_amdgcn_s_barrier();
    }
  }

#pragma unroll
  for (int fr = 0; fr < 8; ++fr) {
#pragma unroll
    for (int cf = 0; cf < 2; ++cf) {
      const int row0 = by * 256 + wr * 128 + fr * 16 + l4 * 4;
      const int col = bx * 128 + wc * 32 + cf * 16 + l15;
#pragma unroll
      for (int q = 0; q < 4; ++q)
        my[(size_t)(row0 + q) * 2816 + col] = (f16)(siluf(accG[fr][cf][q]) * accY[fr][cf][q]);
    }
  }
}

// ---------------- f32 -> f16 convert ---------------------------------------
__global__ __launch_bounds__(256) void cvt_k(const float* __restrict__ in, f16* __restrict__ out) {
  const size_t i = ((size_t)blockIdx.x * 256 + threadIdx.x) * 8;
  const float4 a = *(const float4*)(in + i);
  const float4 b = *(const float4*)(in + i + 4);
  h8 o = {(f16)a.x, (f16)a.y, (f16)a.z, (f16)a.w, (f16)b.x, (f16)b.y, (f16)b.z, (f16)b.w};
  *(h8*)(out + i) = o;
}

// ---------------- RMSNorm over D=1024, f16 in ------------------------------
template<int OUT_F16>
__global__ __launch_bounds__(256) void rmsnorm_k(const f16* __restrict__ x, const float* __restrict__ w,
                                                 void* __restrict__ out) {
  const int r = blockIdx.x, tid = threadIdx.x;
  const h4 xv = *(const h4*)(x + (size_t)r * 1024 + tid * 4);
  const float v0 = (float)xv[0], v1 = (float)xv[1], v2 = (float)xv[2], v3 = (float)xv[3];
  float ss = v0 * v0 + v1 * v1 + v2 * v2 + v3 * v3;
#pragma unroll
  for (int m = 1; m < 64; m <<= 1) ss += __shfl_xor(ss, m);
  __shared__ float red[4];
  if ((tid & 63) == 0) red[tid >> 6] = ss;
  __syncthreads();
  const float scale = rsqrtf((red[0] + red[1] + red[2] + red[3]) * (1.f / 1024.f) + 1e-6f);
  const float4 w4 = *(const float4*)(w + tid * 4);
  float o0 = v0 * scale * w4.x, o1 = v1 * scale * w4.y, o2 = v2 * scale * w4.z, o3 = v3 * scale * w4.w;
  if (OUT_F16) {
    h4 o = {(f16)o0, (f16)o1, (f16)o2, (f16)o3};
    *(h4*)((f16*)out + (size_t)r * 1024 + tid * 4) = o;
  } else {
    *(float4*)((float*)out + (size_t)r * 1024 + tid * 4) = make_float4(o0, o1, o2, o3);
  }
}

// ------- silu + l2norm epilogue; writes q/k/v CHUNK-SWIZZLED ---------------
__global__ __launch_bounds__(256) void qkv_epi(const f16* __restrict__ qkv, f16* __restrict__ qb,
                                               f16* __restrict__ kb, f16* __restrict__ vb) {
  const int r = blockIdx.x, tid = threadIdx.x;
  const int head = tid >> 5, l32 = tid & 31;
  const int i = (r >> 2) & 63;
  const size_t src = (size_t)r * 3072 + head * 128 + l32 * 4;
  {
    const h4 v = *(const h4*)(qkv + src);
    float s0 = siluf((float)v[0]), s1 = siluf((float)v[1]), s2 = siluf((float)v[2]), s3 = siluf((float)v[3]);
    float ss = s0 * s0 + s1 * s1 + s2 * s2 + s3 * s3;
#pragma unroll
    for (int m = 1; m <= 16; m <<= 1) ss += __shfl_xor(ss, m);
    const float sc = rsqrtf(ss + 1e-6f);
    h4 o = {(f16)(s0 * sc), (f16)(s1 * sc), (f16)(s2 * sc), (f16)(s3 * sc)};
    const int c = l32 >> 1, off = (l32 & 1) * 4;
    *(h4*)(qb + (size_t)r * 1024 + head * 128 + swz16(i, c) * 8 + off) = o;
  }
  {
    const h4 v = *(const h4*)(qkv + src + 1024);
    float s0 = siluf((float)v[0]), s1 = siluf((float)v[1]), s2 = siluf((float)v[2]), s3 = siluf((float)v[3]);
    float ss = s0 * s0 + s1 * s1 + s2 * s2 + s3 * s3;
#pragma unroll
    for (int m = 1; m <= 16; m <<= 1) ss += __shfl_xor(ss, m);
    const float sc = rsqrtf(ss + 1e-6f);
    h4 o = {(f16)(s0 * sc), (f16)(s1 * sc), (f16)(s2 * sc), (f16)(s3 * sc)};
    const int c = l32 >> 1, off = (l32 & 1) * 4;
    *(h4*)(kb + (size_t)r * 1024 + head * 128 + swz16(i, c) * 8 + off) = o;
  }
  {
    const h4 v = *(const h4*)(qkv + (size_t)r * 3072 + 2048 + tid * 4);
    h4 o = {(f16)siluf((float)v[0]), (f16)siluf((float)v[1]), (f16)siluf((float)v[2]), (f16)siluf((float)v[3])};
    const int hd = tid >> 5, dh = (tid & 31) * 4;
    const int c = dh >> 3, off = dh & 7;
    *(h4*)(vb + (size_t)r * 1024 + hd * 128 + swz16(i, c) * 8 + off) = o;
  }
}

// ---------------- per-head RMSNorm (obuf f16 in) ---------------------------
__global__ __launch_bounds__(256) void onorm_k(const f16* __restrict__ o, const float* __restrict__ w,
                                               f16* __restrict__ ob) {
  const int r = blockIdx.x, tid = threadIdx.x;
  const int head = tid >> 5, l32 = tid & 31;
  const size_t base = (size_t)r * 1024 + head * 128 + l32 * 4;
  const h4 xv = *(const h4*)(o + base);
  const float v0 = (float)xv[0], v1 = (float)xv[1], v2 = (float)xv[2], v3 = (float)xv[3];
  float ss = v0 * v0 + v1 * v1 + v2 * v2 + v3 * v3;
#pragma unroll
  for (int m = 1; m <= 16; m <<= 1) ss += __shfl_xor(ss, m);
  const float sc = rsqrtf(ss * (1.f / 128.f) + 1e-6f);
  const float4 w4 = *(const float4*)(w + l32 * 4);
  h4 out = {(f16)(v0 * sc * w4.x), (f16)(v1 * sc * w4.y), (f16)(v2 * sc * w4.z), (f16)(v3 * sc * w4.w)};
  *(h4*)(ob + base) = out;
}

// ---------------- beta = 2*sigmoid(h @ Wb) ---------------------------------
__global__ __launch_bounds__(256) void beta_k(const f16* __restrict__ hb, const float* __restrict__ Wb,
                                              float* __restrict__ beta) {
  const int tid = threadIdx.x, lane = tid & 63, wv = tid >> 6;
  const int r = blockIdx.x * 4 + wv;
  const f16* row = hb + (size_t)r * 1024 + lane * 16;
  const h8 v0 = *(const h8*)(row);
  const h8 v1 = *(const h8*)(row + 8);
  const float* wb = Wb + (size_t)(lane * 16) * 8;
  float acc[8] = {};
#pragma unroll
  for (int e = 0; e < 8; ++e) {
    const float x0 = (float)v0[e], x1 = (float)v1[e];
    const float4 w0a = *(const float4*)(wb + e * 8);
    const float4 w0b = *(const float4*)(wb + e * 8 + 4);
    const float4 w1a = *(const float4*)(wb + (e + 8) * 8);
    const float4 w1b = *(const float4*)(wb + (e + 8) * 8 + 4);
    acc[0] += x0 * w0a.x + x1 * w1a.x;  acc[1] += x0 * w0a.y + x1 * w1a.y;
    acc[2] += x0 * w0a.z + x1 * w1a.z;  acc[3] += x0 * w0a.w + x1 * w1a.w;
    acc[4] += x0 * w0b.x + x1 * w1b.x;  acc[5] += x0 * w0b.y + x1 * w1b.y;
    acc[6] += x0 * w0b.z + x1 * w1b.z;  acc[7] += x0 * w0b.w + x1 * w1b.w;
  }
#pragma unroll
  for (int j = 0; j < 8; ++j)
#pragma unroll
    for (int m = 1; m < 64; m <<= 1) acc[j] += __shfl_xor(acc[j], m);
  if (lane == 0) {
#pragma unroll
    for (int j = 0; j < 8; ++j) beta[(size_t)r * 8 + j] = 2.f / (1.f + expf(-acc[j]));
  }
}

// ---------------- W[K][N] f32 -> Wt[N][K] f16 ------------------------------
__global__ __launch_bounds__(256) void transpose_k(const float* __restrict__ W, f16* __restrict__ Wt,
                                                   int K, int N) {
  __shared__ float tile[32][33];
  const int n0 = blockIdx.x * 32, k0 = blockIdx.y * 32;
  const int tx = threadIdx.x & 31, ty = threadIdx.x >> 5;
#pragma unroll
  for (int i = 0; i < 32; i += 8) tile[ty + i][tx] = W[(size_t)(k0 + ty + i) * N + n0 + tx];
  __syncthreads();
#pragma unroll
  for (int i = 0; i < 32; i += 8) Wt[(size_t)(n0 + ty + i) * K + k0 + tx] = (f16)tile[tx][ty + i];
}

__global__ void fill_k(float* p, int n, float v) {
  const int i = blockIdx.x * 256 + threadIdx.x;
  if (i < n) p[i] = v;
}

// ---------------- Phase A: WY transform ------------------------------------
DEV f4 mm16(const f16* A, int as, const f16* B, f4 c, int l15, int l4) {
  h4 a = *(const h4*)(A + l15 * as + l4 * 4);
  h4 b = *(const h4*)(B + l15 * 20 + l4 * 4);
  return __builtin_amdgcn_mfma_f32_16x16x16f16(a, b, c, 0, 0, 0);
}
DEV void wr_T(f16* slot, f4 acc, int l15, int l4, float sgn) {
  h4 v = {(f16)(sgn * acc[0]), (f16)(sgn * acc[1]), (f16)(sgn * acc[2]), (f16)(sgn * acc[3])};
  *(h4*)(slot + l15 * 20 + l4 * 4) = v;
}
DEV void wr_Tb(f16* Tb, int bi, int bj, f4 acc, const float* betas, int l15, int l4, float sgn) {
  const float bc = betas[bj * 16 + l15];
#pragma unroll
  for (int q = 0; q < 4; ++q)
    Tb[(bi * 16 + l4 * 4 + q) * 72 + bj * 16 + l15] = (f16)(sgn * acc[q] * bc);
}

__global__ __launch_bounds__(256) void phaseA(const f16* __restrict__ kb, const f16* __restrict__ qb,
                                              const f16* __restrict__ vb, const float* __restrict__ beta,
                                              f16* __restrict__ wbuf, f16* __restrict__ utbuf,
                                              f16* __restrict__ pbuf, f16* __restrict__ ktbuf) {
  const int blk = blockIdx.x;
  const int c = blk >> 5, bh = blk & 31;
  const int b = bh >> 3, h = bh & 7;
  const int tid = threadIdx.x, lane = tid & 63, wv = tid >> 6;
  const int l15 = lane & 15, l4 = lane >> 4;

  __shared__ __align__(16) f16 Ks[64 * 128];
  __shared__ __align__(16) f16 QVs[64 * 128];
  __shared__ __align__(16) f16 Abuf[64 * 68];
  __shared__ __align__(16) f16 Dr[4][16 * 20];
  __shared__ __align__(16) f16 Dt[4][16 * 20];
  __shared__ __align__(16) f16 Tp[3][16 * 20];
  __shared__ __align__(16) f16 Xp[3][16 * 20];
  __shared__ __align__(16) f16 Tb[64 * 72];
  __shared__ float betas[64];

  const size_t rowstr = (size_t)Bb_ * Dd;
  const size_t gbase = ((size_t)(c * 64) * Bb_ + b) * Dd + h * 128;

#pragma unroll
  for (int i = 0; i < 4; ++i) {
    const int ch = tid + i * 256;
    const int rr = ch >> 4, kc = ch & 15;
    *(h8*)(Ks + ch * 8) = *(const h8*)(kb + gbase + (size_t)rr * rowstr + kc * 8);
    *(h8*)(QVs + ch * 8) = *(const h8*)(qb + gbase + (size_t)rr * rowstr + kc * 8);
  }
  for (int i = tid; i < 64 * 72; i += 256) Tb[i] = (f16)0.f;
  if (tid < 64) betas[tid] = beta[((size_t)(c * 64 + tid) * Bb_ + b) * Hh + h];
  __syncthreads();

  f4 accS[4] = {}, accP[4] = {};
  const int arow = wv * 16 + l15;
#pragma unroll
  for (int kc = 0; kc < 4; ++kc) {
    const int c4 = kc * 4 + l4;
    const h8 aK = *(const h8*)(Ks + arow * 128 + swz16(arow, c4) * 8);
    const h8 aQ = *(const h8*)(QVs + arow * 128 + swz16(arow, c4) * 8);
#pragma unroll
    for (int f = 0; f < 4; ++f) {
      const int brow = f * 16 + l15;
      const h8 bK = *(const h8*)(Ks + brow * 128 + swz16(brow, c4) * 8);
      accS[f] = __builtin_amdgcn_mfma_f32_16x16x32_f16(aK, bK, accS[f], 0, 0, 0);
      accP[f] = __builtin_amdgcn_mfma_f32_16x16x32_f16(aQ, bK, accP[f], 0, 0, 0);
    }
  }
  const size_t pbase = (((size_t)bh * NC + c) * 64) * 64;
#pragma unroll
  for (int f = 0; f < 4; ++f) {
#pragma unroll
    for (int q = 0; q < 4; ++q) {
      const int i = wv * 16 + l4 * 4 + q;
      const int j = f * 16 + l15;
      Abuf[i * 68 + j] = (f16)((j < i) ? betas[i] * accS[f][q] : 0.f);
      pbuf[pbase + (size_t)i * 64 + j] = (f16)((j <= i) ? accP[f][q] : 0.f);
    }
  }
  __syncthreads();

#pragma unroll
  for (int i = 0; i < 4; ++i) {
    const int ch = tid + i * 256;
    const int rr = ch >> 4, kc = ch & 15;
    *(h8*)(QVs + ch * 8) = *(const h8*)(vb + gbase + (size_t)rr * rowstr + kc * 8);
  }

  {
    const int bi = wv;
    const int cc = l15;
    const f16* Ad = Abuf + (bi * 16) * 68 + bi * 16;
    float t[16];
    t[0] = (cc == 0) ? 1.f : 0.f;
#pragma unroll
    for (int i = 1; i < 16; ++i) {
      float s = (cc == i) ? 1.f : 0.f;
#pragma unroll
      for (int j = 0; j < i; ++j) s -= (float)Ad[i * 68 + j] * t[j];
      t[i] = s;
    }
    if (lane < 16) {
#pragma unroll
      for (int j4 = 0; j4 < 4; ++j4) {
        h4 v = {(f16)t[j4 * 4], (f16)t[j4 * 4 + 1], (f16)t[j4 * 4 + 2], (f16)t[j4 * 4 + 3]};
        *(h4*)(&Dt[bi][cc * 20 + j4 * 4]) = v;
      }
      const float bc = betas[bi * 16 + cc];
#pragma unroll
      for (int j = 0; j < 16; ++j) {
        Dr[bi][j * 20 + cc] = (f16)t[j];
        Tb[(bi * 16 + j) * 72 + bi * 16 + cc] = (f16)(t[j] * bc);
      }
    }
  }
  __syncthreads();

  const f16* AB10 = Abuf + 16 * 68 + 0;
  const f16* AB20 = Abuf + 32 * 68 + 0;
  const f16* AB21 = Abuf + 32 * 68 + 16;
  const f16* AB30 = Abuf + 48 * 68 + 0;
  const f16* AB31 = Abuf + 48 * 68 + 16;
  const f16* AB32 = Abuf + 48 * 68 + 32;
  f4 z = {};
  f4 x20, x30;

  if (wv == 0) wr_T(Xp[0], mm16(AB10, 68, Dt[0], z, l15, l4), l15, l4, 1.f);
  if (wv == 1) wr_T(Xp[1], mm16(AB21, 68, Dt[1], z, l15, l4), l15, l4, 1.f);
  if (wv == 2) wr_T(Xp[2], mm16(AB32, 68, Dt[2], z, l15, l4), l15, l4, 1.f);
  if (wv == 3) x20 = mm16(AB20, 68, Dt[0], z, l15, l4);
  __syncthreads();
  if (wv == 0) { f4 r = mm16(Dr[1], 20, Xp[0], z, l15, l4); wr_T(Tp[0], r, l15, l4, -1.f); wr_Tb(Tb, 1, 0, r, betas, l15, l4, -1.f); }
  if (wv == 1) { f4 r = mm16(Dr[2], 20, Xp[1], z, l15, l4); wr_T(Tp[1], r, l15, l4, -1.f); wr_Tb(Tb, 2, 1, r, betas, l15, l4, -1.f); }
  if (wv == 2) { f4 r = mm16(Dr[3], 20, Xp[2], z, l15, l4); wr_Tb(Tb, 3, 2, r, betas, l15, l4, -1.f); }
  if (wv == 3) x30 = mm16(AB30, 68, Dt[0], z, l15, l4);
  __syncthreads();
  if (wv == 3) wr_T(Xp[0], mm16(AB21, 68, Tp[0], x20, l15, l4), l15, l4, 1.f);
  if (wv == 1) { f4 r = mm16(AB31, 68, Dt[1], z, l15, l4); r = mm16(AB32, 68, Tp[1], r, l15, l4); wr_T(Xp[1], r, l15, l4, 1.f); }
  __syncthreads();
  if (wv == 3) { f4 r = mm16(Dr[2], 20, Xp[0], z, l15, l4); wr_T(Tp[2], r, l15, l4, -1.f); wr_Tb(Tb, 2, 0, r, betas, l15, l4, -1.f); }
  if (wv == 1) { f4 r = mm16(Dr[3], 20, Xp[1], z, l15, l4); wr_Tb(Tb, 3, 1, r, betas, l15, l4, -1.f); }
  __syncthreads();
  if (wv == 3) { f4 r = mm16(AB31, 68, Tp[0], x30, l15, l4); r = mm16(AB32, 68, Tp[2], r, l15, l4); wr_T(Xp[2], r, l15, l4, 1.f); }
  __syncthreads();
  if (wv == 3) { f4 r = mm16(Dr[3], 20, Xp[2], z, l15, l4); wr_Tb(Tb, 3, 0, r, betas, l15, l4, -1.f); }
  __syncthreads();

  const size_t wub = ((size_t)bh * NC + c) * 8192;
  const int koff = l4 * 8;
  f4 wacc[8] = {}, uacc[8] = {};
#pragma unroll
  for (int kc = 0; kc < 2; ++kc) {
    const h8 aT = *(const h8*)(Tb + (wv * 16 + l15) * 72 + kc * 32 + koff);
#pragma unroll
    for (int f = 0; f < 8; ++f) {
      const int d = f * 16 + l15, cD = d >> 3, d7 = d & 7;
      h8 bK, bV;
#pragma unroll
      for (int j = 0; j < 8; ++j) {
        const int t2 = kc * 32 + koff + j;
        const int pos = t2 * 128 + swz16(t2, cD) * 8 + d7;
        bK[j] = Ks[pos];
        bV[j] = QVs[pos];
      }
      wacc[f] = __builtin_amdgcn_mfma_f32_16x16x32_f16(aT, bK, wacc[f], 0, 0, 0);
      uacc[f] = __builtin_amdgcn_mfma_f32_16x16x32_f16(aT, bV, uacc[f], 0, 0, 0);
    }
  }
#pragma unroll
  for (int f = 0; f < 8; ++f) {
    const int d = f * 16 + l15, cD = d >> 3, d7 = d & 7;
#pragma unroll
    for (int q = 0; q < 4; ++q) {
      const int i = wv * 16 + l4 * 4 + q;
      wbuf[wub + (size_t)i * 128 + swz16(i, cD) * 8 + d7] = (f16)wacc[f][q];
    }
    h4 uv = {(f16)uacc[f][0], (f16)uacc[f][1], (f16)uacc[f][2], (f16)uacc[f][3]};
    *(h4*)(utbuf + wub + (size_t)d * 64 + wv * 16 + l4 * 4) = uv;
  }

#pragma unroll
  for (int i2 = 0; i2 < 4; ++i2) {
    const int ch = tid + i2 * 256;
    const int dp = ch & 127, c2 = ch >> 7;
    h8 v;
#pragma unroll
    for (int j = 0; j < 8; ++j) {
      const int i = c2 * 8 + j;
      v[j] = Ks[i * 128 + swz16(i, dp >> 3) * 8 + (dp & 7)];
    }
    *(h8*)(ktbuf + wub + (size_t)dp * 64 + (c2 ^ (dp & 7)) * 8) = v;
  }
}

// ---------------- Phase B: chunk recurrence ---------------------------------
__global__ __launch_bounds__(256) void phaseB(const f16* __restrict__ qb, const f16* __restrict__ ktbuf,
                                              const f16* __restrict__ wbuf, const f16* __restrict__ utbuf,
                                              const f16* __restrict__ pbuf, f16* __restrict__ obuf) {
  const int blk = blockIdx.x;
  const int bh = blk >> 2, g = blk & 3;
  const int b = bh >> 3, h = bh & 7;
  const int tid = threadIdx.x, lane = tid & 63, wv = tid >> 6;
  const int l15 = lane & 15, l4 = lane >> 4;

  __shared__ __align__(16) f16 Ws[2][8192];
  __shared__ __align__(16) f16 Qs[2][8192];
  __shared__ __align__(16) f16 Kts[2][8192];
  __shared__ __align__(16) f16 Rt[32 * 72];
  __shared__ __align__(16) f16 Ms[32 * 136];

  for (int i = tid; i < 32 * 136; i += 256) Ms[i] = (f16)0.f;
  f4 macc[2][2] = {};

  const int arow = wv * 16 + l15;
  const int koff = l4 * 8;

  auto STAGE = [&](int c2, int buf) {
#pragma unroll
    for (int i = 0; i < 4; ++i) {
      const int ch = tid + i * 256;
      const size_t tb = ((size_t)bh * NC + c2) * 8192;
      __builtin_amdgcn_global_load_lds(AS1(wbuf + tb + ch * 8), AS3(Ws[buf] + ch * 8), 16, 0, 0);
      __builtin_amdgcn_global_load_lds(AS1(ktbuf + tb + ch * 8), AS3(Kts[buf] + ch * 8), 16, 0, 0);
      const int rr = ch >> 4, kc2 = ch & 15;
      __builtin_amdgcn_global_load_lds(AS1(qb + ((size_t)((c2 * 64 + rr) * 4 + b)) * 1024 + h * 128 + kc2 * 8),
                                       AS3(Qs[buf] + ch * 8), 16, 0, 0);
    }
  };

  STAGE(0, 0);
  asm volatile("s_waitcnt vmcnt(0)" ::: "memory");
  __builtin_amdgcn_s_barrier();

  for (int c = 0; c < NC; ++c) {
    const int cur = c & 1, nxt = cur ^ 1;
    const size_t pcb = ((size_t)bh * NC + c) * 4096;
    const h8 aP0 = *(const h8*)(pbuf + pcb + arow * 64 + koff);
    const h8 aP1 = *(const h8*)(pbuf + pcb + arow * 64 + 32 + koff);
    const size_t ucb = ((size_t)bh * NC + c) * 8192;
    const h4 u0 = *(const h4*)(utbuf + ucb + (size_t)(g * 32 + l15) * 64 + wv * 16 + l4 * 4);
    const h4 u1 = *(const h4*)(utbuf + ucb + (size_t)(g * 32 + 16 + l15) * 64 + wv * 16 + l4 * 4);
    asm volatile("s_waitcnt vmcnt(4)" ::: "memory");
    asm volatile("s_waitcnt lgkmcnt(0)" ::: "memory");
    __builtin_amdgcn_s_barrier();
    if (c + 1 < NC) STAGE(c + 1, nxt);

    f4 accR[2] = {}, accO[2] = {};
    __builtin_amdgcn_s_setprio(1);
#pragma unroll
    for (int kc = 0; kc < 4; ++kc) {
      const int c4 = kc * 4 + l4;
      const h8 aW = *(const h8*)(Ws[cur] + arow * 128 + swz16(arow, c4) * 8);
      const h8 aQ = *(const h8*)(Qs[cur] + arow * 128 + swz16(arow, c4) * 8);
#pragma unroll
      for (int f = 0; f < 2; ++f) {
        const h8 bM = *(const h8*)(Ms + (f * 16 + l15) * 136 + kc * 32 + koff);
        accR[f] = __builtin_amdgcn_mfma_f32_16x16x32_f16(aW, bM, accR[f], 0, 0, 0);
        accO[f] = __builtin_amdgcn_mfma_f32_16x16x32_f16(aQ, bM, accO[f], 0, 0, 0);
      }
    }
    __builtin_amdgcn_s_setprio(0);
    if (c + 1 < NC) asm volatile("s_waitcnt vmcnt(12)" ::: "memory");
    else            asm volatile("s_waitcnt vmcnt(0)" ::: "memory");
#pragma unroll
    for (int f = 0; f < 2; ++f) {
      const h4 uu = f ? u1 : u0;
      h4 rw;
#pragma unroll
      for (int q = 0; q < 4; ++q) {
        const float rv = (float)uu[q] - accR[f][q];
        accR[f][q] = rv;
        rw[q] = (f16)rv;
      }
      *(h4*)(Rt + (f * 16 + l15) * 72 + wv * 16 + l4 * 4) = rw;
    }
    asm volatile("s_waitcnt lgkmcnt(0)" ::: "memory");
    __builtin_amdgcn_s_barrier();

#pragma unroll
    for (int kc = 0; kc < 2; ++kc) {
      const h8 aP = kc ? aP1 : aP0;
#pragma unroll
      for (int f = 0; f < 2; ++f) {
        const h8 bR = *(const h8*)(Rt + (f * 16 + l15) * 72 + kc * 32 + koff);
        accO[f] = __builtin_amdgcn_mfma_f32_16x16x32_f16(aP, bR, accO[f], 0, 0, 0);
      }
    }
#pragma unroll
    for (int f = 0; f < 2; ++f)
#pragma unroll
      for (int q = 0; q < 4; ++q) {
        const int i = wv * 16 + l4 * 4 + q;
        const int cc = f * 16 + l15;
        obuf[((size_t)(c * 64 + i) * Bb_ + b) * Dd + h * 128 + g * 32 + cc] = (f16)accO[f][q];
      }

#pragma unroll
    for (int kc = 0; kc < 2; ++kc) {
      const h8 aR0 = *(const h8*)(Rt + l15 * 72 + kc * 32 + koff);
      const h8 aR1 = *(const h8*)(Rt + (16 + l15) * 72 + kc * 32 + koff);
#pragma unroll
      for (int cf = 0; cf < 2; ++cf) {
        const int kcol = wv * 32 + cf * 16 + l15;
        const int c2 = kc * 4 + l4;
        const h8 bKv = *(const h8*)(Kts[cur] + kcol * 64 + (c2 ^ (kcol & 7)) * 8);
        macc[0][cf] = __builtin_amdgcn_mfma_f32_16x16x32_f16(aR0, bKv, macc[0][cf], 0, 0, 0);
        macc[1][cf] = __builtin_amdgcn_mfma_f32_16x16x32_f16(aR1, bKv, macc[1][cf], 0, 0, 0);
      }
    }
#pragma unroll
    for (int rf = 0; rf < 2; ++rf)
#pragma unroll
      for (int cf = 0; cf < 2; ++cf)
#pragma unroll
        for (int q = 0; q < 4; ++q) {
          const int cr = rf * 16 + l4 * 4 + q;
          const int kcol = wv * 32 + cf * 16 + l15;
          Ms[cr * 136 + kcol] = (f16)macc[rf][cf][q];
        }
  }
}

// ---------------------------------------------------------------------------
extern "C" void kernel_launch(void* const* d_in, const int* in_sizes, int n_in,
                              void* d_out, int out_size, void* d_ws, size_t ws_size,
                              hipStream_t stream) {
  (void)in_sizes; (void)n_in;
  const float* input = (const float*)d_in[0];
  const float* Wq = (const float*)d_in[1];
  const float* Wk = (const float*)d_in[2];
  const float* Wv = (const float*)d_in[3];
  const float* Wb = (const float*)d_in[4];
  const float* Wo = (const float*)d_in[5];
  const float* onw = (const float*)d_in[6];
  const float* n1w = (const float*)d_in[7];
  const float* n2w = (const float*)d_in[8];
  const float* Wg = (const float*)d_in[9];
  const float* Wd = (const float*)d_in[10];
  const float* fnw = (const float*)d_in[11];

  char* ws = (char*)d_ws;
  size_t off = 0;
  auto alloc = [&](size_t bytes) { void* p = ws + off; off += (bytes + 255) & ~(size_t)255; return p; };
  const size_t RD = 8192ull * 1024ull;
  f16*  x     = (f16*)alloc(RD * 2);
  f16*  hb    = (f16*)alloc(RD * 2);
  f16*  qb    = (f16*)alloc(RD * 2);
  f16*  kbuf  = (f16*)alloc(RD * 2);
  f16*  vbuf  = (f16*)alloc(RD * 2);
  float* beta = (float*)alloc(8192ull * 8 * 4);
  f16*  wbuf  = (f16*)alloc(RD * 2);
  f16*  utbuf = (f16*)alloc(RD * 2);
  f16*  ktbuf = (f16*)alloc(RD * 2);
  f16*  pbuf  = (f16*)alloc(32ull * 32 * 64 * 64 * 2);
  char* arena = (char*)alloc(3 * RD * 2);
  f16*  WqkvT = (f16*)alloc(3072ull * 1024 * 2);
  f16*  WoT   = (f16*)alloc(1024ull * 1024 * 2);
  f16*  WgT   = (f16*)alloc(5632ull * 1024 * 2);
  f16*  WdT   = (f16*)alloc(1024ull * 2816 * 2);
  if (off > ws_size) {
    fill_k<<<(out_size + 255) / 256, 256, 0, stream>>>((float*)d_out, out_size, 1.0e6f);
    return;
  }
  f16* qkvraw = (f16*)arena;
  f16* obuf = (f16*)arena;
  f16* my = qb;     // qb/kbuf/vbuf dead by the MLP
  f16* ob = wbuf;   // wbuf dead after phaseB

  cvt_k<<<4096, 256, 0, stream>>>(input, x);

  for (int l = 0; l < 2; ++l) {
    const size_t o2 = (size_t)l * 1024 * 1024;
    transpose_k<<<dim3(32, 32), 256, 0, stream>>>(Wq + o2, WqkvT, 1024, 1024);
    transpose_k<<<dim3(32, 32), 256, 0, stream>>>(Wk + o2, WqkvT + 1024ull * 1024, 1024, 1024);
    transpose_k<<<dim3(32, 32), 256, 0, stream>>>(Wv + o2, WqkvT + 2048ull * 1024, 1024, 1024);
    transpose_k<<<dim3(32, 32), 256, 0, stream>>>(Wo + o2, WoT, 1024, 1024);
    transpose_k<<<dim3(176, 32), 256, 0, stream>>>(Wg + (size_t)l * 1024 * 5632, WgT, 1024, 5632);
    transpose_k<<<dim3(32, 88), 256, 0, stream>>>(Wd + (size_t)l * 2816 * 1024, WdT, 2816, 1024);

    rmsnorm_k<1><<<8192, 256, 0, stream>>>(x, n1w + l * 1024, hb);
    gemm2<2, 128><<<32 * 24, 512, 0, stream>>>(hb, WqkvT, qkvraw, 8192, 3072, 1024, 24);
    beta_k<<<2048, 256, 0, stream>>>(hb, Wb + (size_t)l * 1024 * 8, beta);
    qkv_epi<<<8192, 256, 0, stream>>>(qkvraw, qb, kbuf, vbuf);
    phaseA<<<1024, 256, 0, stream>>>(kbuf, qb, vbuf, beta, wbuf, utbuf, pbuf, ktbuf);
    phaseB<<<128, 256, 0, stream>>>(qb, ktbuf, wbuf, utbuf, pbuf, obuf);
    onorm_k<<<8192, 256, 0, stream>>>(obuf, onw + l * 128, ob);
    gemm2<1, 128><<<32 * 8, 512, 0, stream>>>(ob, WoT, x, 8192, 1024, 1024, 8);

    rmsnorm_k<1><<<8192, 256, 0, stream>>>(x, n2w + l * 1024, hb);
    gemmGLU<<<32 * 22, 512, 0, stream>>>(hb, WgT, my, 1024, 22);
    gemm2<1, 128><<<32 * 8, 512, 0, stream>>>(my, WdT, x, 8192, 1024, 2816, 8);
  }
  rmsnorm_k<0><<<8192, 256, 0, stream>>>(x, fnw, d_out);
}

// Round 10
// 989.170 us; speedup vs baseline: 1.7399x; 1.0046x over previous
//
#include <hip/hip_runtime.h>
#include <hip/hip_bf16.h>
#include <cstdint>

// DeltaNet forward, MI355X. Round 10: 2-phase GEMM tiles (2 barriers/tile),
// RMSNorm folded into GEMM (weight-fold + row-scale epilogue), hb removed.

typedef _Float16 f16;
typedef __attribute__((ext_vector_type(8))) _Float16 h8;
typedef __attribute__((ext_vector_type(4))) _Float16 h4;
typedef __attribute__((ext_vector_type(4))) float f4;

#define DEV __device__ __forceinline__

static constexpr int Bb_ = 4;
static constexpr int Hh  = 8;
static constexpr int Dd  = 1024;
static constexpr int Tt  = 2048;
static constexpr int NC  = 32;

DEV float siluf(float x) { return x / (1.f + expf(-x)); }
DEV int swz16(int row, int c) { return (c & 8) | ((c & 7) ^ (row & 7)); }

#define AS1(p) ((const __attribute__((address_space(1))) void*)(uintptr_t)(p))
#define AS3(p) ((__attribute__((address_space(3))) void*)(uint32_t)(uintptr_t)(p))

DEV h8 rd_sw(const f16* T, int row, int chunk) {
  return *(const h8*)(T + (((row << 3) | (chunk ^ (row & 7))) * 8));
}

// ================= 2-phase GEMM: C[M,N] op= A[M,K]*Bt[N,K]^T, BN=128 =======
// EPI 1: f16 += ; EPI 2: f16 store (xSC: row-scale).
template<int EPI, int SC>
__global__ __launch_bounds__(512, 2) void gemm2(const f16* __restrict__ A, const f16* __restrict__ Bt,
                                                void* __restrict__ C, const float* __restrict__ rs,
                                                int M, int N, int K, int gx) {
  __shared__ __align__(16) f16 ldsA[2][16384];
  __shared__ __align__(16) f16 ldsB[2][8192];
  const int tid = threadIdx.x, lane = tid & 63, w = tid >> 6;
  const int l15 = lane & 15, l4 = lane >> 4;
  const int wr = w >> 2, wc = w & 3;
  const int nwg = gridDim.x;
  int flat = blockIdx.x;
  if ((nwg & 7) == 0) flat = (flat & 7) * (nwg >> 3) + (flat >> 3);
  const int bx = flat % gx, by = flat / gx;

  const f16* Ab = A + (size_t)by * 256 * K;
  const f16* Bb = Bt + (size_t)bx * 128 * K;
  const int NT = K >> 6;
  f4 acc[8][2] = {};

  const int r0 = tid >> 3;
  const size_t soff0 = (size_t)r0 * K + (size_t)(((tid & 7) ^ (r0 & 7)) * 8);
  const size_t soff1 = soff0 + (size_t)64 * K;
  const int dof = tid * 8;
  auto STG = [&](const f16* base, f16* dst) {
    __builtin_amdgcn_global_load_lds(AS1(base + soff0), AS3(dst + dof), 16, 0, 0);
    __builtin_amdgcn_global_load_lds(AS1(base + soff1), AS3(dst + 4096 + dof), 16, 0, 0);
  };

  STG(Bb, ldsB[0]);
  STG(Ab, ldsA[0]);
  STG(Ab + (size_t)128 * K, ldsA[0] + 8192);
  if (NT > 1) {
    STG(Bb + 64, ldsB[1]);
    asm volatile("s_waitcnt vmcnt(2)");
  } else {
    asm volatile("s_waitcnt vmcnt(0)");
  }
  __builtin_amdgcn_s_barrier();

  for (int t = 0; t < NT; ++t) {
    const int cur = t & 1, nxt = cur ^ 1;
    const f16* cA = ldsA[cur];
    const f16* cB = ldsB[cur];
    h8 b[2][2], aX[2][2], aY[2][2];
#pragma unroll
    for (int cf = 0; cf < 2; ++cf)
#pragma unroll
      for (int ks = 0; ks < 2; ++ks)
        b[cf][ks] = rd_sw(cB, wc * 32 + cf * 16 + l15, ks * 4 + l4);
#pragma unroll
    for (int fr = 0; fr < 2; ++fr)
#pragma unroll
      for (int ks = 0; ks < 2; ++ks)
        aX[fr][ks] = rd_sw(cA, wr * 128 + fr * 16 + l15, ks * 4 + l4);
    if (t + 1 < NT) { STG(Ab + (t + 1) * 64, ldsA[nxt]); STG(Ab + (size_t)128 * K + (t + 1) * 64, ldsA[nxt] + 8192); }
    __builtin_amdgcn_s_setprio(1);
#pragma unroll
    for (int fr = 0; fr < 2; ++fr)
#pragma unroll
      for (int cf = 0; cf < 2; ++cf)
#pragma unroll
        for (int ks = 0; ks < 2; ++ks)
          acc[fr][cf] = __builtin_amdgcn_mfma_f32_16x16x32_f16(aX[fr][ks], b[cf][ks], acc[fr][cf], 0, 0, 0);
#pragma unroll
    for (int fr = 0; fr < 2; ++fr)
#pragma unroll
      for (int ks = 0; ks < 2; ++ks)
        aY[fr][ks] = rd_sw(cA, wr * 128 + 32 + fr * 16 + l15, ks * 4 + l4);
#pragma unroll
    for (int fr = 0; fr < 2; ++fr)
#pragma unroll
      for (int cf = 0; cf < 2; ++cf)
#pragma unroll
        for (int ks = 0; ks < 2; ++ks)
          acc[2 + fr][cf] = __builtin_amdgcn_mfma_f32_16x16x32_f16(aY[fr][ks], b[cf][ks], acc[2 + fr][cf], 0, 0, 0);
    __builtin_amdgcn_s_setprio(0);
    __builtin_amdgcn_s_barrier();
    // ---- phase 1 ----
#pragma unroll
    for (int fr = 0; fr < 2; ++fr)
#pragma unroll
      for (int ks = 0; ks < 2; ++ks)
        aX[fr][ks] = rd_sw(cA, wr * 128 + 64 + fr * 16 + l15, ks * 4 + l4);
    if (t + 2 < NT) STG(Bb + (t + 2) * 64, ldsB[cur]);
    __builtin_amdgcn_s_setprio(1);
#pragma unroll
    for (int fr = 0; fr < 2; ++fr)
#pragma unroll
      for (int cf = 0; cf < 2; ++cf)
#pragma unroll
        for (int ks = 0; ks < 2; ++ks)
          acc[4 + fr][cf] = __builtin_amdgcn_mfma_f32_16x16x32_f16(aX[fr][ks], b[cf][ks], acc[4 + fr][cf], 0, 0, 0);
#pragma unroll
    for (int fr = 0; fr < 2; ++fr)
#pragma unroll
      for (int ks = 0; ks < 2; ++ks)
        aY[fr][ks] = rd_sw(cA, wr * 128 + 96 + fr * 16 + l15, ks * 4 + l4);
#pragma unroll
    for (int fr = 0; fr < 2; ++fr)
#pragma unroll
      for (int cf = 0; cf < 2; ++cf)
#pragma unroll
        for (int ks = 0; ks < 2; ++ks)
          acc[6 + fr][cf] = __builtin_amdgcn_mfma_f32_16x16x32_f16(aY[fr][ks], b[cf][ks], acc[6 + fr][cf], 0, 0, 0);
    __builtin_amdgcn_s_setprio(0);
    if (t + 2 < NT)      asm volatile("s_waitcnt vmcnt(2)" ::: "memory");
    else if (t + 1 < NT) asm volatile("s_waitcnt vmcnt(0)" ::: "memory");
    __builtin_amdgcn_s_barrier();
  }

#pragma unroll
  for (int fr = 0; fr < 8; ++fr) {
#pragma unroll
    for (int cf = 0; cf < 2; ++cf) {
      const int row0 = by * 256 + wr * 128 + fr * 16 + l4 * 4;
      const int col = bx * 128 + wc * 32 + cf * 16 + l15;
#pragma unroll
      for (int q = 0; q < 4; ++q) {
        const size_t idx = (size_t)(row0 + q) * N + col;
        float v = acc[fr][cf][q];
        if (SC) v *= rs[row0 + q];
        if (EPI == 1) ((f16*)C)[idx] = (f16)((float)((f16*)C)[idx] + v);
        if (EPI == 2) ((f16*)C)[idx] = (f16)v;
      }
    }
  }
}

// ============ fused GLU GEMM (2-phase): my = s*silu(A Wg_g^T) * s*(A Wg_y^T)
__global__ __launch_bounds__(512, 2) void gemmGLU(const f16* __restrict__ A, const f16* __restrict__ WgT,
                                                  const float* __restrict__ rs, f16* __restrict__ my,
                                                  int K, int gx) {
  __shared__ __align__(16) f16 ldsA[2][16384];
  __shared__ __align__(16) f16 ldsG[2][8192];
  __shared__ __align__(16) f16 ldsY[2][8192];
  const int tid = threadIdx.x, lane = tid & 63, w = tid >> 6;
  const int l15 = lane & 15, l4 = lane >> 4;
  const int wr = w >> 2, wc = w & 3;
  const int nwg = gridDim.x;
  int flat = blockIdx.x;
  if ((nwg & 7) == 0) flat = (flat & 7) * (nwg >> 3) + (flat >> 3);
  const int bx = flat % gx, by = flat / gx;

  const f16* Ab = A + (size_t)by * 256 * K;
  const f16* Gb = WgT + (size_t)bx * 128 * K;
  const f16* Yb = WgT + (size_t)(2816 + bx * 128) * K;
  const int NT = K >> 6;
  f4 accG[8][2] = {}, accY[8][2] = {};

  const int r0 = tid >> 3;
  const size_t soff0 = (size_t)r0 * K + (size_t)(((tid & 7) ^ (r0 & 7)) * 8);
  const size_t soff1 = soff0 + (size_t)64 * K;
  const int dof = tid * 8;
  auto STG = [&](const f16* base, f16* dst) {
    __builtin_amdgcn_global_load_lds(AS1(base + soff0), AS3(dst + dof), 16, 0, 0);
    __builtin_amdgcn_global_load_lds(AS1(base + soff1), AS3(dst + 4096 + dof), 16, 0, 0);
  };

  STG(Gb, ldsG[0]);
  STG(Yb, ldsY[0]);
  STG(Ab, ldsA[0]);
  STG(Ab + (size_t)128 * K, ldsA[0] + 8192);
  if (NT > 1) {
    STG(Gb + 64, ldsG[1]);
    STG(Yb + 64, ldsY[1]);
    asm volatile("s_waitcnt vmcnt(4)");
  } else {
    asm volatile("s_waitcnt vmcnt(0)");
  }
  __builtin_amdgcn_s_barrier();

  for (int t = 0; t < NT; ++t) {
    const int cur = t & 1, nxt = cur ^ 1;
    const f16* cA = ldsA[cur];
    h8 bg[2][2], byv[2][2], aX[2][2], aY[2][2];
#pragma unroll
    for (int cf = 0; cf < 2; ++cf)
#pragma unroll
      for (int ks = 0; ks < 2; ++ks) {
        bg[cf][ks] = rd_sw(ldsG[cur], wc * 32 + cf * 16 + l15, ks * 4 + l4);
        byv[cf][ks] = rd_sw(ldsY[cur], wc * 32 + cf * 16 + l15, ks * 4 + l4);
      }
#pragma unroll
    for (int fr = 0; fr < 2; ++fr)
#pragma unroll
      for (int ks = 0; ks < 2; ++ks)
        aX[fr][ks] = rd_sw(cA, wr * 128 + fr * 16 + l15, ks * 4 + l4);
    if (t + 1 < NT) { STG(Ab + (t + 1) * 64, ldsA[nxt]); STG(Ab + (size_t)128 * K + (t + 1) * 64, ldsA[nxt] + 8192); }
    __builtin_amdgcn_s_setprio(1);
#pragma unroll
    for (int fr = 0; fr < 2; ++fr)
#pragma unroll
      for (int cf = 0; cf < 2; ++cf)
#pragma unroll
        for (int ks = 0; ks < 2; ++ks) {
          accG[fr][cf] = __builtin_amdgcn_mfma_f32_16x16x32_f16(aX[fr][ks], bg[cf][ks], accG[fr][cf], 0, 0, 0);
          accY[fr][cf] = __builtin_amdgcn_mfma_f32_16x16x32_f16(aX[fr][ks], byv[cf][ks], accY[fr][cf], 0, 0, 0);
        }
#pragma unroll
    for (int fr = 0; fr < 2; ++fr)
#pragma unroll
      for (int ks = 0; ks < 2; ++ks)
        aY[fr][ks] = rd_sw(cA, wr * 128 + 32 + fr * 16 + l15, ks * 4 + l4);
#pragma unroll
    for (int fr = 0; fr < 2; ++fr)
#pragma unroll
      for (int cf = 0; cf < 2; ++cf)
#pragma unroll
        for (int ks = 0; ks < 2; ++ks) {
          accG[2 + fr][cf] = __builtin_amdgcn_mfma_f32_16x16x32_f16(aY[fr][ks], bg[cf][ks], accG[2 + fr][cf], 0, 0, 0);
          accY[2 + fr][cf] = __builtin_amdgcn_mfma_f32_16x16x32_f16(aY[fr][ks], byv[cf][ks], accY[2 + fr][cf], 0, 0, 0);
        }
    __builtin_amdgcn_s_setprio(0);
    __builtin_amdgcn_s_barrier();
    // ---- phase 1 ----
#pragma unroll
    for (int fr = 0; fr < 2; ++fr)
#pragma unroll
      for (int ks = 0; ks < 2; ++ks)
        aX[fr][ks] = rd_sw(cA, wr * 128 + 64 + fr * 16 + l15, ks * 4 + l4);
    if (t + 2 < NT) { STG(Gb + (t + 2) * 64, ldsG[cur]); STG(Yb + (t + 2) * 64, ldsY[cur]); }
    __builtin_amdgcn_s_setprio(1);
#pragma unroll
    for (int fr = 0; fr < 2; ++fr)
#pragma unroll
      for (int cf = 0; cf < 2; ++cf)
#pragma unroll
        for (int ks = 0; ks < 2; ++ks) {
          accG[4 + fr][cf] = __builtin_amdgcn_mfma_f32_16x16x32_f16(aX[fr][ks], bg[cf][ks], accG[4 + fr][cf], 0, 0, 0);
          accY[4 + fr][cf] = __builtin_amdgcn_mfma_f32_16x16x32_f16(aX[fr][ks], byv[cf][ks], accY[4 + fr][cf], 0, 0, 0);
        }
#pragma unroll
    for (int fr = 0; fr < 2; ++fr)
#pragma unroll
      for (int ks = 0; ks < 2; ++ks)
        aY[fr][ks] = rd_sw(cA, wr * 128 + 96 + fr * 16 + l15, ks * 4 + l4);
#pragma unroll
    for (int fr = 0; fr < 2; ++fr)
#pragma unroll
      for (int cf = 0; cf < 2; ++cf)
#pragma unroll
        for (int ks = 0; ks < 2; ++ks) {
          accG[6 + fr][cf] = __builtin_amdgcn_mfma_f32_16x16x32_f16(aY[fr][ks], bg[cf][ks], accG[6 + fr][cf], 0, 0, 0);
          accY[6 + fr][cf] = __builtin_amdgcn_mfma_f32_16x16x32_f16(aY[fr][ks], byv[cf][ks], accY[6 + fr][cf], 0, 0, 0);
        }
    __builtin_amdgcn_s_setprio(0);
    if (t + 2 < NT)      asm volatile("s_waitcnt vmcnt(4)" ::: "memory");
    else if (t + 1 < NT) asm volatile("s_waitcnt vmcnt(0)" ::: "memory");
    __builtin_amdgcn_s_barrier();
  }

#pragma unroll
  for (int fr = 0; fr < 8; ++fr) {
#pragma unroll
    for (int cf = 0; cf < 2; ++cf) {
      const int row0 = by * 256 + wr * 128 + fr * 16 + l4 * 4;
      const int col = bx * 128 + wc * 32 + cf * 16 + l15;
#pragma unroll
      for (int q = 0; q < 4; ++q) {
        const float s = rs[row0 + q];
        my[(size_t)(row0 + q) * 2816 + col] = (f16)(siluf(s * accG[fr][cf][q]) * (s * accY[fr][cf][q]));
      }
    }
  }
}

// ---------------- f32 -> f16 convert ---------------------------------------
__global__ __launch_bounds__(256) void cvt_k(const float* __restrict__ in, f16* __restrict__ out) {
  const size_t i = ((size_t)blockIdx.x * 256 + threadIdx.x) * 8;
  const float4 a = *(const float4*)(in + i);
  const float4 b = *(const float4*)(in + i + 4);
  h8 o = {(f16)a.x, (f16)a.y, (f16)a.z, (f16)a.w, (f16)b.x, (f16)b.y, (f16)b.z, (f16)b.w};
  *(h8*)(out + i) = o;
}

// ---------------- per-row rsqrt(mean(x^2)+eps) -----------------------------
__global__ __launch_bounds__(256) void rowscale_k(const f16* __restrict__ x, float* __restrict__ rs) {
  const int tid = threadIdx.x, lane = tid & 63, wv = tid >> 6;
  const int r = blockIdx.x * 4 + wv;
  const f16* row = x + (size_t)r * 1024 + lane * 16;
  const h8 v0 = *(const h8*)(row);
  const h8 v1 = *(const h8*)(row + 8);
  float ss = 0.f;
#pragma unroll
  for (int e = 0; e < 8; ++e) {
    const float a = (float)v0[e], b = (float)v1[e];
    ss += a * a + b * b;
  }
#pragma unroll
  for (int m = 1; m < 64; m <<= 1) ss += __shfl_xor(ss, m);
  if (lane == 0) rs[r] = rsqrtf(ss * (1.f / 1024.f) + 1e-6f);
}

// ---------------- final RMSNorm (f16 in, f32 out) --------------------------
__global__ __launch_bounds__(256) void rmsnorm_f(const f16* __restrict__ x, const float* __restrict__ w,
                                                 float* __restrict__ out) {
  const int r = blockIdx.x, tid = threadIdx.x;
  const h4 xv = *(const h4*)(x + (size_t)r * 1024 + tid * 4);
  const float v0 = (float)xv[0], v1 = (float)xv[1], v2 = (float)xv[2], v3 = (float)xv[3];
  float ss = v0 * v0 + v1 * v1 + v2 * v2 + v3 * v3;
#pragma unroll
  for (int m = 1; m < 64; m <<= 1) ss += __shfl_xor(ss, m);
  __shared__ float red[4];
  if ((tid & 63) == 0) red[tid >> 6] = ss;
  __syncthreads();
  const float scale = rsqrtf((red[0] + red[1] + red[2] + red[3]) * (1.f / 1024.f) + 1e-6f);
  const float4 w4 = *(const float4*)(w + tid * 4);
  *(float4*)(out + (size_t)r * 1024 + tid * 4) =
      make_float4(v0 * scale * w4.x, v1 * scale * w4.y, v2 * scale * w4.z, v3 * scale * w4.w);
}

// ------- silu + l2norm epilogue; writes q/k/v CHUNK-SWIZZLED ---------------
__global__ __launch_bounds__(256) void qkv_epi(const f16* __restrict__ qkv, f16* __restrict__ qb,
                                               f16* __restrict__ kb, f16* __restrict__ vb) {
  const int r = blockIdx.x, tid = threadIdx.x;
  const int head = tid >> 5, l32 = tid & 31;
  const int i = (r >> 2) & 63;
  const size_t src = (size_t)r * 3072 + head * 128 + l32 * 4;
  {
    const h4 v = *(const h4*)(qkv + src);
    float s0 = siluf((float)v[0]), s1 = siluf((float)v[1]), s2 = siluf((float)v[2]), s3 = siluf((float)v[3]);
    float ss = s0 * s0 + s1 * s1 + s2 * s2 + s3 * s3;
#pragma unroll
    for (int m = 1; m <= 16; m <<= 1) ss += __shfl_xor(ss, m);
    const float sc = rsqrtf(ss + 1e-6f);
    h4 o = {(f16)(s0 * sc), (f16)(s1 * sc), (f16)(s2 * sc), (f16)(s3 * sc)};
    const int c = l32 >> 1, off = (l32 & 1) * 4;
    *(h4*)(qb + (size_t)r * 1024 + head * 128 + swz16(i, c) * 8 + off) = o;
  }
  {
    const h4 v = *(const h4*)(qkv + src + 1024);
    float s0 = siluf((float)v[0]), s1 = siluf((float)v[1]), s2 = siluf((float)v[2]), s3 = siluf((float)v[3]);
    float ss = s0 * s0 + s1 * s1 + s2 * s2 + s3 * s3;
#pragma unroll
    for (int m = 1; m <= 16; m <<= 1) ss += __shfl_xor(ss, m);
    const float sc = rsqrtf(ss + 1e-6f);
    h4 o = {(f16)(s0 * sc), (f16)(s1 * sc), (f16)(s2 * sc), (f16)(s3 * sc)};
    const int c = l32 >> 1, off = (l32 & 1) * 4;
    *(h4*)(kb + (size_t)r * 1024 + head * 128 + swz16(i, c) * 8 + off) = o;
  }
  {
    const h4 v = *(const h4*)(qkv + (size_t)r * 3072 + 2048 + tid * 4);
    h4 o = {(f16)siluf((float)v[0]), (f16)siluf((float)v[1]), (f16)siluf((float)v[2]), (f16)siluf((float)v[3])};
    const int hd = tid >> 5, dh = (tid & 31) * 4;
    const int c = dh >> 3, off = dh & 7;
    *(h4*)(vb + (size_t)r * 1024 + hd * 128 + swz16(i, c) * 8 + off) = o;
  }
}

// ---------------- per-head RMSNorm -----------------------------------------
__global__ __launch_bounds__(256) void onorm_k(const f16* __restrict__ o, const float* __restrict__ w,
                                               f16* __restrict__ ob) {
  const int r = blockIdx.x, tid = threadIdx.x;
  const int head = tid >> 5, l32 = tid & 31;
  const size_t base = (size_t)r * 1024 + head * 128 + l32 * 4;
  const h4 xv = *(const h4*)(o + base);
  const float v0 = (float)xv[0], v1 = (float)xv[1], v2 = (float)xv[2], v3 = (float)xv[3];
  float ss = v0 * v0 + v1 * v1 + v2 * v2 + v3 * v3;
#pragma unroll
  for (int m = 1; m <= 16; m <<= 1) ss += __shfl_xor(ss, m);
  const float sc = rsqrtf(ss * (1.f / 128.f) + 1e-6f);
  const float4 w4 = *(const float4*)(w + l32 * 4);
  h4 out = {(f16)(v0 * sc * w4.x), (f16)(v1 * sc * w4.y), (f16)(v2 * sc * w4.z), (f16)(v3 * sc * w4.w)};
  *(h4*)(ob + base) = out;
}

// ---------------- beta = 2*sigmoid(s * (x @ Wb')) --------------------------
__global__ __launch_bounds__(256) void beta_k(const f16* __restrict__ x, const float* __restrict__ Wb2,
                                              const float* __restrict__ rs, float* __restrict__ beta) {
  const int tid = threadIdx.x, lane = tid & 63, wv = tid >> 6;
  const int r = blockIdx.x * 4 + wv;
  const f16* row = x + (size_t)r * 1024 + lane * 16;
  const h8 v0 = *(const h8*)(row);
  const h8 v1 = *(const h8*)(row + 8);
  const float* wb = Wb2 + (size_t)(lane * 16) * 8;
  float acc[8] = {};
#pragma unroll
  for (int e = 0; e < 8; ++e) {
    const float x0 = (float)v0[e], x1 = (float)v1[e];
    const float4 w0a = *(const float4*)(wb + e * 8);
    const float4 w0b = *(const float4*)(wb + e * 8 + 4);
    const float4 w1a = *(const float4*)(wb + (e + 8) * 8);
    const float4 w1b = *(const float4*)(wb + (e + 8) * 8 + 4);
    acc[0] += x0 * w0a.x + x1 * w1a.x;  acc[1] += x0 * w0a.y + x1 * w1a.y;
    acc[2] += x0 * w0a.z + x1 * w1a.z;  acc[3] += x0 * w0a.w + x1 * w1a.w;
    acc[4] += x0 * w0b.x + x1 * w1b.x;  acc[5] += x0 * w0b.y + x1 * w1b.y;
    acc[6] += x0 * w0b.z + x1 * w1b.z;  acc[7] += x0 * w0b.w + x1 * w1b.w;
  }
#pragma unroll
  for (int j = 0; j < 8; ++j)
#pragma unroll
    for (int m = 1; m < 64; m <<= 1) acc[j] += __shfl_xor(acc[j], m);
  if (lane == 0) {
    const float s = rs[r];
#pragma unroll
    for (int j = 0; j < 8; ++j) beta[(size_t)r * 8 + j] = 2.f / (1.f + expf(-acc[j] * s));
  }
}

// ---------------- W[K][N] f32 -> Wt[N][K] f16 (opt row-weight fold) --------
template<int FOLD>
__global__ __launch_bounds__(256) void transpose_k(const float* __restrict__ W, const float* __restrict__ rw,
                                                   f16* __restrict__ Wt, int K, int N) {
  __shared__ float tile[32][33];
  const int n0 = blockIdx.x * 32, k0 = blockIdx.y * 32;
  const int tx = threadIdx.x & 31, ty = threadIdx.x >> 5;
#pragma unroll
  for (int i = 0; i < 32; i += 8) {
    float v = W[(size_t)(k0 + ty + i) * N + n0 + tx];
    if (FOLD) v *= rw[k0 + ty + i];
    tile[ty + i][tx] = v;
  }
  __syncthreads();
#pragma unroll
  for (int i = 0; i < 32; i += 8) Wt[(size_t)(n0 + ty + i) * K + k0 + tx] = (f16)tile[tx][ty + i];
}

// ---------------- Wb' = diag(n1w) Wb ---------------------------------------
__global__ __launch_bounds__(256) void bweight_k(const float* __restrict__ Wb, const float* __restrict__ n1w,
                                                 float* __restrict__ Wb2) {
  const int idx = blockIdx.x * 256 + threadIdx.x;  // 8192
  Wb2[idx] = Wb[idx] * n1w[idx >> 3];
}

__global__ void fill_k(float* p, int n, float v) {
  const int i = blockIdx.x * 256 + threadIdx.x;
  if (i < n) p[i] = v;
}

// ---------------- Phase A: WY transform ------------------------------------
DEV f4 mm16(const f16* A, int as, const f16* B, f4 c, int l15, int l4) {
  h4 a = *(const h4*)(A + l15 * as + l4 * 4);
  h4 b = *(const h4*)(B + l15 * 20 + l4 * 4);
  return __builtin_amdgcn_mfma_f32_16x16x16f16(a, b, c, 0, 0, 0);
}
DEV void wr_T(f16* slot, f4 acc, int l15, int l4, float sgn) {
  h4 v = {(f16)(sgn * acc[0]), (f16)(sgn * acc[1]), (f16)(sgn * acc[2]), (f16)(sgn * acc[3])};
  *(h4*)(slot + l15 * 20 + l4 * 4) = v;
}
DEV void wr_Tb(f16* Tb, int bi, int bj, f4 acc, const float* betas, int l15, int l4, float sgn) {
  const float bc = betas[bj * 16 + l15];
#pragma unroll
  for (int q = 0; q < 4; ++q)
    Tb[(bi * 16 + l4 * 4 + q) * 72 + bj * 16 + l15] = (f16)(sgn * acc[q] * bc);
}

__global__ __launch_bounds__(256) void phaseA(const f16* __restrict__ kb, const f16* __restrict__ qb,
                                              const f16* __restrict__ vb, const float* __restrict__ beta,
                                              f16* __restrict__ wbuf, f16* __restrict__ utbuf,
                                              f16* __restrict__ pbuf, f16* __restrict__ ktbuf) {
  const int blk = blockIdx.x;
  const int c = blk >> 5, bh = blk & 31;
  const int b = bh >> 3, h = bh & 7;
  const int tid = threadIdx.x, lane = tid & 63, wv = tid >> 6;
  const int l15 = lane & 15, l4 = lane >> 4;

  __shared__ __align__(16) f16 Ks[64 * 128];
  __shared__ __align__(16) f16 QVs[64 * 128];
  __shared__ __align__(16) f16 Abuf[64 * 68];
  __shared__ __align__(16) f16 Dr[4][16 * 20];
  __shared__ __align__(16) f16 Dt[4][16 * 20];
  __shared__ __align__(16) f16 Tp[3][16 * 20];
  __shared__ __align__(16) f16 Xp[3][16 * 20];
  __shared__ __align__(16) f16 Tb[64 * 72];
  __shared__ float betas[64];

  const size_t rowstr = (size_t)Bb_ * Dd;
  const size_t gbase = ((size_t)(c * 64) * Bb_ + b) * Dd + h * 128;

#pragma unroll
  for (int i = 0; i < 4; ++i) {
    const int ch = tid + i * 256;
    const int rr = ch >> 4, kc = ch & 15;
    *(h8*)(Ks + ch * 8) = *(const h8*)(kb + gbase + (size_t)rr * rowstr + kc * 8);
    *(h8*)(QVs + ch * 8) = *(const h8*)(qb + gbase + (size_t)rr * rowstr + kc * 8);
  }
  for (int i = tid; i < 64 * 72; i += 256) Tb[i] = (f16)0.f;
  if (tid < 64) betas[tid] = beta[((size_t)(c * 64 + tid) * Bb_ + b) * Hh + h];
  __syncthreads();

  f4 accS[4] = {}, accP[4] = {};
  const int arow = wv * 16 + l15;
#pragma unroll
  for (int kc = 0; kc < 4; ++kc) {
    const int c4 = kc * 4 + l4;
    const h8 aK = *(const h8*)(Ks + arow * 128 + swz16(arow, c4) * 8);
    const h8 aQ = *(const h8*)(QVs + arow * 128 + swz16(arow, c4) * 8);
#pragma unroll
    for (int f = 0; f < 4; ++f) {
      const int brow = f * 16 + l15;
      const h8 bK = *(const h8*)(Ks + brow * 128 + swz16(brow, c4) * 8);
      accS[f] = __builtin_amdgcn_mfma_f32_16x16x32_f16(aK, bK, accS[f], 0, 0, 0);
      accP[f] = __builtin_amdgcn_mfma_f32_16x16x32_f16(aQ, bK, accP[f], 0, 0, 0);
    }
  }
  const size_t pbase = (((size_t)bh * NC + c) * 64) * 64;
#pragma unroll
  for (int f = 0; f < 4; ++f) {
#pragma unroll
    for (int q = 0; q < 4; ++q) {
      const int i = wv * 16 + l4 * 4 + q;
      const int j = f * 16 + l15;
      Abuf[i * 68 + j] = (f16)((j < i) ? betas[i] * accS[f][q] : 0.f);
      pbuf[pbase + (size_t)i * 64 + j] = (f16)((j <= i) ? accP[f][q] : 0.f);
    }
  }
  __syncthreads();

#pragma unroll
  for (int i = 0; i < 4; ++i) {
    const int ch = tid + i * 256;
    const int rr = ch >> 4, kc = ch & 15;
    *(h8*)(QVs + ch * 8) = *(const h8*)(vb + gbase + (size_t)rr * rowstr + kc * 8);
  }

  {
    const int bi = wv;
    const int cc = l15;
    const f16* Ad = Abuf + (bi * 16) * 68 + bi * 16;
    float t[16];
    t[0] = (cc == 0) ? 1.f : 0.f;
#pragma unroll
    for (int i = 1; i < 16; ++i) {
      float s = (cc == i) ? 1.f : 0.f;
#pragma unroll
      for (int j = 0; j < i; ++j) s -= (float)Ad[i * 68 + j] * t[j];
      t[i] = s;
    }
    if (lane < 16) {
#pragma unroll
      for (int j4 = 0; j4 < 4; ++j4) {
        h4 v = {(f16)t[j4 * 4], (f16)t[j4 * 4 + 1], (f16)t[j4 * 4 + 2], (f16)t[j4 * 4 + 3]};
        *(h4*)(&Dt[bi][cc * 20 + j4 * 4]) = v;
      }
      const float bc = betas[bi * 16 + cc];
#pragma unroll
      for (int j = 0; j < 16; ++j) {
        Dr[bi][j * 20 + cc] = (f16)t[j];
        Tb[(bi * 16 + j) * 72 + bi * 16 + cc] = (f16)(t[j] * bc);
      }
    }
  }
  __syncthreads();

  const f16* AB10 = Abuf + 16 * 68 + 0;
  const f16* AB20 = Abuf + 32 * 68 + 0;
  const f16* AB21 = Abuf + 32 * 68 + 16;
  const f16* AB30 = Abuf + 48 * 68 + 0;
  const f16* AB31 = Abuf + 48 * 68 + 16;
  const f16* AB32 = Abuf + 48 * 68 + 32;
  f4 z = {};
  f4 x20, x30;

  if (wv == 0) wr_T(Xp[0], mm16(AB10, 68, Dt[0], z, l15, l4), l15, l4, 1.f);
  if (wv == 1) wr_T(Xp[1], mm16(AB21, 68, Dt[1], z, l15, l4), l15, l4, 1.f);
  if (wv == 2) wr_T(Xp[2], mm16(AB32, 68, Dt[2], z, l15, l4), l15, l4, 1.f);
  if (wv == 3) x20 = mm16(AB20, 68, Dt[0], z, l15, l4);
  __syncthreads();
  if (wv == 0) { f4 r = mm16(Dr[1], 20, Xp[0], z, l15, l4); wr_T(Tp[0], r, l15, l4, -1.f); wr_Tb(Tb, 1, 0, r, betas, l15, l4, -1.f); }
  if (wv == 1) { f4 r = mm16(Dr[2], 20, Xp[1], z, l15, l4); wr_T(Tp[1], r, l15, l4, -1.f); wr_Tb(Tb, 2, 1, r, betas, l15, l4, -1.f); }
  if (wv == 2) { f4 r = mm16(Dr[3], 20, Xp[2], z, l15, l4); wr_Tb(Tb, 3, 2, r, betas, l15, l4, -1.f); }
  if (wv == 3) x30 = mm16(AB30, 68, Dt[0], z, l15, l4);
  __syncthreads();
  if (wv == 3) wr_T(Xp[0], mm16(AB21, 68, Tp[0], x20, l15, l4), l15, l4, 1.f);
  if (wv == 1) { f4 r = mm16(AB31, 68, Dt[1], z, l15, l4); r = mm16(AB32, 68, Tp[1], r, l15, l4); wr_T(Xp[1], r, l15, l4, 1.f); }
  __syncthreads();
  if (wv == 3) { f4 r = mm16(Dr[2], 20, Xp[0], z, l15, l4); wr_T(Tp[2], r, l15, l4, -1.f); wr_Tb(Tb, 2, 0, r, betas, l15, l4, -1.f); }
  if (wv == 1) { f4 r = mm16(Dr[3], 20, Xp[1], z, l15, l4); wr_Tb(Tb, 3, 1, r, betas, l15, l4, -1.f); }
  __syncthreads();
  if (wv == 3) { f4 r = mm16(AB31, 68, Tp[0], x30, l15, l4); r = mm16(AB32, 68, Tp[2], r, l15, l4); wr_T(Xp[2], r, l15, l4, 1.f); }
  __syncthreads();
  if (wv == 3) { f4 r = mm16(Dr[3], 20, Xp[2], z, l15, l4); wr_Tb(Tb, 3, 0, r, betas, l15, l4, -1.f); }
  __syncthreads();

  const size_t wub = ((size_t)bh * NC + c) * 8192;
  const int koff = l4 * 8;
  f4 wacc[8] = {}, uacc[8] = {};
#pragma unroll
  for (int kc = 0; kc < 2; ++kc) {
    const h8 aT = *(const h8*)(Tb + (wv * 16 + l15) * 72 + kc * 32 + koff);
#pragma unroll
    for (int f = 0; f < 8; ++f) {
      const int d = f * 16 + l15, cD = d >> 3, d7 = d & 7;
      h8 bK, bV;
#pragma unroll
      for (int j = 0; j < 8; ++j) {
        const int t2 = kc * 32 + koff + j;
        const int pos = t2 * 128 + swz16(t2, cD) * 8 + d7;
        bK[j] = Ks[pos];
        bV[j] = QVs[pos];
      }
      wacc[f] = __builtin_amdgcn_mfma_f32_16x16x32_f16(aT, bK, wacc[f], 0, 0, 0);
      uacc[f] = __builtin_amdgcn_mfma_f32_16x16x32_f16(aT, bV, uacc[f], 0, 0, 0);
    }
  }
#pragma unroll
  for (int f = 0; f < 8; ++f) {
    const int d = f * 16 + l15, cD = d >> 3, d7 = d & 7;
#pragma unroll
    for (int q = 0; q < 4; ++q) {
      const int i = wv * 16 + l4 * 4 + q;
      wbuf[wub + (size_t)i * 128 + swz16(i, cD) * 8 + d7] = (f16)wacc[f][q];
    }
    h4 uv = {(f16)uacc[f][0], (f16)uacc[f][1], (f16)uacc[f][2], (f16)uacc[f][3]};
    *(h4*)(utbuf + wub + (size_t)d * 64 + wv * 16 + l4 * 4) = uv;
  }

#pragma unroll
  for (int i2 = 0; i2 < 4; ++i2) {
    const int ch = tid + i2 * 256;
    const int dp = ch & 127, c2 = ch >> 7;
    h8 v;
#pragma unroll
    for (int j = 0; j < 8; ++j) {
      const int i = c2 * 8 + j;
      v[j] = Ks[i * 128 + swz16(i, dp >> 3) * 8 + (dp & 7)];
    }
    *(h8*)(ktbuf + wub + (size_t)dp * 64 + (c2 ^ (dp & 7)) * 8) = v;
  }
}

// ---------------- Phase B: chunk recurrence ---------------------------------
__global__ __launch_bounds__(256) void phaseB(const f16* __restrict__ qb, const f16* __restrict__ ktbuf,
                                              const f16* __restrict__ wbuf, const f16* __restrict__ utbuf,
                                              const f16* __restrict__ pbuf, f16* __restrict__ obuf) {
  const int blk = blockIdx.x;
  const int bh = blk >> 2, g = blk & 3;
  const int b = bh >> 3, h = bh & 7;
  const int tid = threadIdx.x, lane = tid & 63, wv = tid >> 6;
  const int l15 = lane & 15, l4 = lane >> 4;

  __shared__ __align__(16) f16 Ws[2][8192];
  __shared__ __align__(16) f16 Qs[2][8192];
  __shared__ __align__(16) f16 Kts[2][8192];
  __shared__ __align__(16) f16 Rt[32 * 72];
  __shared__ __align__(16) f16 Ms[32 * 136];

  for (int i = tid; i < 32 * 136; i += 256) Ms[i] = (f16)0.f;
  f4 macc[2][2] = {};

  const int arow = wv * 16 + l15;
  const int koff = l4 * 8;

  auto STAGE = [&](int c2, int buf) {
#pragma unroll
    for (int i = 0; i < 4; ++i) {
      const int ch = tid + i * 256;
      const size_t tb = ((size_t)bh * NC + c2) * 8192;
      __builtin_amdgcn_global_load_lds(AS1(wbuf + tb + ch * 8), AS3(Ws[buf] + ch * 8), 16, 0, 0);
      __builtin_amdgcn_global_load_lds(AS1(ktbuf + tb + ch * 8), AS3(Kts[buf] + ch * 8), 16, 0, 0);
      const int rr = ch >> 4, kc2 = ch & 15;
      __builtin_amdgcn_global_load_lds(AS1(qb + ((size_t)((c2 * 64 + rr) * 4 + b)) * 1024 + h * 128 + kc2 * 8),
                                       AS3(Qs[buf] + ch * 8), 16, 0, 0);
    }
  };

  STAGE(0, 0);
  asm volatile("s_waitcnt vmcnt(0)" ::: "memory");
  __builtin_amdgcn_s_barrier();

  for (int c = 0; c < NC; ++c) {
    const int cur = c & 1, nxt = cur ^ 1;
    const size_t pcb = ((size_t)bh * NC + c) * 4096;
    const h8 aP0 = *(const h8*)(pbuf + pcb + arow * 64 + koff);
    const h8 aP1 = *(const h8*)(pbuf + pcb + arow * 64 + 32 + koff);
    const size_t ucb = ((size_t)bh * NC + c) * 8192;
    const h4 u0 = *(const h4*)(utbuf + ucb + (size_t)(g * 32 + l15) * 64 + wv * 16 + l4 * 4);
    const h4 u1 = *(const h4*)(utbuf + ucb + (size_t)(g * 32 + 16 + l15) * 64 + wv * 16 + l4 * 4);
    asm volatile("s_waitcnt vmcnt(4)" ::: "memory");
    asm volatile("s_waitcnt lgkmcnt(0)" ::: "memory");
    __builtin_amdgcn_s_barrier();
    if (c + 1 < NC) STAGE(c + 1, nxt);

    f4 accR[2] = {}, accO[2] = {};
    __builtin_amdgcn_s_setprio(1);
#pragma unroll
    for (int kc = 0; kc < 4; ++kc) {
      const int c4 = kc * 4 + l4;
      const h8 aW = *(const h8*)(Ws[cur] + arow * 128 + swz16(arow, c4) * 8);
      const h8 aQ = *(const h8*)(Qs[cur] + arow * 128 + swz16(arow, c4) * 8);
#pragma unroll
      for (int f = 0; f < 2; ++f) {
        const h8 bM = *(const h8*)(Ms + (f * 16 + l15) * 136 + kc * 32 + koff);
        accR[f] = __builtin_amdgcn_mfma_f32_16x16x32_f16(aW, bM, accR[f], 0, 0, 0);
        accO[f] = __builtin_amdgcn_mfma_f32_16x16x32_f16(aQ, bM, accO[f], 0, 0, 0);
      }
    }
    __builtin_amdgcn_s_setprio(0);
    if (c + 1 < NC) asm volatile("s_waitcnt vmcnt(12)" ::: "memory");
    else            asm volatile("s_waitcnt vmcnt(0)" ::: "memory");
#pragma unroll
    for (int f = 0; f < 2; ++f) {
      const h4 uu = f ? u1 : u0;
      h4 rw;
#pragma unroll
      for (int q = 0; q < 4; ++q) {
        const float rv = (float)uu[q] - accR[f][q];
        accR[f][q] = rv;
        rw[q] = (f16)rv;
      }
      *(h4*)(Rt + (f * 16 + l15) * 72 + wv * 16 + l4 * 4) = rw;
    }
    asm volatile("s_waitcnt lgkmcnt(0)" ::: "memory");
    __builtin_amdgcn_s_barrier();

#pragma unroll
    for (int kc = 0; kc < 2; ++kc) {
      const h8 aP = kc ? aP1 : aP0;
#pragma unroll
      for (int f = 0; f < 2; ++f) {
        const h8 bR = *(const h8*)(Rt + (f * 16 + l15) * 72 + kc * 32 + koff);
        accO[f] = __builtin_amdgcn_mfma_f32_16x16x32_f16(aP, bR, accO[f], 0, 0, 0);
      }
    }
#pragma unroll
    for (int f = 0; f < 2; ++f)
#pragma unroll
      for (int q = 0; q < 4; ++q) {
        const int i = wv * 16 + l4 * 4 + q;
        const int cc = f * 16 + l15;
        obuf[((size_t)(c * 64 + i) * Bb_ + b) * Dd + h * 128 + g * 32 + cc] = (f16)accO[f][q];
      }

#pragma unroll
    for (int kc = 0; kc < 2; ++kc) {
      const h8 aR0 = *(const h8*)(Rt + l15 * 72 + kc * 32 + koff);
      const h8 aR1 = *(const h8*)(Rt + (16 + l15) * 72 + kc * 32 + koff);
#pragma unroll
      for (int cf = 0; cf < 2; ++cf) {
        const int kcol = wv * 32 + cf * 16 + l15;
        const int c2 = kc * 4 + l4;
        const h8 bKv = *(const h8*)(Kts[cur] + kcol * 64 + (c2 ^ (kcol & 7)) * 8);
        macc[0][cf] = __builtin_amdgcn_mfma_f32_16x16x32_f16(aR0, bKv, macc[0][cf], 0, 0, 0);
        macc[1][cf] = __builtin_amdgcn_mfma_f32_16x16x32_f16(aR1, bKv, macc[1][cf], 0, 0, 0);
      }
    }
#pragma unroll
    for (int rf = 0; rf < 2; ++rf)
#pragma unroll
      for (int cf = 0; cf < 2; ++cf)
#pragma unroll
        for (int q = 0; q < 4; ++q) {
          const int cr = rf * 16 + l4 * 4 + q;
          const int kcol = wv * 32 + cf * 16 + l15;
          Ms[cr * 136 + kcol] = (f16)macc[rf][cf][q];
        }
  }
}

// ---------------------------------------------------------------------------
extern "C" void kernel_launch(void* const* d_in, const int* in_sizes, int n_in,
                              void* d_out, int out_size, void* d_ws, size_t ws_size,
                              hipStream_t stream) {
  (void)in_sizes; (void)n_in;
  const float* input = (const float*)d_in[0];
  const float* Wq = (const float*)d_in[1];
  const float* Wk = (const float*)d_in[2];
  const float* Wv = (const float*)d_in[3];
  const float* Wb = (const float*)d_in[4];
  const float* Wo = (const float*)d_in[5];
  const float* onw = (const float*)d_in[6];
  const float* n1w = (const float*)d_in[7];
  const float* n2w = (const float*)d_in[8];
  const float* Wg = (const float*)d_in[9];
  const float* Wd = (const float*)d_in[10];
  const float* fnw = (const float*)d_in[11];

  char* ws = (char*)d_ws;
  size_t off = 0;
  auto alloc = [&](size_t bytes) { void* p = ws + off; off += (bytes + 255) & ~(size_t)255; return p; };
  const size_t RD = 8192ull * 1024ull;
  f16*  x     = (f16*)alloc(RD * 2);
  f16*  qb    = (f16*)alloc(RD * 2);
  f16*  kbuf  = (f16*)alloc(RD * 2);
  f16*  vbuf  = (f16*)alloc(RD * 2);
  float* beta = (float*)alloc(8192ull * 8 * 4);
  float* rs   = (float*)alloc(8192ull * 4);
  float* Wb2  = (float*)alloc(1024ull * 8 * 4);
  f16*  wbuf  = (f16*)alloc(RD * 2);
  f16*  utbuf = (f16*)alloc(RD * 2);
  f16*  ktbuf = (f16*)alloc(RD * 2);
  f16*  pbuf  = (f16*)alloc(32ull * 32 * 64 * 64 * 2);
  char* arena = (char*)alloc(3 * RD * 2);
  f16*  WqkvT = (f16*)alloc(3072ull * 1024 * 2);
  f16*  WoT   = (f16*)alloc(1024ull * 1024 * 2);
  f16*  WgT   = (f16*)alloc(5632ull * 1024 * 2);
  f16*  WdT   = (f16*)alloc(1024ull * 2816 * 2);
  if (off > ws_size) {
    fill_k<<<(out_size + 255) / 256, 256, 0, stream>>>((float*)d_out, out_size, 1.0e6f);
    return;
  }
  f16* qkvraw = (f16*)arena;
  f16* obuf = (f16*)arena;
  f16* my = qb;     // qb/kbuf/vbuf dead by the MLP
  f16* ob = wbuf;   // wbuf dead after phaseB

  cvt_k<<<4096, 256, 0, stream>>>(input, x);

  for (int l = 0; l < 2; ++l) {
    const size_t o2 = (size_t)l * 1024 * 1024;
    transpose_k<1><<<dim3(32, 32), 256, 0, stream>>>(Wq + o2, n1w + l * 1024, WqkvT, 1024, 1024);
    transpose_k<1><<<dim3(32, 32), 256, 0, stream>>>(Wk + o2, n1w + l * 1024, WqkvT + 1024ull * 1024, 1024, 1024);
    transpose_k<1><<<dim3(32, 32), 256, 0, stream>>>(Wv + o2, n1w + l * 1024, WqkvT + 2048ull * 1024, 1024, 1024);
    transpose_k<0><<<dim3(32, 32), 256, 0, stream>>>(Wo + o2, nullptr, WoT, 1024, 1024);
    transpose_k<1><<<dim3(176, 32), 256, 0, stream>>>(Wg + (size_t)l * 1024 * 5632, n2w + l * 1024, WgT, 1024, 5632);
    transpose_k<0><<<dim3(32, 88), 256, 0, stream>>>(Wd + (size_t)l * 2816 * 1024, nullptr, WdT, 2816, 1024);
    bweight_k<<<32, 256, 0, stream>>>(Wb + (size_t)l * 1024 * 8, n1w + l * 1024, Wb2);

    rowscale_k<<<2048, 256, 0, stream>>>(x, rs);
    gemm2<2, 1><<<32 * 24, 512, 0, stream>>>(x, WqkvT, qkvraw, rs, 8192, 3072, 1024, 24);
    beta_k<<<2048, 256, 0, stream>>>(x, Wb2, rs, beta);
    qkv_epi<<<8192, 256, 0, stream>>>(qkvraw, qb, kbuf, vbuf);
    phaseA<<<1024, 256, 0, stream>>>(kbuf, qb, vbuf, beta, wbuf, utbuf, pbuf, ktbuf);
    phaseB<<<128, 256, 0, stream>>>(qb, ktbuf, wbuf, utbuf, pbuf, obuf);
    onorm_k<<<8192, 256, 0, stream>>>(obuf, onw + l * 128, ob);
    gemm2<1, 0><<<32 * 8, 512, 0, stream>>>(ob, WoT, x, nullptr, 8192, 1024, 1024, 8);

    rowscale_k<<<2048, 256, 0, stream>>>(x, rs);
    gemmGLU<<<32 * 22, 512, 0, stream>>>(x, WgT, rs, my, 1024, 22);
    gemm2<1, 0><<<32 * 8, 512, 0, stream>>>(my, WdT, x, nullptr, 8192, 1024, 2816, 8);
  }
  rmsnorm_f<<<8192, 256, 0, stream>>>(x, fnw, (float*)d_out);
}

// Round 11
// 943.558 us; speedup vs baseline: 1.8240x; 1.0483x over previous
//
#include <hip/hip_runtime.h>
#include <hip/hip_bf16.h>
#include <cstdint>

// DeltaNet forward, MI355X. Round 11: phaseB g-split 4->8 (full CU coverage),
// qkv_epi fused into QKV GEMM epilogue (l2norm in-epilogue, qkvraw killed).

typedef _Float16 f16;
typedef __attribute__((ext_vector_type(8))) _Float16 h8;
typedef __attribute__((ext_vector_type(4))) _Float16 h4;
typedef __attribute__((ext_vector_type(4))) float f4;

#define DEV __device__ __forceinline__

static constexpr int Bb_ = 4;
static constexpr int Hh  = 8;
static constexpr int Dd  = 1024;
static constexpr int Tt  = 2048;
static constexpr int NC  = 32;

DEV float siluf(float x) { return x / (1.f + expf(-x)); }
DEV int swz16(int row, int c) { return (c & 8) | ((c & 7) ^ (row & 7)); }

#define AS1(p) ((const __attribute__((address_space(1))) void*)(uintptr_t)(p))
#define AS3(p) ((__attribute__((address_space(3))) void*)(uint32_t)(uintptr_t)(p))

DEV h8 rd_sw(const f16* T, int row, int chunk) {
  return *(const h8*)(T + (((row << 3) | (chunk ^ (row & 7))) * 8));
}

// ================= 2-phase GEMM: C[M,N] op= A[M,K]*Bt[N,K]^T, BN=128 =======
// EPI 1: f16 += ; EPI 2: f16 store (xSC row-scale).
template<int EPI, int SC>
__global__ __launch_bounds__(512, 2) void gemm2(const f16* __restrict__ A, const f16* __restrict__ Bt,
                                                void* __restrict__ C, const float* __restrict__ rs,
                                                int M, int N, int K, int gx) {
  __shared__ __align__(16) f16 ldsA[2][16384];
  __shared__ __align__(16) f16 ldsB[2][8192];
  const int tid = threadIdx.x, lane = tid & 63, w = tid >> 6;
  const int l15 = lane & 15, l4 = lane >> 4;
  const int wr = w >> 2, wc = w & 3;
  const int nwg = gridDim.x;
  int flat = blockIdx.x;
  if ((nwg & 7) == 0) flat = (flat & 7) * (nwg >> 3) + (flat >> 3);
  const int bx = flat % gx, by = flat / gx;

  const f16* Ab = A + (size_t)by * 256 * K;
  const f16* Bb = Bt + (size_t)bx * 128 * K;
  const int NT = K >> 6;
  f4 acc[8][2] = {};

  const int r0 = tid >> 3;
  const size_t soff0 = (size_t)r0 * K + (size_t)(((tid & 7) ^ (r0 & 7)) * 8);
  const size_t soff1 = soff0 + (size_t)64 * K;
  const int dof = tid * 8;
  auto STG = [&](const f16* base, f16* dst) {
    __builtin_amdgcn_global_load_lds(AS1(base + soff0), AS3(dst + dof), 16, 0, 0);
    __builtin_amdgcn_global_load_lds(AS1(base + soff1), AS3(dst + 4096 + dof), 16, 0, 0);
  };

  STG(Bb, ldsB[0]);
  STG(Ab, ldsA[0]);
  STG(Ab + (size_t)128 * K, ldsA[0] + 8192);
  if (NT > 1) {
    STG(Bb + 64, ldsB[1]);
    asm volatile("s_waitcnt vmcnt(2)");
  } else {
    asm volatile("s_waitcnt vmcnt(0)");
  }
  __builtin_amdgcn_s_barrier();

  for (int t = 0; t < NT; ++t) {
    const int cur = t & 1, nxt = cur ^ 1;
    const f16* cA = ldsA[cur];
    const f16* cB = ldsB[cur];
    h8 b[2][2], aX[2][2], aY[2][2];
#pragma unroll
    for (int cf = 0; cf < 2; ++cf)
#pragma unroll
      for (int ks = 0; ks < 2; ++ks)
        b[cf][ks] = rd_sw(cB, wc * 32 + cf * 16 + l15, ks * 4 + l4);
#pragma unroll
    for (int fr = 0; fr < 2; ++fr)
#pragma unroll
      for (int ks = 0; ks < 2; ++ks)
        aX[fr][ks] = rd_sw(cA, wr * 128 + fr * 16 + l15, ks * 4 + l4);
    if (t + 1 < NT) { STG(Ab + (t + 1) * 64, ldsA[nxt]); STG(Ab + (size_t)128 * K + (t + 1) * 64, ldsA[nxt] + 8192); }
    __builtin_amdgcn_s_setprio(1);
#pragma unroll
    for (int fr = 0; fr < 2; ++fr)
#pragma unroll
      for (int cf = 0; cf < 2; ++cf)
#pragma unroll
        for (int ks = 0; ks < 2; ++ks)
          acc[fr][cf] = __builtin_amdgcn_mfma_f32_16x16x32_f16(aX[fr][ks], b[cf][ks], acc[fr][cf], 0, 0, 0);
#pragma unroll
    for (int fr = 0; fr < 2; ++fr)
#pragma unroll
      for (int ks = 0; ks < 2; ++ks)
        aY[fr][ks] = rd_sw(cA, wr * 128 + 32 + fr * 16 + l15, ks * 4 + l4);
#pragma unroll
    for (int fr = 0; fr < 2; ++fr)
#pragma unroll
      for (int cf = 0; cf < 2; ++cf)
#pragma unroll
        for (int ks = 0; ks < 2; ++ks)
          acc[2 + fr][cf] = __builtin_amdgcn_mfma_f32_16x16x32_f16(aY[fr][ks], b[cf][ks], acc[2 + fr][cf], 0, 0, 0);
    __builtin_amdgcn_s_setprio(0);
    __builtin_amdgcn_s_barrier();
#pragma unroll
    for (int fr = 0; fr < 2; ++fr)
#pragma unroll
      for (int ks = 0; ks < 2; ++ks)
        aX[fr][ks] = rd_sw(cA, wr * 128 + 64 + fr * 16 + l15, ks * 4 + l4);
    if (t + 2 < NT) STG(Bb + (t + 2) * 64, ldsB[cur]);
    __builtin_amdgcn_s_setprio(1);
#pragma unroll
    for (int fr = 0; fr < 2; ++fr)
#pragma unroll
      for (int cf = 0; cf < 2; ++cf)
#pragma unroll
        for (int ks = 0; ks < 2; ++ks)
          acc[4 + fr][cf] = __builtin_amdgcn_mfma_f32_16x16x32_f16(aX[fr][ks], b[cf][ks], acc[4 + fr][cf], 0, 0, 0);
#pragma unroll
    for (int fr = 0; fr < 2; ++fr)
#pragma unroll
      for (int ks = 0; ks < 2; ++ks)
        aY[fr][ks] = rd_sw(cA, wr * 128 + 96 + fr * 16 + l15, ks * 4 + l4);
#pragma unroll
    for (int fr = 0; fr < 2; ++fr)
#pragma unroll
      for (int cf = 0; cf < 2; ++cf)
#pragma unroll
        for (int ks = 0; ks < 2; ++ks)
          acc[6 + fr][cf] = __builtin_amdgcn_mfma_f32_16x16x32_f16(aY[fr][ks], b[cf][ks], acc[6 + fr][cf], 0, 0, 0);
    __builtin_amdgcn_s_setprio(0);
    if (t + 2 < NT)      asm volatile("s_waitcnt vmcnt(2)" ::: "memory");
    else if (t + 1 < NT) asm volatile("s_waitcnt vmcnt(0)" ::: "memory");
    __builtin_amdgcn_s_barrier();
  }

#pragma unroll
  for (int fr = 0; fr < 8; ++fr) {
#pragma unroll
    for (int cf = 0; cf < 2; ++cf) {
      const int row0 = by * 256 + wr * 128 + fr * 16 + l4 * 4;
      const int col = bx * 128 + wc * 32 + cf * 16 + l15;
#pragma unroll
      for (int q = 0; q < 4; ++q) {
        const size_t idx = (size_t)(row0 + q) * N + col;
        float v = acc[fr][cf][q];
        if (SC) v *= rs[row0 + q];
        if (EPI == 1) ((f16*)C)[idx] = (f16)((float)((f16*)C)[idx] + v);
        if (EPI == 2) ((f16*)C)[idx] = (f16)v;
      }
    }
  }
}

// ============ QKV GEMM with fused silu+l2norm epilogue =====================
// N=3072 over WqkvT=[WqT;WkT;WvT]; bx<8: Q head bx; 8..15: K head; 16..23: V.
__global__ __launch_bounds__(512, 2) void gemmQKV(const f16* __restrict__ A, const f16* __restrict__ Bt,
                                                  const float* __restrict__ rs, f16* __restrict__ qb,
                                                  f16* __restrict__ kb, f16* __restrict__ vb,
                                                  int K, int gx) {
  __shared__ __align__(16) f16 ldsA[2][16384];
  __shared__ __align__(16) f16 ldsB[2][8192];
  __shared__ float ps[4][256];
  const int tid = threadIdx.x, lane = tid & 63, w = tid >> 6;
  const int l15 = lane & 15, l4 = lane >> 4;
  const int wr = w >> 2, wc = w & 3;
  const int nwg = gridDim.x;
  int flat = blockIdx.x;
  if ((nwg & 7) == 0) flat = (flat & 7) * (nwg >> 3) + (flat >> 3);
  const int bx = flat % gx, by = flat / gx;

  const f16* Ab = A + (size_t)by * 256 * K;
  const f16* Bb = Bt + (size_t)bx * 128 * K;
  const int NT = K >> 6;
  f4 acc[8][2] = {};

  const int r0 = tid >> 3;
  const size_t soff0 = (size_t)r0 * K + (size_t)(((tid & 7) ^ (r0 & 7)) * 8);
  const size_t soff1 = soff0 + (size_t)64 * K;
  const int dof = tid * 8;
  auto STG = [&](const f16* base, f16* dst) {
    __builtin_amdgcn_global_load_lds(AS1(base + soff0), AS3(dst + dof), 16, 0, 0);
    __builtin_amdgcn_global_load_lds(AS1(base + soff1), AS3(dst + 4096 + dof), 16, 0, 0);
  };

  STG(Bb, ldsB[0]);
  STG(Ab, ldsA[0]);
  STG(Ab + (size_t)128 * K, ldsA[0] + 8192);
  if (NT > 1) {
    STG(Bb + 64, ldsB[1]);
    asm volatile("s_waitcnt vmcnt(2)");
  } else {
    asm volatile("s_waitcnt vmcnt(0)");
  }
  __builtin_amdgcn_s_barrier();

  for (int t = 0; t < NT; ++t) {
    const int cur = t & 1, nxt = cur ^ 1;
    const f16* cA = ldsA[cur];
    const f16* cB = ldsB[cur];
    h8 b[2][2], aX[2][2], aY[2][2];
#pragma unroll
    for (int cf = 0; cf < 2; ++cf)
#pragma unroll
      for (int ks = 0; ks < 2; ++ks)
        b[cf][ks] = rd_sw(cB, wc * 32 + cf * 16 + l15, ks * 4 + l4);
#pragma unroll
    for (int fr = 0; fr < 2; ++fr)
#pragma unroll
      for (int ks = 0; ks < 2; ++ks)
        aX[fr][ks] = rd_sw(cA, wr * 128 + fr * 16 + l15, ks * 4 + l4);
    if (t + 1 < NT) { STG(Ab + (t + 1) * 64, ldsA[nxt]); STG(Ab + (size_t)128 * K + (t + 1) * 64, ldsA[nxt] + 8192); }
    __builtin_amdgcn_s_setprio(1);
#pragma unroll
    for (int fr = 0; fr < 2; ++fr)
#pragma unroll
      for (int cf = 0; cf < 2; ++cf)
#pragma unroll
        for (int ks = 0; ks < 2; ++ks)
          acc[fr][cf] = __builtin_amdgcn_mfma_f32_16x16x32_f16(aX[fr][ks], b[cf][ks], acc[fr][cf], 0, 0, 0);
#pragma unroll
    for (int fr = 0; fr < 2; ++fr)
#pragma unroll
      for (int ks = 0; ks < 2; ++ks)
        aY[fr][ks] = rd_sw(cA, wr * 128 + 32 + fr * 16 + l15, ks * 4 + l4);
#pragma unroll
    for (int fr = 0; fr < 2; ++fr)
#pragma unroll
      for (int cf = 0; cf < 2; ++cf)
#pragma unroll
        for (int ks = 0; ks < 2; ++ks)
          acc[2 + fr][cf] = __builtin_amdgcn_mfma_f32_16x16x32_f16(aY[fr][ks], b[cf][ks], acc[2 + fr][cf], 0, 0, 0);
    __builtin_amdgcn_s_setprio(0);
    __builtin_amdgcn_s_barrier();
#pragma unroll
    for (int fr = 0; fr < 2; ++fr)
#pragma unroll
      for (int ks = 0; ks < 2; ++ks)
        aX[fr][ks] = rd_sw(cA, wr * 128 + 64 + fr * 16 + l15, ks * 4 + l4);
    if (t + 2 < NT) STG(Bb + (t + 2) * 64, ldsB[cur]);
    __builtin_amdgcn_s_setprio(1);
#pragma unroll
    for (int fr = 0; fr < 2; ++fr)
#pragma unroll
      for (int cf = 0; cf < 2; ++cf)
#pragma unroll
        for (int ks = 0; ks < 2; ++ks)
          acc[4 + fr][cf] = __builtin_amdgcn_mfma_f32_16x16x32_f16(aX[fr][ks], b[cf][ks], acc[4 + fr][cf], 0, 0, 0);
#pragma unroll
    for (int fr = 0; fr < 2; ++fr)
#pragma unroll
      for (int ks = 0; ks < 2; ++ks)
        aY[fr][ks] = rd_sw(cA, wr * 128 + 96 + fr * 16 + l15, ks * 4 + l4);
#pragma unroll
    for (int fr = 0; fr < 2; ++fr)
#pragma unroll
      for (int cf = 0; cf < 2; ++cf)
#pragma unroll
        for (int ks = 0; ks < 2; ++ks)
          acc[6 + fr][cf] = __builtin_amdgcn_mfma_f32_16x16x32_f16(aY[fr][ks], b[cf][ks], acc[6 + fr][cf], 0, 0, 0);
    __builtin_amdgcn_s_setprio(0);
    if (t + 2 < NT)      asm volatile("s_waitcnt vmcnt(2)" ::: "memory");
    else if (t + 1 < NT) asm volatile("s_waitcnt vmcnt(0)" ::: "memory");
    __builtin_amdgcn_s_barrier();
  }

  // ---- epilogue: silu(rs*acc); Q/K: per-row l2norm over head; scatter ----
#pragma unroll
  for (int fr = 0; fr < 8; ++fr)
#pragma unroll
    for (int q = 0; q < 4; ++q) {
      const int grow = by * 256 + wr * 128 + fr * 16 + l4 * 4 + q;
      const float s = rs[grow];
#pragma unroll
      for (int cf = 0; cf < 2; ++cf)
        acc[fr][cf][q] = siluf(s * acc[fr][cf][q]);
    }
  if (bx < 16) {
    float sq[8][4];
#pragma unroll
    for (int fr = 0; fr < 8; ++fr)
#pragma unroll
      for (int q = 0; q < 4; ++q) {
        float v = acc[fr][0][q] * acc[fr][0][q] + acc[fr][1][q] * acc[fr][1][q];
#pragma unroll
        for (int m = 1; m < 16; m <<= 1) v += __shfl_xor(v, m);
        sq[fr][q] = v;
      }
    if (l15 == 0) {
#pragma unroll
      for (int fr = 0; fr < 8; ++fr)
#pragma unroll
        for (int q = 0; q < 4; ++q)
          ps[wc][wr * 128 + fr * 16 + l4 * 4 + q] = sq[fr][q];
    }
    __syncthreads();
#pragma unroll
    for (int fr = 0; fr < 8; ++fr)
#pragma unroll
      for (int q = 0; q < 4; ++q) {
        const int rl = wr * 128 + fr * 16 + l4 * 4 + q;
        const float sc = rsqrtf(ps[0][rl] + ps[1][rl] + ps[2][rl] + ps[3][rl] + 1e-6f);
#pragma unroll
        for (int cf = 0; cf < 2; ++cf) acc[fr][cf][q] *= sc;
      }
  }
  f16* dst = (bx < 8) ? qb : ((bx < 16) ? kb : vb);
  const int head = bx & 7;
#pragma unroll
  for (int fr = 0; fr < 8; ++fr)
#pragma unroll
    for (int cf = 0; cf < 2; ++cf)
#pragma unroll
      for (int q = 0; q < 4; ++q) {
        const int grow = by * 256 + wr * 128 + fr * 16 + l4 * 4 + q;
        const int i = (grow >> 2) & 63;
        const int dh = wc * 32 + cf * 16 + l15;
        dst[(size_t)grow * 1024 + head * 128 + swz16(i, dh >> 3) * 8 + (dh & 7)] = (f16)acc[fr][cf][q];
      }
}

// ============ fused GLU GEMM (2-phase) =====================================
__global__ __launch_bounds__(512, 2) void gemmGLU(const f16* __restrict__ A, const f16* __restrict__ WgT,
                                                  const float* __restrict__ rs, f16* __restrict__ my,
                                                  int K, int gx) {
  __shared__ __align__(16) f16 ldsA[2][16384];
  __shared__ __align__(16) f16 ldsG[2][8192];
  __shared__ __align__(16) f16 ldsY[2][8192];
  const int tid = threadIdx.x, lane = tid & 63, w = tid >> 6;
  const int l15 = lane & 15, l4 = lane >> 4;
  const int wr = w >> 2, wc = w & 3;
  const int nwg = gridDim.x;
  int flat = blockIdx.x;
  if ((nwg & 7) == 0) flat = (flat & 7) * (nwg >> 3) + (flat >> 3);
  const int bx = flat % gx, by = flat / gx;

  const f16* Ab = A + (size_t)by * 256 * K;
  const f16* Gb = WgT + (size_t)bx * 128 * K;
  const f16* Yb = WgT + (size_t)(2816 + bx * 128) * K;
  const int NT = K >> 6;
  f4 accG[8][2] = {}, accY[8][2] = {};

  const int r0 = tid >> 3;
  const size_t soff0 = (size_t)r0 * K + (size_t)(((tid & 7) ^ (r0 & 7)) * 8);
  const size_t soff1 = soff0 + (size_t)64 * K;
  const int dof = tid * 8;
  auto STG = [&](const f16* base, f16* dst) {
    __builtin_amdgcn_global_load_lds(AS1(base + soff0), AS3(dst + dof), 16, 0, 0);
    __builtin_amdgcn_global_load_lds(AS1(base + soff1), AS3(dst + 4096 + dof), 16, 0, 0);
  };

  STG(Gb, ldsG[0]);
  STG(Yb, ldsY[0]);
  STG(Ab, ldsA[0]);
  STG(Ab + (size_t)128 * K, ldsA[0] + 8192);
  if (NT > 1) {
    STG(Gb + 64, ldsG[1]);
    STG(Yb + 64, ldsY[1]);
    asm volatile("s_waitcnt vmcnt(4)");
  } else {
    asm volatile("s_waitcnt vmcnt(0)");
  }
  __builtin_amdgcn_s_barrier();

  for (int t = 0; t < NT; ++t) {
    const int cur = t & 1, nxt = cur ^ 1;
    const f16* cA = ldsA[cur];
    h8 bg[2][2], byv[2][2], aX[2][2], aY[2][2];
#pragma unroll
    for (int cf = 0; cf < 2; ++cf)
#pragma unroll
      for (int ks = 0; ks < 2; ++ks) {
        bg[cf][ks] = rd_sw(ldsG[cur], wc * 32 + cf * 16 + l15, ks * 4 + l4);
        byv[cf][ks] = rd_sw(ldsY[cur], wc * 32 + cf * 16 + l15, ks * 4 + l4);
      }
#pragma unroll
    for (int fr = 0; fr < 2; ++fr)
#pragma unroll
      for (int ks = 0; ks < 2; ++ks)
        aX[fr][ks] = rd_sw(cA, wr * 128 + fr * 16 + l15, ks * 4 + l4);
    if (t + 1 < NT) { STG(Ab + (t + 1) * 64, ldsA[nxt]); STG(Ab + (size_t)128 * K + (t + 1) * 64, ldsA[nxt] + 8192); }
    __builtin_amdgcn_s_setprio(1);
#pragma unroll
    for (int fr = 0; fr < 2; ++fr)
#pragma unroll
      for (int cf = 0; cf < 2; ++cf)
#pragma unroll
        for (int ks = 0; ks < 2; ++ks) {
          accG[fr][cf] = __builtin_amdgcn_mfma_f32_16x16x32_f16(aX[fr][ks], bg[cf][ks], accG[fr][cf], 0, 0, 0);
          accY[fr][cf] = __builtin_amdgcn_mfma_f32_16x16x32_f16(aX[fr][ks], byv[cf][ks], accY[fr][cf], 0, 0, 0);
        }
#pragma unroll
    for (int fr = 0; fr < 2; ++fr)
#pragma unroll
      for (int ks = 0; ks < 2; ++ks)
        aY[fr][ks] = rd_sw(cA, wr * 128 + 32 + fr * 16 + l15, ks * 4 + l4);
#pragma unroll
    for (int fr = 0; fr < 2; ++fr)
#pragma unroll
      for (int cf = 0; cf < 2; ++cf)
#pragma unroll
        for (int ks = 0; ks < 2; ++ks) {
          accG[2 + fr][cf] = __builtin_amdgcn_mfma_f32_16x16x32_f16(aY[fr][ks], bg[cf][ks], accG[2 + fr][cf], 0, 0, 0);
          accY[2 + fr][cf] = __builtin_amdgcn_mfma_f32_16x16x32_f16(aY[fr][ks], byv[cf][ks], accY[2 + fr][cf], 0, 0, 0);
        }
    __builtin_amdgcn_s_setprio(0);
    __builtin_amdgcn_s_barrier();
#pragma unroll
    for (int fr = 0; fr < 2; ++fr)
#pragma unroll
      for (int ks = 0; ks < 2; ++ks)
        aX[fr][ks] = rd_sw(cA, wr * 128 + 64 + fr * 16 + l15, ks * 4 + l4);
    if (t + 2 < NT) { STG(Gb + (t + 2) * 64, ldsG[cur]); STG(Yb + (t + 2) * 64, ldsY[cur]); }
    __builtin_amdgcn_s_setprio(1);
#pragma unroll
    for (int fr = 0; fr < 2; ++fr)
#pragma unroll
      for (int cf = 0; cf < 2; ++cf)
#pragma unroll
        for (int ks = 0; ks < 2; ++ks) {
          accG[4 + fr][cf] = __builtin_amdgcn_mfma_f32_16x16x32_f16(aX[fr][ks], bg[cf][ks], accG[4 + fr][cf], 0, 0, 0);
          accY[4 + fr][cf] = __builtin_amdgcn_mfma_f32_16x16x32_f16(aX[fr][ks], byv[cf][ks], accY[4 + fr][cf], 0, 0, 0);
        }
#pragma unroll
    for (int fr = 0; fr < 2; ++fr)
#pragma unroll
      for (int ks = 0; ks < 2; ++ks)
        aY[fr][ks] = rd_sw(cA, wr * 128 + 96 + fr * 16 + l15, ks * 4 + l4);
#pragma unroll
    for (int fr = 0; fr < 2; ++fr)
#pragma unroll
      for (int cf = 0; cf < 2; ++cf)
#pragma unroll
        for (int ks = 0; ks < 2; ++ks) {
          accG[6 + fr][cf] = __builtin_amdgcn_mfma_f32_16x16x32_f16(aY[fr][ks], bg[cf][ks], accG[6 + fr][cf], 0, 0, 0);
          accY[6 + fr][cf] = __builtin_amdgcn_mfma_f32_16x16x32_f16(aY[fr][ks], byv[cf][ks], accY[6 + fr][cf], 0, 0, 0);
        }
    __builtin_amdgcn_s_setprio(0);
    if (t + 2 < NT)      asm volatile("s_waitcnt vmcnt(4)" ::: "memory");
    else if (t + 1 < NT) asm volatile("s_waitcnt vmcnt(0)" ::: "memory");
    __builtin_amdgcn_s_barrier();
  }

#pragma unroll
  for (int fr = 0; fr < 8; ++fr) {
#pragma unroll
    for (int cf = 0; cf < 2; ++cf) {
      const int row0 = by * 256 + wr * 128 + fr * 16 + l4 * 4;
      const int col = bx * 128 + wc * 32 + cf * 16 + l15;
#pragma unroll
      for (int q = 0; q < 4; ++q) {
        const float s = rs[row0 + q];
        my[(size_t)(row0 + q) * 2816 + col] = (f16)(siluf(s * accG[fr][cf][q]) * (s * accY[fr][cf][q]));
      }
    }
  }
}

// ---------------- f32 -> f16 convert ---------------------------------------
__global__ __launch_bounds__(256) void cvt_k(const float* __restrict__ in, f16* __restrict__ out) {
  const size_t i = ((size_t)blockIdx.x * 256 + threadIdx.x) * 8;
  const float4 a = *(const float4*)(in + i);
  const float4 b = *(const float4*)(in + i + 4);
  h8 o = {(f16)a.x, (f16)a.y, (f16)a.z, (f16)a.w, (f16)b.x, (f16)b.y, (f16)b.z, (f16)b.w};
  *(h8*)(out + i) = o;
}

// ---------------- per-row rsqrt(mean(x^2)+eps) -----------------------------
__global__ __launch_bounds__(256) void rowscale_k(const f16* __restrict__ x, float* __restrict__ rs) {
  const int tid = threadIdx.x, lane = tid & 63, wv = tid >> 6;
  const int r = blockIdx.x * 4 + wv;
  const f16* row = x + (size_t)r * 1024 + lane * 16;
  const h8 v0 = *(const h8*)(row);
  const h8 v1 = *(const h8*)(row + 8);
  float ss = 0.f;
#pragma unroll
  for (int e = 0; e < 8; ++e) {
    const float a = (float)v0[e], b = (float)v1[e];
    ss += a * a + b * b;
  }
#pragma unroll
  for (int m = 1; m < 64; m <<= 1) ss += __shfl_xor(ss, m);
  if (lane == 0) rs[r] = rsqrtf(ss * (1.f / 1024.f) + 1e-6f);
}

// ---------------- final RMSNorm (f16 in, f32 out) --------------------------
__global__ __launch_bounds__(256) void rmsnorm_f(const f16* __restrict__ x, const float* __restrict__ w,
                                                 float* __restrict__ out) {
  const int r = blockIdx.x, tid = threadIdx.x;
  const h4 xv = *(const h4*)(x + (size_t)r * 1024 + tid * 4);
  const float v0 = (float)xv[0], v1 = (float)xv[1], v2 = (float)xv[2], v3 = (float)xv[3];
  float ss = v0 * v0 + v1 * v1 + v2 * v2 + v3 * v3;
#pragma unroll
  for (int m = 1; m < 64; m <<= 1) ss += __shfl_xor(ss, m);
  __shared__ float red[4];
  if ((tid & 63) == 0) red[tid >> 6] = ss;
  __syncthreads();
  const float scale = rsqrtf((red[0] + red[1] + red[2] + red[3]) * (1.f / 1024.f) + 1e-6f);
  const float4 w4 = *(const float4*)(w + tid * 4);
  *(float4*)(out + (size_t)r * 1024 + tid * 4) =
      make_float4(v0 * scale * w4.x, v1 * scale * w4.y, v2 * scale * w4.z, v3 * scale * w4.w);
}

// ---------------- per-head RMSNorm -----------------------------------------
__global__ __launch_bounds__(256) void onorm_k(const f16* __restrict__ o, const float* __restrict__ w,
                                               f16* __restrict__ ob) {
  const int r = blockIdx.x, tid = threadIdx.x;
  const int head = tid >> 5, l32 = tid & 31;
  const size_t base = (size_t)r * 1024 + head * 128 + l32 * 4;
  const h4 xv = *(const h4*)(o + base);
  const float v0 = (float)xv[0], v1 = (float)xv[1], v2 = (float)xv[2], v3 = (float)xv[3];
  float ss = v0 * v0 + v1 * v1 + v2 * v2 + v3 * v3;
#pragma unroll
  for (int m = 1; m <= 16; m <<= 1) ss += __shfl_xor(ss, m);
  const float sc = rsqrtf(ss * (1.f / 128.f) + 1e-6f);
  const float4 w4 = *(const float4*)(w + l32 * 4);
  h4 out = {(f16)(v0 * sc * w4.x), (f16)(v1 * sc * w4.y), (f16)(v2 * sc * w4.z), (f16)(v3 * sc * w4.w)};
  *(h4*)(ob + base) = out;
}

// ---------------- beta = 2*sigmoid(s * (x @ Wb')) --------------------------
__global__ __launch_bounds__(256) void beta_k(const f16* __restrict__ x, const float* __restrict__ Wb2,
                                              const float* __restrict__ rs, float* __restrict__ beta) {
  const int tid = threadIdx.x, lane = tid & 63, wv = tid >> 6;
  const int r = blockIdx.x * 4 + wv;
  const f16* row = x + (size_t)r * 1024 + lane * 16;
  const h8 v0 = *(const h8*)(row);
  const h8 v1 = *(const h8*)(row + 8);
  const float* wb = Wb2 + (size_t)(lane * 16) * 8;
  float acc[8] = {};
#pragma unroll
  for (int e = 0; e < 8; ++e) {
    const float x0 = (float)v0[e], x1 = (float)v1[e];
    const float4 w0a = *(const float4*)(wb + e * 8);
    const float4 w0b = *(const float4*)(wb + e * 8 + 4);
    const float4 w1a = *(const float4*)(wb + (e + 8) * 8);
    const float4 w1b = *(const float4*)(wb + (e + 8) * 8 + 4);
    acc[0] += x0 * w0a.x + x1 * w1a.x;  acc[1] += x0 * w0a.y + x1 * w1a.y;
    acc[2] += x0 * w0a.z + x1 * w1a.z;  acc[3] += x0 * w0a.w + x1 * w1a.w;
    acc[4] += x0 * w0b.x + x1 * w1b.x;  acc[5] += x0 * w0b.y + x1 * w1b.y;
    acc[6] += x0 * w0b.z + x1 * w1b.z;  acc[7] += x0 * w0b.w + x1 * w1b.w;
  }
#pragma unroll
  for (int j = 0; j < 8; ++j)
#pragma unroll
    for (int m = 1; m < 64; m <<= 1) acc[j] += __shfl_xor(acc[j], m);
  if (lane == 0) {
    const float s = rs[r];
#pragma unroll
    for (int j = 0; j < 8; ++j) beta[(size_t)r * 8 + j] = 2.f / (1.f + expf(-acc[j] * s));
  }
}

// ---------------- W[K][N] f32 -> Wt[N][K] f16 (opt row-weight fold) --------
template<int FOLD>
__global__ __launch_bounds__(256) void transpose_k(const float* __restrict__ W, const float* __restrict__ rw,
                                                   f16* __restrict__ Wt, int K, int N) {
  __shared__ float tile[32][33];
  const int n0 = blockIdx.x * 32, k0 = blockIdx.y * 32;
  const int tx = threadIdx.x & 31, ty = threadIdx.x >> 5;
#pragma unroll
  for (int i = 0; i < 32; i += 8) {
    float v = W[(size_t)(k0 + ty + i) * N + n0 + tx];
    if (FOLD) v *= rw[k0 + ty + i];
    tile[ty + i][tx] = v;
  }
  __syncthreads();
#pragma unroll
  for (int i = 0; i < 32; i += 8) Wt[(size_t)(n0 + ty + i) * K + k0 + tx] = (f16)tile[tx][ty + i];
}

// ---------------- Wb' = diag(n1w) Wb ---------------------------------------
__global__ __launch_bounds__(256) void bweight_k(const float* __restrict__ Wb, const float* __restrict__ n1w,
                                                 float* __restrict__ Wb2) {
  const int idx = blockIdx.x * 256 + threadIdx.x;
  Wb2[idx] = Wb[idx] * n1w[idx >> 3];
}

__global__ void fill_k(float* p, int n, float v) {
  const int i = blockIdx.x * 256 + threadIdx.x;
  if (i < n) p[i] = v;
}

// ---------------- Phase A: WY transform ------------------------------------
DEV f4 mm16(const f16* A, int as, const f16* B, f4 c, int l15, int l4) {
  h4 a = *(const h4*)(A + l15 * as + l4 * 4);
  h4 b = *(const h4*)(B + l15 * 20 + l4 * 4);
  return __builtin_amdgcn_mfma_f32_16x16x16f16(a, b, c, 0, 0, 0);
}
DEV void wr_T(f16* slot, f4 acc, int l15, int l4, float sgn) {
  h4 v = {(f16)(sgn * acc[0]), (f16)(sgn * acc[1]), (f16)(sgn * acc[2]), (f16)(sgn * acc[3])};
  *(h4*)(slot + l15 * 20 + l4 * 4) = v;
}
DEV void wr_Tb(f16* Tb, int bi, int bj, f4 acc, const float* betas, int l15, int l4, float sgn) {
  const float bc = betas[bj * 16 + l15];
#pragma unroll
  for (int q = 0; q < 4; ++q)
    Tb[(bi * 16 + l4 * 4 + q) * 72 + bj * 16 + l15] = (f16)(sgn * acc[q] * bc);
}

__global__ __launch_bounds__(256) void phaseA(const f16* __restrict__ kb, const f16* __restrict__ qb,
                                              const f16* __restrict__ vb, const float* __restrict__ beta,
                                              f16* __restrict__ wbuf, f16* __restrict__ utbuf,
                                              f16* __restrict__ pbuf, f16* __restrict__ ktbuf) {
  const int blk = blockIdx.x;
  const int c = blk >> 5, bh = blk & 31;
  const int b = bh >> 3, h = bh & 7;
  const int tid = threadIdx.x, lane = tid & 63, wv = tid >> 6;
  const int l15 = lane & 15, l4 = lane >> 4;

  __shared__ __align__(16) f16 Ks[64 * 128];
  __shared__ __align__(16) f16 QVs[64 * 128];
  __shared__ __align__(16) f16 Abuf[64 * 68];
  __shared__ __align__(16) f16 Dr[4][16 * 20];
  __shared__ __align__(16) f16 Dt[4][16 * 20];
  __shared__ __align__(16) f16 Tp[3][16 * 20];
  __shared__ __align__(16) f16 Xp[3][16 * 20];
  __shared__ __align__(16) f16 Tb[64 * 72];
  __shared__ float betas[64];

  const size_t rowstr = (size_t)Bb_ * Dd;
  const size_t gbase = ((size_t)(c * 64) * Bb_ + b) * Dd + h * 128;

#pragma unroll
  for (int i = 0; i < 4; ++i) {
    const int ch = tid + i * 256;
    const int rr = ch >> 4, kc = ch & 15;
    *(h8*)(Ks + ch * 8) = *(const h8*)(kb + gbase + (size_t)rr * rowstr + kc * 8);
    *(h8*)(QVs + ch * 8) = *(const h8*)(qb + gbase + (size_t)rr * rowstr + kc * 8);
  }
  for (int i = tid; i < 64 * 72; i += 256) Tb[i] = (f16)0.f;
  if (tid < 64) betas[tid] = beta[((size_t)(c * 64 + tid) * Bb_ + b) * Hh + h];
  __syncthreads();

  f4 accS[4] = {}, accP[4] = {};
  const int arow = wv * 16 + l15;
#pragma unroll
  for (int kc = 0; kc < 4; ++kc) {
    const int c4 = kc * 4 + l4;
    const h8 aK = *(const h8*)(Ks + arow * 128 + swz16(arow, c4) * 8);
    const h8 aQ = *(const h8*)(QVs + arow * 128 + swz16(arow, c4) * 8);
#pragma unroll
    for (int f = 0; f < 4; ++f) {
      const int brow = f * 16 + l15;
      const h8 bK = *(const h8*)(Ks + brow * 128 + swz16(brow, c4) * 8);
      accS[f] = __builtin_amdgcn_mfma_f32_16x16x32_f16(aK, bK, accS[f], 0, 0, 0);
      accP[f] = __builtin_amdgcn_mfma_f32_16x16x32_f16(aQ, bK, accP[f], 0, 0, 0);
    }
  }
  const size_t pbase = (((size_t)bh * NC + c) * 64) * 64;
#pragma unroll
  for (int f = 0; f < 4; ++f) {
#pragma unroll
    for (int q = 0; q < 4; ++q) {
      const int i = wv * 16 + l4 * 4 + q;
      const int j = f * 16 + l15;
      Abuf[i * 68 + j] = (f16)((j < i) ? betas[i] * accS[f][q] : 0.f);
      pbuf[pbase + (size_t)i * 64 + j] = (f16)((j <= i) ? accP[f][q] : 0.f);
    }
  }
  __syncthreads();

#pragma unroll
  for (int i = 0; i < 4; ++i) {
    const int ch = tid + i * 256;
    const int rr = ch >> 4, kc = ch & 15;
    *(h8*)(QVs + ch * 8) = *(const h8*)(vb + gbase + (size_t)rr * rowstr + kc * 8);
  }

  {
    const int bi = wv;
    const int cc = l15;
    const f16* Ad = Abuf + (bi * 16) * 68 + bi * 16;
    float t[16];
    t[0] = (cc == 0) ? 1.f : 0.f;
#pragma unroll
    for (int i = 1; i < 16; ++i) {
      float s = (cc == i) ? 1.f : 0.f;
#pragma unroll
      for (int j = 0; j < i; ++j) s -= (float)Ad[i * 68 + j] * t[j];
      t[i] = s;
    }
    if (lane < 16) {
#pragma unroll
      for (int j4 = 0; j4 < 4; ++j4) {
        h4 v = {(f16)t[j4 * 4], (f16)t[j4 * 4 + 1], (f16)t[j4 * 4 + 2], (f16)t[j4 * 4 + 3]};
        *(h4*)(&Dt[bi][cc * 20 + j4 * 4]) = v;
      }
      const float bc = betas[bi * 16 + cc];
#pragma unroll
      for (int j = 0; j < 16; ++j) {
        Dr[bi][j * 20 + cc] = (f16)t[j];
        Tb[(bi * 16 + j) * 72 + bi * 16 + cc] = (f16)(t[j] * bc);
      }
    }
  }
  __syncthreads();

  const f16* AB10 = Abuf + 16 * 68 + 0;
  const f16* AB20 = Abuf + 32 * 68 + 0;
  const f16* AB21 = Abuf + 32 * 68 + 16;
  const f16* AB30 = Abuf + 48 * 68 + 0;
  const f16* AB31 = Abuf + 48 * 68 + 16;
  const f16* AB32 = Abuf + 48 * 68 + 32;
  f4 z = {};
  f4 x20, x30;

  if (wv == 0) wr_T(Xp[0], mm16(AB10, 68, Dt[0], z, l15, l4), l15, l4, 1.f);
  if (wv == 1) wr_T(Xp[1], mm16(AB21, 68, Dt[1], z, l15, l4), l15, l4, 1.f);
  if (wv == 2) wr_T(Xp[2], mm16(AB32, 68, Dt[2], z, l15, l4), l15, l4, 1.f);
  if (wv == 3) x20 = mm16(AB20, 68, Dt[0], z, l15, l4);
  __syncthreads();
  if (wv == 0) { f4 r = mm16(Dr[1], 20, Xp[0], z, l15, l4); wr_T(Tp[0], r, l15, l4, -1.f); wr_Tb(Tb, 1, 0, r, betas, l15, l4, -1.f); }
  if (wv == 1) { f4 r = mm16(Dr[2], 20, Xp[1], z, l15, l4); wr_T(Tp[1], r, l15, l4, -1.f); wr_Tb(Tb, 2, 1, r, betas, l15, l4, -1.f); }
  if (wv == 2) { f4 r = mm16(Dr[3], 20, Xp[2], z, l15, l4); wr_Tb(Tb, 3, 2, r, betas, l15, l4, -1.f); }
  if (wv == 3) x30 = mm16(AB30, 68, Dt[0], z, l15, l4);
  __syncthreads();
  if (wv == 3) wr_T(Xp[0], mm16(AB21, 68, Tp[0], x20, l15, l4), l15, l4, 1.f);
  if (wv == 1) { f4 r = mm16(AB31, 68, Dt[1], z, l15, l4); r = mm16(AB32, 68, Tp[1], r, l15, l4); wr_T(Xp[1], r, l15, l4, 1.f); }
  __syncthreads();
  if (wv == 3) { f4 r = mm16(Dr[2], 20, Xp[0], z, l15, l4); wr_T(Tp[2], r, l15, l4, -1.f); wr_Tb(Tb, 2, 0, r, betas, l15, l4, -1.f); }
  if (wv == 1) { f4 r = mm16(Dr[3], 20, Xp[1], z, l15, l4); wr_Tb(Tb, 3, 1, r, betas, l15, l4, -1.f); }
  __syncthreads();
  if (wv == 3) { f4 r = mm16(AB31, 68, Tp[0], x30, l15, l4); r = mm16(AB32, 68, Tp[2], r, l15, l4); wr_T(Xp[2], r, l15, l4, 1.f); }
  __syncthreads();
  if (wv == 3) { f4 r = mm16(Dr[3], 20, Xp[2], z, l15, l4); wr_Tb(Tb, 3, 0, r, betas, l15, l4, -1.f); }
  __syncthreads();

  const size_t wub = ((size_t)bh * NC + c) * 8192;
  const int koff = l4 * 8;
  f4 wacc[8] = {}, uacc[8] = {};
#pragma unroll
  for (int kc = 0; kc < 2; ++kc) {
    const h8 aT = *(const h8*)(Tb + (wv * 16 + l15) * 72 + kc * 32 + koff);
#pragma unroll
    for (int f = 0; f < 8; ++f) {
      const int d = f * 16 + l15, cD = d >> 3, d7 = d & 7;
      h8 bK, bV;
#pragma unroll
      for (int j = 0; j < 8; ++j) {
        const int t2 = kc * 32 + koff + j;
        const int pos = t2 * 128 + swz16(t2, cD) * 8 + d7;
        bK[j] = Ks[pos];
        bV[j] = QVs[pos];
      }
      wacc[f] = __builtin_amdgcn_mfma_f32_16x16x32_f16(aT, bK, wacc[f], 0, 0, 0);
      uacc[f] = __builtin_amdgcn_mfma_f32_16x16x32_f16(aT, bV, uacc[f], 0, 0, 0);
    }
  }
#pragma unroll
  for (int f = 0; f < 8; ++f) {
    const int d = f * 16 + l15, cD = d >> 3, d7 = d & 7;
#pragma unroll
    for (int q = 0; q < 4; ++q) {
      const int i = wv * 16 + l4 * 4 + q;
      wbuf[wub + (size_t)i * 128 + swz16(i, cD) * 8 + d7] = (f16)wacc[f][q];
    }
    h4 uv = {(f16)uacc[f][0], (f16)uacc[f][1], (f16)uacc[f][2], (f16)uacc[f][3]};
    *(h4*)(utbuf + wub + (size_t)d * 64 + wv * 16 + l4 * 4) = uv;
  }

#pragma unroll
  for (int i2 = 0; i2 < 4; ++i2) {
    const int ch = tid + i2 * 256;
    const int dp = ch & 127, c2 = ch >> 7;
    h8 v;
#pragma unroll
    for (int j = 0; j < 8; ++j) {
      const int i = c2 * 8 + j;
      v[j] = Ks[i * 128 + swz16(i, dp >> 3) * 8 + (dp & 7)];
    }
    *(h8*)(ktbuf + wub + (size_t)dp * 64 + (c2 ^ (dp & 7)) * 8) = v;
  }
}

// ---------------- Phase B: chunk recurrence (g in 0..7, 16 cols) -----------
__global__ __launch_bounds__(256) void phaseB(const f16* __restrict__ qb, const f16* __restrict__ ktbuf,
                                              const f16* __restrict__ wbuf, const f16* __restrict__ utbuf,
                                              const f16* __restrict__ pbuf, f16* __restrict__ obuf) {
  const int blk = blockIdx.x;          // g*32 + bh : siblings share XCD class
  const int bh = blk & 31, g = blk >> 5;
  const int b = bh >> 3, h = bh & 7;
  const int tid = threadIdx.x, lane = tid & 63, wv = tid >> 6;
  const int l15 = lane & 15, l4 = lane >> 4;

  __shared__ __align__(16) f16 Ws[2][8192];
  __shared__ __align__(16) f16 Qs[2][8192];
  __shared__ __align__(16) f16 Kts[2][8192];
  __shared__ __align__(16) f16 Rt[16 * 72];
  __shared__ __align__(16) f16 Ms[16 * 136];

  for (int i = tid; i < 16 * 136; i += 256) Ms[i] = (f16)0.f;
  f4 macc2[2] = {};

  const int arow = wv * 16 + l15;
  const int koff = l4 * 8;

  auto STAGE = [&](int c2, int buf) {
#pragma unroll
    for (int i = 0; i < 4; ++i) {
      const int ch = tid + i * 256;
      const size_t tb = ((size_t)bh * NC + c2) * 8192;
      __builtin_amdgcn_global_load_lds(AS1(wbuf + tb + ch * 8), AS3(Ws[buf] + ch * 8), 16, 0, 0);
      __builtin_amdgcn_global_load_lds(AS1(ktbuf + tb + ch * 8), AS3(Kts[buf] + ch * 8), 16, 0, 0);
      const int rr = ch >> 4, kc2 = ch & 15;
      __builtin_amdgcn_global_load_lds(AS1(qb + ((size_t)((c2 * 64 + rr) * 4 + b)) * 1024 + h * 128 + kc2 * 8),
                                       AS3(Qs[buf] + ch * 8), 16, 0, 0);
    }
  };

  STAGE(0, 0);
  asm volatile("s_waitcnt vmcnt(0)" ::: "memory");
  __builtin_amdgcn_s_barrier();

  for (int c = 0; c < NC; ++c) {
    const int cur = c & 1, nxt = cur ^ 1;
    const size_t pcb = ((size_t)bh * NC + c) * 4096;
    const h8 aP0 = *(const h8*)(pbuf + pcb + arow * 64 + koff);
    const h8 aP1 = *(const h8*)(pbuf + pcb + arow * 64 + 32 + koff);
    const size_t ucb = ((size_t)bh * NC + c) * 8192;
    const h4 u0 = *(const h4*)(utbuf + ucb + (size_t)(g * 16 + l15) * 64 + wv * 16 + l4 * 4);
    asm volatile("s_waitcnt vmcnt(3)" ::: "memory");   // prev stage retired
    asm volatile("s_waitcnt lgkmcnt(0)" ::: "memory");
    __builtin_amdgcn_s_barrier();
    if (c + 1 < NC) STAGE(c + 1, nxt);

    f4 accR = {}, accO = {};
    __builtin_amdgcn_s_setprio(1);
#pragma unroll
    for (int kc = 0; kc < 4; ++kc) {
      const int c4 = kc * 4 + l4;
      const h8 aW = *(const h8*)(Ws[cur] + arow * 128 + swz16(arow, c4) * 8);
      const h8 aQ = *(const h8*)(Qs[cur] + arow * 128 + swz16(arow, c4) * 8);
      const h8 bM = *(const h8*)(Ms + l15 * 136 + kc * 32 + koff);
      accR = __builtin_amdgcn_mfma_f32_16x16x32_f16(aW, bM, accR, 0, 0, 0);
      accO = __builtin_amdgcn_mfma_f32_16x16x32_f16(aQ, bM, accO, 0, 0, 0);
    }
    __builtin_amdgcn_s_setprio(0);
    if (c + 1 < NC) asm volatile("s_waitcnt vmcnt(12)" ::: "memory");  // u,P arrived
    else            asm volatile("s_waitcnt vmcnt(0)" ::: "memory");
    {
      h4 rw;
#pragma unroll
      for (int q = 0; q < 4; ++q) {
        const float rv = (float)u0[q] - accR[q];
        rw[q] = (f16)rv;
      }
      *(h4*)(Rt + l15 * 72 + wv * 16 + l4 * 4) = rw;
    }
    asm volatile("s_waitcnt lgkmcnt(0)" ::: "memory");
    __builtin_amdgcn_s_barrier();

#pragma unroll
    for (int kc = 0; kc < 2; ++kc) {
      const h8 aP = kc ? aP1 : aP0;
      const h8 bR = *(const h8*)(Rt + l15 * 72 + kc * 32 + koff);
      accO = __builtin_amdgcn_mfma_f32_16x16x32_f16(aP, bR, accO, 0, 0, 0);
    }
#pragma unroll
    for (int q = 0; q < 4; ++q) {
      const int i = wv * 16 + l4 * 4 + q;
      obuf[((size_t)(c * 64 + i) * Bb_ + b) * Dd + h * 128 + g * 16 + l15] = (f16)accO[q];
    }

#pragma unroll
    for (int kc = 0; kc < 2; ++kc) {
      const h8 aR0 = *(const h8*)(Rt + l15 * 72 + kc * 32 + koff);
#pragma unroll
      for (int cf = 0; cf < 2; ++cf) {
        const int kcol = wv * 32 + cf * 16 + l15;
        const int c2 = kc * 4 + l4;
        const h8 bKv = *(const h8*)(Kts[cur] + kcol * 64 + (c2 ^ (kcol & 7)) * 8);
        macc2[cf] = __builtin_amdgcn_mfma_f32_16x16x32_f16(aR0, bKv, macc2[cf], 0, 0, 0);
      }
    }
#pragma unroll
    for (int cf = 0; cf < 2; ++cf)
#pragma unroll
      for (int q = 0; q < 4; ++q) {
        const int cr = l4 * 4 + q;
        const int kcol = wv * 32 + cf * 16 + l15;
        Ms[cr * 136 + kcol] = (f16)macc2[cf][q];
      }
  }
}

// ---------------------------------------------------------------------------
extern "C" void kernel_launch(void* const* d_in, const int* in_sizes, int n_in,
                              void* d_out, int out_size, void* d_ws, size_t ws_size,
                              hipStream_t stream) {
  (void)in_sizes; (void)n_in;
  const float* input = (const float*)d_in[0];
  const float* Wq = (const float*)d_in[1];
  const float* Wk = (const float*)d_in[2];
  const float* Wv = (const float*)d_in[3];
  const float* Wb = (const float*)d_in[4];
  const float* Wo = (const float*)d_in[5];
  const float* onw = (const float*)d_in[6];
  const float* n1w = (const float*)d_in[7];
  const float* n2w = (const float*)d_in[8];
  const float* Wg = (const float*)d_in[9];
  const float* Wd = (const float*)d_in[10];
  const float* fnw = (const float*)d_in[11];

  char* ws = (char*)d_ws;
  size_t off = 0;
  auto alloc = [&](size_t bytes) { void* p = ws + off; off += (bytes + 255) & ~(size_t)255; return p; };
  const size_t RD = 8192ull * 1024ull;
  f16*  x     = (f16*)alloc(RD * 2);
  f16*  qb    = (f16*)alloc(RD * 2);
  f16*  kbuf  = (f16*)alloc(RD * 2);
  f16*  vbuf  = (f16*)alloc(RD * 2);
  float* beta = (float*)alloc(8192ull * 8 * 4);
  float* rs   = (float*)alloc(8192ull * 4);
  float* Wb2  = (float*)alloc(1024ull * 8 * 4);
  f16*  wbuf  = (f16*)alloc(RD * 2);
  f16*  utbuf = (f16*)alloc(RD * 2);
  f16*  ktbuf = (f16*)alloc(RD * 2);
  f16*  pbuf  = (f16*)alloc(32ull * 32 * 64 * 64 * 2);
  char* arena = (char*)alloc(3 * RD * 2);
  f16*  WqkvT = (f16*)alloc(3072ull * 1024 * 2);
  f16*  WoT   = (f16*)alloc(1024ull * 1024 * 2);
  f16*  WgT   = (f16*)alloc(5632ull * 1024 * 2);
  f16*  WdT   = (f16*)alloc(1024ull * 2816 * 2);
  if (off > ws_size) {
    fill_k<<<(out_size + 255) / 256, 256, 0, stream>>>((float*)d_out, out_size, 1.0e6f);
    return;
  }
  f16* obuf = (f16*)arena;
  f16* my = qb;     // qb/kbuf/vbuf dead by the MLP
  f16* ob = wbuf;   // wbuf dead after phaseB

  cvt_k<<<4096, 256, 0, stream>>>(input, x);

  for (int l = 0; l < 2; ++l) {
    const size_t o2 = (size_t)l * 1024 * 1024;
    transpose_k<1><<<dim3(32, 32), 256, 0, stream>>>(Wq + o2, n1w + l * 1024, WqkvT, 1024, 1024);
    transpose_k<1><<<dim3(32, 32), 256, 0, stream>>>(Wk + o2, n1w + l * 1024, WqkvT + 1024ull * 1024, 1024, 1024);
    transpose_k<1><<<dim3(32, 32), 256, 0, stream>>>(Wv + o2, n1w + l * 1024, WqkvT + 2048ull * 1024, 1024, 1024);
    transpose_k<0><<<dim3(32, 32), 256, 0, stream>>>(Wo + o2, nullptr, WoT, 1024, 1024);
    transpose_k<1><<<dim3(176, 32), 256, 0, stream>>>(Wg + (size_t)l * 1024 * 5632, n2w + l * 1024, WgT, 1024, 5632);
    transpose_k<0><<<dim3(32, 88), 256, 0, stream>>>(Wd + (size_t)l * 2816 * 1024, nullptr, WdT, 2816, 1024);
    bweight_k<<<32, 256, 0, stream>>>(Wb + (size_t)l * 1024 * 8, n1w + l * 1024, Wb2);

    rowscale_k<<<2048, 256, 0, stream>>>(x, rs);
    gemmQKV<<<32 * 24, 512, 0, stream>>>(x, WqkvT, rs, qb, kbuf, vbuf, 1024, 24);
    beta_k<<<2048, 256, 0, stream>>>(x, Wb2, rs, beta);
    phaseA<<<1024, 256, 0, stream>>>(kbuf, qb, vbuf, beta, wbuf, utbuf, pbuf, ktbuf);
    phaseB<<<256, 256, 0, stream>>>(qb, ktbuf, wbuf, utbuf, pbuf, obuf);
    onorm_k<<<8192, 256, 0, stream>>>(obuf, onw + l * 128, ob);
    gemm2<1, 0><<<32 * 8, 512, 0, stream>>>(ob, WoT, x, nullptr, 8192, 1024, 1024, 8);

    rowscale_k<<<2048, 256, 0, stream>>>(x, rs);
    gemmGLU<<<32 * 22, 512, 0, stream>>>(x, WgT, rs, my, 1024, 22);
    gemm2<1, 0><<<32 * 8, 512, 0, stream>>>(my, WdT, x, nullptr, 8192, 1024, 2816, 8);
  }
  rmsnorm_f<<<8192, 256, 0, stream>>>(x, fnw, (float*)d_out);
}